// Round 8
// baseline (704.899 us; speedup 1.0000x reference)
//
#include <hip/hip_runtime.h>
#include <math.h>

#define B_ 4
#define CCH 128
#define HH 64
#define WW 64
#define LL 4096
#define NCHK 64

__device__ __forceinline__ float siluf(float x) { return x / (1.f + __expf(-x)); }
__device__ __forceinline__ float softplusf(float x) { return (x > 20.f) ? x : log1pf(__expf(x)); }
// swizzled [n][l] layout, pitch 64: phys = n*64 + (((l>>2) ^ ((n>>2)&15))<<2 | (l&3))
__device__ __forceinline__ int swz(int n, int l) {
  return (n << 6) + ((((l >> 2) ^ ((n >> 2) & 15)) << 2) | (l & 3));
}

// ---------------- seed tokenize ----------------
__global__ __launch_bounds__(256) void k_seedtok(const float* __restrict__ x,
    const float* __restrict__ w, const float* __restrict__ bias, float* __restrict__ gf)
{
  __shared__ float sw[8*128];
  int tid = threadIdx.x;
  for (int i = tid; i < 1024; i += 256) sw[i] = w[i];
  __syncthreads();
  int idx = blockIdx.x * 256 + tid;
  int b = idx / LL, l = idx % LL;
  const float* xp = x + (size_t)b*CCH*LL + l;
  float acc[8];
#pragma unroll
  for (int g = 0; g < 8; ++g) acc[g] = bias[g];
  for (int c = 0; c < CCH; ++c) {
    float xv = xp[(size_t)c*LL];
#pragma unroll
    for (int g = 0; g < 8; ++g) acc[g] += xv * sw[g*128 + c];
  }
  float* o = gf + (size_t)idx*8;
#pragma unroll
  for (int g = 0; g < 8; ++g) o[g] = acc[g];
}

// ---------------- fused in-projection + causal conv3 + silu + softplus(dt) v4 (seed path) ----------------
template<int DIN, int NZ, int NDS, int NDT>
__global__ __launch_bounds__(256) void k_inproj(
    const float* __restrict__ src, int srcMode,
    const float* __restrict__ in_w, const float* __restrict__ in_b,
    const float* __restrict__ conv_w, const float* __restrict__ conv_b,
    const float* __restrict__ dt_bias,
    float* __restrict__ zb, float* __restrict__ dtb,
    float* __restrict__ xsb, float* __restrict__ Bb, float* __restrict__ Cb)
{
  constexpr int NXBC = NZ + 2*NDS;
  constexpr int NTOT = 2*NZ + 2*NDS + NDT;
  constexpr int NZQ  = NZ/4;
  constexpr int NDSQ = NDS/4;
  constexpr int XP   = DIN + 1;
  __shared__ float xt[66*XP];
  __shared__ float wl[NTOT*DIN];
  __shared__ float cwl[NXBC*3];
  __shared__ float cbl[NXBC];
  __shared__ float ibl[NTOT];
  __shared__ float dts[64*NDT];
  __shared__ float hp[NXBC*2];
  int tid = threadIdx.x;
  int seq = blockIdx.x >> 6;
  int l0  = (blockIdx.x & 63) << 6;
  for (int i = tid; i < NTOT*DIN; i += 256) wl[i] = in_w[i];
  for (int i = tid; i < NXBC*3; i += 256) cwl[i] = conv_w[i];
  for (int i = tid; i < NXBC; i += 256) cbl[i] = conv_b[i];
  for (int i = tid; i < NTOT; i += 256) ibl[i] = in_b[i];
  const float* sp; int sstr;
  if (srcMode == 0) { sp = src + (size_t)seq*LL*DIN; sstr = DIN; }
  else { sp = src + (size_t)(seq & 3)*LL*CCH + (seq >> 2)*16; sstr = CCH; }
  for (int i = tid; i < 66*DIN; i += 256) {
    int r = i / DIN, d = i % DIN;
    int l = l0 - 2 + r;
    xt[r*XP + d] = (l >= 0) ? sp[(size_t)l*sstr + d] : 0.f;
  }
  __syncthreads();
  for (int i = tid; i < 2*NXBC; i += 256) {
    int t = i & 1, ch = i >> 1;
    const float* wr = &wl[(NZ + ch)*DIN];
    const float* xp = &xt[t*XP];
    float acc = 0.f;
#pragma unroll
    for (int d = 0; d < DIN; ++d) acc += xp[d]*wr[d];
    hp[ch*2 + t] = acc;
  }
  __syncthreads();
  int l = tid & 63, w4 = tid >> 6;
  float xr2[DIN];
#pragma unroll
  for (int d = 0; d < DIN; ++d) xr2[d] = xt[(l+2)*XP + d];
  size_t gl = (size_t)seq*LL + l0 + l;
  int tok = l0 + l;
  float v0ok = (tok >= 2) ? 1.f : 0.f;
  float v1ok = (tok >= 1) ? 1.f : 0.f;
  {
    float zv[NZQ];
#pragma unroll
    for (int j = 0; j < NZQ; ++j) {
      int row = w4*NZQ + j;
      const float* wr = &wl[row*DIN];
      float acc = ibl[row];
#pragma unroll
      for (int d = 0; d < DIN; ++d) acc += xr2[d]*wr[d];
      zv[j] = acc;
    }
#pragma unroll
    for (int g = 0; g < NZQ/4; ++g)
      *(float4*)&zb[gl*NZ + w4*NZQ + 4*g] = make_float4(zv[4*g], zv[4*g+1], zv[4*g+2], zv[4*g+3]);
  }
  if (w4 < NDT) {
    int row = NTOT - NDT + w4;
    const float* wr = &wl[row*DIN];
    float acc = ibl[row] + dt_bias[w4];
#pragma unroll
    for (int d = 0; d < DIN; ++d) acc += xr2[d]*wr[d];
    dts[l*NDT + w4] = softplusf(acc);
  }
  auto convch = [&](int ch) -> float {
    int row = NZ + ch;
    const float* wr = &wl[row*DIN];
    float pm = 0.f;
#pragma unroll
    for (int d = 0; d < DIN; ++d) pm += xr2[d]*wr[d];
    float m1 = __shfl_up(pm, 1, 64);
    float m2 = __shfl_up(pm, 2, 64);
    float h0 = hp[ch*2 + 0], h1 = hp[ch*2 + 1];
    if (l == 0) m1 = h1;
    m2 = (l == 0) ? h0 : ((l == 1) ? h1 : m2);
    float ib = ibl[row];
    float conv = cbl[ch] + (m2+ib)*v0ok*cwl[ch*3+0] + (m1+ib)*v1ok*cwl[ch*3+1] + (pm+ib)*cwl[ch*3+2];
    return siluf(conv);
  };
  {
    float xv[NZQ];
#pragma unroll
    for (int j = 0; j < NZQ; ++j) xv[j] = convch(w4*NZQ + j);
#pragma unroll
    for (int g = 0; g < NZQ/4; ++g)
      *(float4*)&xsb[gl*NZ + w4*NZQ + 4*g] = make_float4(xv[4*g], xv[4*g+1], xv[4*g+2], xv[4*g+3]);
  }
  {
    float bv[NDSQ];
#pragma unroll
    for (int j = 0; j < NDSQ; ++j) bv[j] = convch(NZ + w4*NDSQ + j);
#pragma unroll
    for (int g = 0; g < NDSQ/4; ++g)
      *(float4*)&Bb[gl*NDS + w4*NDSQ + 4*g] = make_float4(bv[4*g], bv[4*g+1], bv[4*g+2], bv[4*g+3]);
  }
  {
    float cv[NDSQ];
#pragma unroll
    for (int j = 0; j < NDSQ; ++j) cv[j] = convch(NZ + NDS + w4*NDSQ + j);
#pragma unroll
    for (int g = 0; g < NDSQ/4; ++g)
      *(float4*)&Cb[gl*NDS + w4*NDSQ + 4*g] = make_float4(cv[4*g], cv[4*g+1], cv[4*g+2], cv[4*g+3]);
  }
  __syncthreads();
  if (tid < 64) {
    if constexpr (NDT == 4) {
      *(float4*)&dtb[((size_t)seq*LL + l0 + tid)*4] =
          make_float4(dts[tid*4], dts[tid*4+1], dts[tid*4+2], dts[tid*4+3]);
    } else {
      *(float2*)&dtb[((size_t)seq*LL + l0 + tid)*NDT] = make_float2(dts[tid*NDT], dts[tid*NDT+1]);
    }
  }
}

// ======= FUSED inproj + intra-chunk SSD for the cascade config (DIN=16,NZ=32,NDS=64,NDT=4,NH=4) =======
// One block per (seq, chunk). Wave w (lane = token): z quarter, dt head w, xs head w (kept in regs),
// B quarter -> rotated LDS [l][n], C quarter -> swz LDS + global. Then Gram, Yd, states in-block.
// B and dt never touch global memory.
__global__ __launch_bounds__(256, 3) void k_inssd(
    const float* __restrict__ src, int srcMode,
    const float* __restrict__ in_w, const float* __restrict__ in_b,
    const float* __restrict__ conv_w, const float* __restrict__ conv_b,
    const float* __restrict__ dt_bias, const float* __restrict__ A_log,
    float* __restrict__ zb, float* __restrict__ xsb, float* __restrict__ Cb,
    float* __restrict__ ybuf, float* __restrict__ states,
    float* __restrict__ cdec, float* __restrict__ acsOut)
{
  const int DIN = 16, NZ = 32, NDS = 64, DI = 32;
  const int NXBC = 160, NTOT = 196, XP = 17;
  __shared__ float sm[13606];            // 54424 B -> 3 blocks/CU
  float* Bl  = sm;                       // 4096: B [l][n] rotated: phys = l*64 + ((n+l)&63)
  float* Ct  = sm + 4096;                // 4096: C swz(n,l); later Gt swz(s,l)
  float* U   = sm + 8192;                // union: phase A staging / phase B xde
  float* xt  = U;                        // 66*17 = 1122
  float* wl  = U + 1122;                 // 196*16 = 3136
  float* cwl = U + 4258;                 // 480
  float* cbl = U + 4738;                 // 160
  float* ibl = U + 4898;                 // 196
  float* hp  = U + 5094;                 // 320
  float* xde = U;                        // phase B: 4*64*8 = 2048
  int tid = threadIdx.x;
  int cid = blockIdx.x & 63;
  int seq = blockIdx.x >> 6;
  int l0  = cid << 6;
  for (int i = tid; i < NTOT*DIN; i += 256) wl[i] = in_w[i];
  for (int i = tid; i < NXBC*3; i += 256) cwl[i] = conv_w[i];
  for (int i = tid; i < NXBC; i += 256) cbl[i] = conv_b[i];
  for (int i = tid; i < NTOT; i += 256) ibl[i] = in_b[i];
  const float* sp; int sstr;
  if (srcMode == 0) { sp = src + (size_t)seq*LL*DIN; sstr = DIN; }
  else { sp = src + (size_t)(seq & 3)*LL*CCH + (seq >> 2)*16; sstr = CCH; }
  for (int i = tid; i < 66*DIN; i += 256) {
    int r = i / DIN, d = i % DIN;
    int l = l0 - 2 + r;
    xt[r*XP + d] = (l >= 0) ? sp[(size_t)l*sstr + d] : 0.f;
  }
  __syncthreads();
  for (int i = tid; i < 2*NXBC; i += 256) {
    int t = i & 1, ch = i >> 1;
    const float* wr = &wl[(NZ + ch)*DIN];
    const float* xp = &xt[t*XP];
    float acc = 0.f;
#pragma unroll
    for (int d = 0; d < DIN; ++d) acc += xp[d]*wr[d];
    hp[ch*2 + t] = acc;
  }
  __syncthreads();
  int lane = tid & 63, w = tid >> 6;          // lane = token, w = wave = head
  float xr2[DIN];
#pragma unroll
  for (int d = 0; d < DIN; ++d) xr2[d] = xt[(lane+2)*XP + d];
  size_t gl = (size_t)seq*LL + l0 + lane;
  int tok = l0 + lane;
  float v0ok = (tok >= 2) ? 1.f : 0.f;
  float v1ok = (tok >= 1) ? 1.f : 0.f;
  // ---- z quarter ----
  {
    float zv[8];
#pragma unroll
    for (int j = 0; j < 8; ++j) {
      int row = w*8 + j;
      const float* wr = &wl[row*DIN];
      float acc = ibl[row];
#pragma unroll
      for (int d = 0; d < DIN; ++d) acc += xr2[d]*wr[d];
      zv[j] = acc;
    }
    *(float4*)&zb[gl*NZ + w*8 + 0] = make_float4(zv[0], zv[1], zv[2], zv[3]);
    *(float4*)&zb[gl*NZ + w*8 + 4] = make_float4(zv[4], zv[5], zv[6], zv[7]);
  }
  // ---- dt head w (kept in register) ----
  float dtv;
  {
    int row = NTOT - 4 + w;
    const float* wr = &wl[row*DIN];
    float acc = ibl[row] + dt_bias[w];
#pragma unroll
    for (int d = 0; d < DIN; ++d) acc += xr2[d]*wr[d];
    dtv = softplusf(acc);
  }
  auto convch = [&](int ch) -> float {
    int row = NZ + ch;
    const float* wr = &wl[row*DIN];
    float pm = 0.f;
#pragma unroll
    for (int d = 0; d < DIN; ++d) pm += xr2[d]*wr[d];
    float m1 = __shfl_up(pm, 1, 64);
    float m2 = __shfl_up(pm, 2, 64);
    float h0 = hp[ch*2 + 0], h1 = hp[ch*2 + 1];
    if (lane == 0) m1 = h1;
    m2 = (lane == 0) ? h0 : ((lane == 1) ? h1 : m2);
    float ib = ibl[row];
    float conv = cbl[ch] + (m2+ib)*v0ok*cwl[ch*3+0] + (m1+ib)*v1ok*cwl[ch*3+1] + (pm+ib)*cwl[ch*3+2];
    return siluf(conv);
  };
  // ---- xs head w: 8 channels, keep in regs + write global ----
  float xv[8];
#pragma unroll
  for (int j = 0; j < 8; ++j) xv[j] = convch(w*8 + j);
  *(float4*)&xsb[gl*DI + w*8 + 0] = make_float4(xv[0], xv[1], xv[2], xv[3]);
  *(float4*)&xsb[gl*DI + w*8 + 4] = make_float4(xv[4], xv[5], xv[6], xv[7]);
  // ---- B quarter -> rotated LDS only ----
#pragma unroll
  for (int j = 0; j < 16; ++j) {
    int n = w*16 + j;
    float b = convch(NZ + n);
    Bl[lane*64 + ((n + lane) & 63)] = b;
  }
  // ---- C quarter -> swz LDS + global ----
  {
    float cv[16];
#pragma unroll
    for (int j = 0; j < 16; ++j) {
      int n = w*16 + j;
      cv[j] = convch(NZ + NDS + n);
      Ct[swz(n, lane)] = cv[j];
    }
#pragma unroll
    for (int g = 0; g < 4; ++g)
      *(float4*)&Cb[gl*NDS + w*16 + 4*g] = make_float4(cv[4*g], cv[4*g+1], cv[4*g+2], cv[4*g+3]);
  }
  __syncthreads();   // sync1: all phase-A LDS reads complete; Bl/Ct staged
  // ---- acs scan (head w) + xde write (aliases dead phase-A arrays) ----
  float Aval = -__expf(A_log[w]);
  float v = dtv * Aval;
#pragma unroll
  for (int off = 1; off < 64; off <<= 1) {
    float t = __shfl_up(v, off, 64);
    if (lane >= off) v += t;
  }
  float acs_l = v;
  float m = __shfl(v, 31, 64);
  float acsLast = __shfl(v, 63, 64);
  float el = __expf(fminf(acs_l - m, 60.f));
  float fl = __expf(fminf(m - acs_l, 60.f));
  {
    float s1 = dtv*fl;
    float* xe = &xde[(w*64 + lane)*8];
    *(float4*)xe     = make_float4(xv[0]*s1, xv[1]*s1, xv[2]*s1, xv[3]*s1);
    *(float4*)(xe+4) = make_float4(xv[4]*s1, xv[5]*s1, xv[6]*s1, xv[7]*s1);
  }
  // ---- Gram G = C.B^T (4l x 4s per thread) ----
  int lt = (tid >> 4) << 2, st = (tid & 15) << 2;
  float acc[4][4] = {};
#pragma unroll 4
  for (int n = 0; n < 64; ++n) {
    float4 cvv = *(const float4*)&Ct[swz(n, lt)];
    float cc[4] = {cvv.x, cvv.y, cvv.z, cvv.w};
    float bb[4];
#pragma unroll
    for (int j = 0; j < 4; ++j) bb[j] = Bl[(st+j)*64 + ((n + st + j) & 63)];
#pragma unroll
    for (int i2 = 0; i2 < 4; ++i2)
#pragma unroll
      for (int j2 = 0; j2 < 4; ++j2)
        acc[i2][j2] += cc[i2]*bb[j2];
  }
  __syncthreads();   // sync2: Gram reads of Ct done
#pragma unroll
  for (int j = 0; j < 4; ++j) {
    *(float4*)&Ct[swz(st + j, lt)] = make_float4(acc[0][j], acc[1][j], acc[2][j], acc[3][j]);
  }
  __syncthreads();   // sync3: Gt complete
  // ---- per-head Yd (wave w = head) ----
  int lg = lane >> 2, lm = lane & 3;
  float ya[8] = {0,0,0,0,0,0,0,0};
#pragma unroll 4
  for (int s = 0; s < 64; ++s) {
    float g = Ct[(s << 6) + (((lg ^ ((s >> 2) & 15))) << 2 | lm)];
    g = (s <= lane) ? g : 0.f;
    const float* xr = &xde[(w*64 + s)*8];
    float4 a0 = *(const float4*)xr, a1 = *(const float4*)(xr + 4);
    ya[0] += g*a0.x; ya[1] += g*a0.y; ya[2] += g*a0.z; ya[3] += g*a0.w;
    ya[4] += g*a1.x; ya[5] += g*a1.y; ya[6] += g*a1.z; ya[7] += g*a1.w;
  }
  float* yp = &ybuf[gl*DI + w*8];
  *(float4*)yp     = make_float4(ya[0]*el, ya[1]*el, ya[2]*el, ya[3]*el);
  *(float4*)(yp+4) = make_float4(ya[4]*el, ya[5]*el, ya[6]*el, ya[7]*el);
  // ---- states (lane = n) ----
  {
    float r2 = __expf(acsLast - m);
    float sa[8] = {0,0,0,0,0,0,0,0};
#pragma unroll 4
    for (int ll = 0; ll < 64; ++ll) {
      float b = Bl[ll*64 + ((lane + ll) & 63)];
      const float* xr = &xde[(w*64 + ll)*8];
      float4 a0 = *(const float4*)xr, a1 = *(const float4*)(xr + 4);
      sa[0] += b*a0.x; sa[1] += b*a0.y; sa[2] += b*a0.z; sa[3] += b*a0.w;
      sa[4] += b*a1.x; sa[5] += b*a1.y; sa[6] += b*a1.z; sa[7] += b*a1.w;
    }
    float* sp2 = &states[(((size_t)seq*4 + w)*NCHK + cid)*(size_t)(8*NDS) + lane*8];
    *(float4*)sp2     = make_float4(sa[0]*r2, sa[1]*r2, sa[2]*r2, sa[3]*r2);
    *(float4*)(sp2+4) = make_float4(sa[4]*r2, sa[5]*r2, sa[6]*r2, sa[7]*r2);
  }
  if (lane == 63) cdec[((size_t)seq*4 + w)*NCHK + cid] = __expf(acsLast);
  acsOut[((size_t)seq*4 + w)*LL + l0 + lane] = acs_l;
}

// ---------------- SSD intra-chunk v3 (seed path) ----------------
template<int DS, int NH>
__global__ __launch_bounds__(256) void k_ssd1(
    const float* __restrict__ xs, const float* __restrict__ dtb,
    const float* __restrict__ Bb, const float* __restrict__ Cb,
    const float* __restrict__ A_log,
    float* __restrict__ ybuf, float* __restrict__ states,
    float* __restrict__ cdec, float* __restrict__ acsOut)
{
  constexpr int DI = NH*8;
  constexpr int NG = DS/4;
  __shared__ __align__(16) float BtBl[DS*64];
  __shared__ __align__(16) float CtGt[64*64];
  __shared__ __align__(16) float xde[NH*64*8];
  int tid = threadIdx.x;
  int cid = blockIdx.x & 63;
  int seq = blockIdx.x >> 6;
  int l0  = cid << 6;
  for (int i = tid; i < 16*DS; i += 256) {
    int ng = i % NG, l = i / NG;
    size_t g = ((size_t)seq*LL + l0 + l)*DS + 4*ng;
    float4 bv = *(const float4*)&Bb[g];
    float4 cv = *(const float4*)&Cb[g];
    BtBl[swz(4*ng+0, l)] = bv.x; BtBl[swz(4*ng+1, l)] = bv.y;
    BtBl[swz(4*ng+2, l)] = bv.z; BtBl[swz(4*ng+3, l)] = bv.w;
    CtGt[swz(4*ng+0, l)] = cv.x; CtGt[swz(4*ng+1, l)] = cv.y;
    CtGt[swz(4*ng+2, l)] = cv.z; CtGt[swz(4*ng+3, l)] = cv.w;
  }
  __syncthreads();
  int lt = (tid >> 4) << 2, st = (tid & 15) << 2;
  float acc[4][4] = {};
#pragma unroll 4
  for (int n = 0; n < DS; ++n) {
    float4 cv = *(const float4*)&CtGt[swz(n, lt)];
    float4 bv = *(const float4*)&BtBl[swz(n, st)];
    float cc[4] = {cv.x, cv.y, cv.z, cv.w};
    float bb[4] = {bv.x, bv.y, bv.z, bv.w};
#pragma unroll
    for (int i2 = 0; i2 < 4; ++i2)
#pragma unroll
      for (int j2 = 0; j2 < 4; ++j2)
        acc[i2][j2] += cc[i2]*bb[j2];
  }
  __syncthreads();
#pragma unroll
  for (int j = 0; j < 4; ++j) {
    float4 gv = make_float4(acc[0][j], acc[1][j], acc[2][j], acc[3][j]);
    *(float4*)&CtGt[swz(st + j, lt)] = gv;
  }
  for (int i = tid; i < 16*DS; i += 256) {
    int ng = i % NG, l = i / NG;
    float4 bv = *(const float4*)&Bb[((size_t)seq*LL + l0 + l)*DS + 4*ng];
    *(float4*)&BtBl[l*DS + 4*ng] = bv;
  }
  __syncthreads();
  int w = tid >> 6, lane = tid & 63;
  if (w < NH) {
    int h = w;
    float dt_l = dtb[((size_t)seq*LL + l0 + lane)*NH + h];
    float Aval = -__expf(A_log[h]);
    float v = dt_l * Aval;
#pragma unroll
    for (int off = 1; off < 64; off <<= 1) {
      float t = __shfl_up(v, off, 64);
      if (lane >= off) v += t;
    }
    float acs_l = v;
    float m = __shfl(v, 31, 64);
    float acsLast = __shfl(v, 63, 64);
    float el = __expf(fminf(acs_l - m, 60.f));
    float fl = __expf(fminf(m - acs_l, 60.f));
    const float* xp = &xs[((size_t)seq*LL + l0 + lane)*DI + h*8];
    float4 x0 = *(const float4*)xp, x1 = *(const float4*)(xp + 4);
    float s1 = dt_l*fl;
    float* xe = &xde[(h*64 + lane)*8];
    *(float4*)xe     = make_float4(x0.x*s1, x0.y*s1, x0.z*s1, x0.w*s1);
    *(float4*)(xe+4) = make_float4(x1.x*s1, x1.y*s1, x1.z*s1, x1.w*s1);
    int lg = lane >> 2, lm = lane & 3;
    float ya[8] = {0,0,0,0,0,0,0,0};
#pragma unroll 4
    for (int s = 0; s < 64; ++s) {
      float g = CtGt[(s << 6) + ((((lg ^ ((s >> 2) & 15))) << 2) | lm)];
      g = (s <= lane) ? g : 0.f;
      const float* xr = &xde[(h*64 + s)*8];
      float4 a0 = *(const float4*)xr, a1 = *(const float4*)(xr + 4);
      ya[0] += g*a0.x; ya[1] += g*a0.y; ya[2] += g*a0.z; ya[3] += g*a0.w;
      ya[4] += g*a1.x; ya[5] += g*a1.y; ya[6] += g*a1.z; ya[7] += g*a1.w;
    }
    float* yp = &ybuf[((size_t)seq*LL + l0 + lane)*DI + h*8];
    *(float4*)yp     = make_float4(ya[0]*el, ya[1]*el, ya[2]*el, ya[3]*el);
    *(float4*)(yp+4) = make_float4(ya[4]*el, ya[5]*el, ya[6]*el, ya[7]*el);
    if (lane < DS) {
      float r2 = __expf(acsLast - m);
      float sa[8] = {0,0,0,0,0,0,0,0};
#pragma unroll 4
      for (int ll = 0; ll < 64; ++ll) {
        float b = BtBl[ll*DS + lane];
        const float* xr = &xde[(h*64 + ll)*8];
        float4 a0 = *(const float4*)xr, a1 = *(const float4*)(xr + 4);
        sa[0] += b*a0.x; sa[1] += b*a0.y; sa[2] += b*a0.z; sa[3] += b*a0.w;
        sa[4] += b*a1.x; sa[5] += b*a1.y; sa[6] += b*a1.z; sa[7] += b*a1.w;
      }
      float* sp2 = &states[(((size_t)seq*NH + h)*NCHK + cid)*(size_t)(8*DS) + lane*8];
      *(float4*)sp2     = make_float4(sa[0]*r2, sa[1]*r2, sa[2]*r2, sa[3]*r2);
      *(float4*)(sp2+4) = make_float4(sa[4]*r2, sa[5]*r2, sa[6]*r2, sa[7]*r2);
    }
    if (lane == 63) cdec[((size_t)seq*NH + h)*NCHK + cid] = __expf(acsLast);
    acsOut[((size_t)seq*NH + h)*LL + l0 + lane] = acs_l;
  }
}

// ---------------- inter-chunk scan ----------------
__global__ __launch_bounds__(512) void k_scan(float* __restrict__ st, const float* __restrict__ cd, int PN)
{
  int tid = threadIdx.x;
  size_t base = (size_t)blockIdx.x * NCHK * PN + tid;
  const float* c = cd + (size_t)blockIdx.x * NCHK;
  float carry = 0.f;
  for (int k = 0; k < NCHK; ++k) {
    size_t a = base + (size_t)k*PN;
    float s = st[a];
    st[a] = carry;
    carry = carry*c[k] + s;
  }
}

// ---------------- Yo + D*xs combine v2 ----------------
template<int DS, int NH>
__global__ __launch_bounds__(256) void k_ssd_yo(
    float* __restrict__ ybuf, const float* __restrict__ Cb,
    const float* __restrict__ prevSt, const float* __restrict__ acsG,
    const float* __restrict__ Dp, const float* __restrict__ xs)
{
  constexpr int DI = NH*8;
  constexpr int NG = DS/4;
  __shared__ __align__(16) float Ct2[DS*64];
  __shared__ __align__(16) float pvs[NH*DS*8];
  int tid = threadIdx.x;
  int cid = blockIdx.x & 63;
  int seq = blockIdx.x >> 6;
  int l0  = cid << 6;
  for (int i = tid; i < 16*DS; i += 256) {
    int ng = i % NG, l = i / NG;
    float4 cv = *(const float4*)&Cb[((size_t)seq*LL + l0 + l)*DS + 4*ng];
    Ct2[swz(4*ng+0, l)] = cv.x; Ct2[swz(4*ng+1, l)] = cv.y;
    Ct2[swz(4*ng+2, l)] = cv.z; Ct2[swz(4*ng+3, l)] = cv.w;
  }
  for (int i = tid; i < NH*DS*8; i += 256) {
    int h = i / (DS*8), r = i % (DS*8);
    pvs[i] = prevSt[(((size_t)seq*NH + h)*NCHK + cid)*(size_t)(DS*8) + r];
  }
  __syncthreads();
  int w = tid >> 6, lane = tid & 63;
  if (w < NH) {
    int h = w;
    float el = __expf(acsG[((size_t)seq*NH + h)*LL + l0 + lane]);
    float Dh = Dp[h];
    int lg = lane >> 2, lm = lane & 3;
    float acc[8] = {0,0,0,0,0,0,0,0};
#pragma unroll 4
    for (int n = 0; n < DS; ++n) {
      float c = Ct2[(n << 6) + ((((lg ^ ((n >> 2) & 15))) << 2) | lm)];
      const float* pr = &pvs[(h*DS + n)*8];
      float4 p0 = *(const float4*)pr, p1 = *(const float4*)(pr + 4);
      acc[0] += c*p0.x; acc[1] += c*p0.y; acc[2] += c*p0.z; acc[3] += c*p0.w;
      acc[4] += c*p1.x; acc[5] += c*p1.y; acc[6] += c*p1.z; acc[7] += c*p1.w;
    }
    size_t gi = ((size_t)seq*LL + l0 + lane)*DI + h*8;
    float4 y0 = *(const float4*)&ybuf[gi], y1 = *(const float4*)&ybuf[gi+4];
    float4 xv0 = *(const float4*)&xs[gi], xv1 = *(const float4*)&xs[gi+4];
    y0.x += el*acc[0] + Dh*xv0.x; y0.y += el*acc[1] + Dh*xv0.y;
    y0.z += el*acc[2] + Dh*xv0.z; y0.w += el*acc[3] + Dh*xv0.w;
    y1.x += el*acc[4] + Dh*xv1.x; y1.y += el*acc[5] + Dh*xv1.y;
    y1.z += el*acc[6] + Dh*xv1.z; y1.w += el*acc[7] + Dh*xv1.w;
    *(float4*)&ybuf[gi] = y0; *(float4*)&ybuf[gi+4] = y1;
  }
}

// ---------------- gating + RMSNorm + out-proj + optional residual ----------------
template<int DI, int DOUT>
__global__ __launch_bounds__(256) void k_gate(
    const float* __restrict__ ybuf, const float* __restrict__ zbuf,
    const float* __restrict__ rms_w, const float* __restrict__ out_w,
    float* __restrict__ dst, int resMode, const float* __restrict__ res,
    const float* __restrict__ skipPtr)
{
  __shared__ float ow[DOUT*DI];
  __shared__ float rw[DI];
  int tid = threadIdx.x;
  for (int i = tid; i < DOUT*DI; i += 256) ow[i] = out_w[i];
  for (int i = tid; i < DI; i += 256) rw[i] = rms_w[i];
  __syncthreads();
  size_t idx = (size_t)blockIdx.x*256 + tid;
  float y[DI];
  const float* yp = ybuf + idx*DI;
  const float* zp = zbuf + idx*DI;
  float ss = 0.f;
#pragma unroll
  for (int i = 0; i < DI; ++i) {
    float z = zp[i];
    float g = yp[i] * (z / (1.f + __expf(-z)));
    y[i] = g; ss += g*g;
  }
  float r = rsqrtf(ss*(1.f/DI) + 1e-5f);
#pragma unroll
  for (int i = 0; i < DI; ++i) y[i] *= r*rw[i];
  const float* rp = nullptr; float skip = 1.f;
  int seq = (int)(idx / LL), l = (int)(idx % LL);
  if (resMode == 1) rp = res + idx*DOUT;
  else if (resMode == 2) {
    int s = seq / B_, b = seq % B_;
    rp = res + ((size_t)b*LL + l)*CCH + s*DOUT;
    skip = skipPtr[0];
  }
  float* dp = dst + idx*DOUT;
#pragma unroll
  for (int o = 0; o < DOUT; ++o) {
    float acc = 0.f;
#pragma unroll
    for (int i = 0; i < DI; ++i) acc += y[i]*ow[o*DI + i];
    if (rp) acc += skip * rp[o];
    dp[o] = acc;
  }
}

// ---------------- LN over C of x[b,c,l] -> xn[b,l,c] ----------------
__global__ __launch_bounds__(256) void k_ln1(const float* __restrict__ x,
    const float* __restrict__ w, const float* __restrict__ bb, float* __restrict__ xn)
{
  __shared__ float tile[128*65];
  __shared__ float mu[64], rs[64];
  int tid = threadIdx.x;
  int b = blockIdx.x >> 6;
  int l0 = (blockIdx.x & 63) << 6;
  for (int i = tid; i < 8192; i += 256) {
    int l = i & 63, c = i >> 6;
    tile[c*65 + l] = x[((size_t)b*CCH + c)*LL + l0 + l];
  }
  __syncthreads();
  if (tid < 64) {
    float s = 0.f;
    for (int c = 0; c < CCH; ++c) s += tile[c*65 + tid];
    float m = s * (1.f/CCH);
    float v = 0.f;
    for (int c = 0; c < CCH; ++c) { float d = tile[c*65 + tid] - m; v += d*d; }
    mu[tid] = m; rs[tid] = rsqrtf(v*(1.f/CCH) + 1e-5f);
  }
  __syncthreads();
  for (int i = tid; i < 8192; i += 256) {
    int c = i & 127, l = i >> 7;
    xn[((size_t)b*LL + l0 + l)*CCH + c] = (tile[c*65 + l] - mu[l])*rs[l]*w[c] + bb[c];
  }
}

// ---------------- gm[seq,c] = mean_l ys[seq,l,c] ----------------
__global__ __launch_bounds__(256) void k_gm(const float* __restrict__ ys, float* __restrict__ gm)
{
  __shared__ float red[256];
  int tid = threadIdx.x;
  int seq = blockIdx.x;
  int c = tid & 15, lane = tid >> 4;
  float s = 0.f;
  for (int l = lane; l < LL; l += 16) s += ys[((size_t)seq*LL + l)*16 + c];
  red[tid] = s;
  __syncthreads();
  if (tid < 16) {
    float t = 0.f;
    for (int g = 0; g < 16; ++g) t += red[g*16 + tid];
    gm[(size_t)seq*16 + tid] = t * (1.f/LL);
  }
}

// ---------------- gmix ----------------
__global__ __launch_bounds__(256) void k_mix(const float* __restrict__ gm,
    const float* __restrict__ crossW, float* __restrict__ gmix)
{
  __shared__ float wsm[64];
  int tid = threadIdx.x;
  if (tid < 8) {
    float mx = -1e30f;
    for (int p = 0; p < 8; ++p) mx = fmaxf(mx, crossW[tid*8 + p]);
    float e[8]; float s = 0.f;
    for (int p = 0; p < 8; ++p) { e[p] = __expf(crossW[tid*8 + p] - mx); s += e[p]; }
    for (int p = 0; p < 8; ++p) wsm[tid*8 + p] = e[p] / s;
  }
  __syncthreads();
  for (int i = tid; i < 512; i += 256) {
    int c = i & 15; int bb = (i >> 4) & 3; int p = i >> 6;
    float acc = 0.f;
    for (int q = 0; q < 8; ++q) acc += gm[((size_t)(q*B_ + bb))*16 + c] * wsm[q*8 + p];
    gmix[((size_t)(p*B_ + bb))*16 + c] = acc;
  }
}

// ---------------- assemble ys+gmix, LN2, + (x + detok(gf2)) -> outb[b,c,l] ----------------
__global__ __launch_bounds__(256) void k_out2(const float* __restrict__ ys,
    const float* __restrict__ gmix, const float* __restrict__ w, const float* __restrict__ bb,
    const float* __restrict__ x, const float* __restrict__ gf2,
    const float* __restrict__ dw, const float* __restrict__ db,
    float* __restrict__ outb)
{
  __shared__ float tile[128*65];
  __shared__ float mu[64], rs[64];
  int tid = threadIdx.x;
  int b = blockIdx.x >> 6;
  int l0 = (blockIdx.x & 63) << 6;
  for (int i = tid; i < 8192; i += 256) {
    int c = i & 15; int l = (i >> 4) & 63; int s = i >> 10;
    int seq = s*B_ + b;
    tile[(s*16 + c)*65 + l] = ys[((size_t)seq*LL + l0 + l)*16 + c] + gmix[(size_t)seq*16 + c];
  }
  __syncthreads();
  if (tid < 64) {
    float sm = 0.f;
    for (int c = 0; c < 128; ++c) sm += tile[c*65 + tid];
    float m = sm * (1.f/128.f);
    float v = 0.f;
    for (int c = 0; c < 128; ++c) { float d = tile[c*65 + tid] - m; v += d*d; }
    mu[tid] = m; rs[tid] = rsqrtf(v*(1.f/128.f) + 1e-5f);
  }
  __syncthreads();
  int lfix = tid & 63;
  float g8[8];
  {
    const float* gp = gf2 + ((size_t)b*LL + l0 + lfix)*8;
#pragma unroll
    for (int k = 0; k < 8; ++k) g8[k] = gp[k];
  }
  for (int i = tid; i < 8192; i += 256) {
    int l = i & 63, c = i >> 6;
    size_t gi = ((size_t)b*CCH + c)*LL + l0 + l;
    float det = db[c];
#pragma unroll
    for (int k = 0; k < 8; ++k) det += g8[k]*dw[c*8 + k];
    outb[gi] = (tile[c*65 + l] - mu[l])*rs[l]*w[c] + bb[c] + x[gi] + det;
  }
}

// ---------------- fc1 v2: register-tiled GEMM ----------------
__global__ __launch_bounds__(256) void k_fc1(const float* __restrict__ src,
    const float* __restrict__ w, const float* __restrict__ bias, float* __restrict__ dst)
{
  constexpr int WP = 129;
  __shared__ float st[128*64];
  __shared__ float wt[64*WP];
  int tid = threadIdx.x;
  int blk = blockIdx.x;
  int ot = blk & 3;
  int lt = (blk >> 2) & 63;
  int b  = blk >> 8;
  int l0 = lt << 6, o0 = ot << 6;
  for (int i = tid; i < 8192; i += 256) {
    int l = i & 63, c = i >> 6;
    st[c*64 + l] = src[((size_t)b*CCH + c)*LL + l0 + l];
  }
  for (int i = tid; i < 8192; i += 256) {
    int c = i & 127, o = i >> 7;
    wt[o*WP + c] = w[(size_t)(o0 + o)*128 + c];
  }
  __syncthreads();
  int l4 = (tid & 15) << 2, o4 = (tid >> 4) << 2;
  float a0[4] = {}, a1[4] = {}, a2[4] = {}, a3[4] = {};
#pragma unroll 4
  for (int c = 0; c < 128; ++c) {
    float4 sv = *(float4*)&st[c*64 + l4];
    float w0 = wt[(o4+0)*WP + c];
    float w1 = wt[(o4+1)*WP + c];
    float w2 = wt[(o4+2)*WP + c];
    float w3 = wt[(o4+3)*WP + c];
    a0[0] += w0*sv.x; a0[1] += w0*sv.y; a0[2] += w0*sv.z; a0[3] += w0*sv.w;
    a1[0] += w1*sv.x; a1[1] += w1*sv.y; a1[2] += w1*sv.z; a1[3] += w1*sv.w;
    a2[0] += w2*sv.x; a2[1] += w2*sv.y; a2[2] += w2*sv.z; a2[3] += w2*sv.w;
    a3[0] += w3*sv.x; a3[1] += w3*sv.y; a3[2] += w3*sv.z; a3[3] += w3*sv.w;
  }
  float* rows[4] = {a0, a1, a2, a3};
#pragma unroll
  for (int j = 0; j < 4; ++j) {
    int o = o0 + o4 + j;
    float bi = bias[o];
    float* a = rows[j];
    *(float4*)&dst[((size_t)b*256 + o)*LL + l0 + l4] =
        make_float4(a[0]+bi, a[1]+bi, a[2]+bi, a[3]+bi);
  }
}

// ---------------- depthwise 3x3 + gelu, LDS-tiled ----------------
__global__ __launch_bounds__(256) void k_dw(const float* __restrict__ h1,
    const float* __restrict__ w, const float* __restrict__ bias, float* __restrict__ h2)
{
  __shared__ float tile[66*66];
  int tid = threadIdx.x;
  int blk = blockIdx.x;
  const float* base = h1 + (size_t)blk*LL;
  const float* wp = w + (blk & 255)*9;
  float bi = bias[blk & 255];
  for (int i = tid; i < 66*66; i += 256) {
    int r = i / 66, cc = i % 66;
    int gr = r - 1, gc = cc - 1;
    tile[i] = (gr >= 0 && gr < HH && gc >= 0 && gc < WW) ? base[gr*WW + gc] : 0.f;
  }
  float w00 = wp[0], w01 = wp[1], w02 = wp[2];
  float w10 = wp[3], w11 = wp[4], w12 = wp[5];
  float w20 = wp[6], w21 = wp[7], w22 = wp[8];
  __syncthreads();
  float* outp = h2 + (size_t)blk*LL;
#pragma unroll
  for (int k = 0; k < 16; ++k) {
    int j = tid + k*256;
    int row = j >> 6, col = j & 63;
    const float* t0 = &tile[row*66 + col];
    float acc = t0[0]*w00  + t0[1]*w01  + t0[2]*w02
              + t0[66]*w10 + t0[67]*w11 + t0[68]*w12
              + t0[132]*w20 + t0[133]*w21 + t0[134]*w22;
    float v = acc + bi;
    float u = 0.7978845608028654f*(v + 0.044715f*v*v*v);
    float e = __expf(2.f*u);
    float th = 1.f - 2.f/(e + 1.f);
    outp[j] = 0.5f*v*(1.f + th);
  }
}

// ---------------- fc2 v2: register-tiled GEMM ----------------
__global__ __launch_bounds__(256) void k_fc2(const float* __restrict__ h2,
    const float* __restrict__ w, const float* __restrict__ bias,
    const float* __restrict__ resid, float* __restrict__ dst)
{
  constexpr int WP = 260;
  __shared__ float st[128*64];
  __shared__ float wt[32*WP];
  int tid = threadIdx.x;
  int blk = blockIdx.x;
  int ct = blk & 3;
  int lt = (blk >> 2) & 63;
  int b  = blk >> 8;
  int l0 = lt << 6, c0 = ct << 5;
  for (int i = tid; i < 32*256; i += 256) {
    int o = i & 255, c = i >> 8;
    wt[c*WP + o] = w[(size_t)(c0 + c)*256 + o];
  }
  int l4 = (tid & 15) << 2, c2 = (tid >> 4) << 1;
  float a0[4] = {}, a1[4] = {};
  for (int ko = 0; ko < 256; ko += 128) {
    __syncthreads();
    for (int i = tid; i < 8192; i += 256) {
      int l = i & 63, o = i >> 6;
      st[o*64 + l] = h2[((size_t)b*256 + ko + o)*LL + l0 + l];
    }
    __syncthreads();
#pragma unroll 4
    for (int o = 0; o < 128; ++o) {
      float4 sv = *(float4*)&st[o*64 + l4];
      float w0 = wt[(c2+0)*WP + ko + o];
      float w1 = wt[(c2+1)*WP + ko + o];
      a0[0] += w0*sv.x; a0[1] += w0*sv.y; a0[2] += w0*sv.z; a0[3] += w0*sv.w;
      a1[0] += w1*sv.x; a1[1] += w1*sv.y; a1[2] += w1*sv.z; a1[3] += w1*sv.w;
    }
  }
  float* rows[2] = {a0, a1};
#pragma unroll
  for (int j = 0; j < 2; ++j) {
    int c = c0 + c2 + j;
    float bi = bias[c];
    size_t gi = ((size_t)b*CCH + c)*LL + l0 + l4;
    float4 rv = *(const float4*)&resid[gi];
    float* a = rows[j];
    *(float4*)&dst[gi] = make_float4(a[0]+bi+rv.x, a[1]+bi+rv.y, a[2]+bi+rv.z, a[3]+bi+rv.w);
  }
}

extern "C" void kernel_launch(void* const* d_in, const int* in_sizes, int n_in,
                              void* d_out, int out_size, void* d_ws, size_t ws_size,
                              hipStream_t stream) {
  (void)in_sizes; (void)n_in; (void)out_size; (void)ws_size;
  const float* x        = (const float*)d_in[0];
  const float* tok_w    = (const float*)d_in[1];
  const float* tok_b    = (const float*)d_in[2];
  const float* detok_w  = (const float*)d_in[3];
  const float* detok_b  = (const float*)d_in[4];
  const float* sm_in_w  = (const float*)d_in[5];
  const float* sm_in_b  = (const float*)d_in[6];
  const float* sm_conv_w= (const float*)d_in[7];
  const float* sm_conv_b= (const float*)d_in[8];
  const float* sm_A_log = (const float*)d_in[9];
  const float* sm_D     = (const float*)d_in[10];
  const float* sm_dt_b  = (const float*)d_in[11];
  const float* sm_rms_w = (const float*)d_in[12];
  const float* sm_out_w = (const float*)d_in[13];
  const float* cm_in_w  = (const float*)d_in[14];
  const float* cm_in_b  = (const float*)d_in[15];
  const float* cm_conv_w= (const float*)d_in[16];
  const float* cm_conv_b= (const float*)d_in[17];
  const float* cm_A_log = (const float*)d_in[18];
  const float* cm_D     = (const float*)d_in[19];
  const float* cm_dt_b  = (const float*)d_in[20];
  const float* cm_rms_w = (const float*)d_in[21];
  const float* cm_out_w = (const float*)d_in[22];
  const float* cross_W  = (const float*)d_in[23];
  const float* n1w      = (const float*)d_in[24];
  const float* n1b      = (const float*)d_in[25];
  const float* n2w      = (const float*)d_in[26];
  const float* n2b      = (const float*)d_in[27];
  const float* fc1w     = (const float*)d_in[28];
  const float* fc1b     = (const float*)d_in[29];
  const float* dww      = (const float*)d_in[30];
  const float* dwb      = (const float*)d_in[31];
  const float* fc2w     = (const float*)d_in[32];
  const float* fc2b     = (const float*)d_in[33];
  const float* skp      = (const float*)d_in[34];
  float* ws  = (float*)d_ws;
  float* out = (float*)d_out;

  const size_t SGF0 = 0;
  const size_t SOUTn= 131072;
  const size_t XN   = 2097152;
  const size_t YS   = 4194304;
  const size_t OUTB = 6291456;
  const size_t GM   = 8388608;
  const size_t GMIX = 8389120;
  const size_t SCR  = 8389632;
  const size_t CZ   = SCR;
  const size_t CXS  = CZ   + 4194304;
  const size_t CCF  = CXS  + 4194304;
  const size_t CACS = CCF  + 8388608;
  const size_t CST  = CACS + 2097152;
  const size_t CCD  = CST  + 4194304;
  const size_t CY   = CCD  + 8192;
  const size_t XB   = CY   + 4194304;
  const size_t SZ   = SCR;
  const size_t SDT  = SZ  + 262144;
  const size_t SXS  = SDT + 32768;
  const size_t SB   = SXS + 262144;
  const size_t SC   = SB  + 262144;
  const size_t SACS = SC  + 262144;
  const size_t SST  = SACS + 32768;
  const size_t SCD  = SST + 65536;
  const size_t SY   = SCD + 512;
  const size_t H1 = SCR;
  const size_t H2 = SCR + 4194304;

  // ===== seed path =====
  k_seedtok<<<64, 256, 0, stream>>>(x, tok_w, tok_b, ws + SGF0);
  k_inproj<8,16,16,2><<<B_*64, 256, 0, stream>>>(ws + SGF0, 0, sm_in_w, sm_in_b, sm_conv_w,
      sm_conv_b, sm_dt_b, ws + SZ, ws + SDT, ws + SXS, ws + SB, ws + SC);
  k_ssd1<16,2><<<B_*NCHK, 256, 0, stream>>>(ws + SXS, ws + SDT, ws + SB, ws + SC,
      sm_A_log, ws + SY, ws + SST, ws + SCD, ws + SACS);
  k_scan<<<B_*2, 128, 0, stream>>>(ws + SST, ws + SCD, 128);
  k_ssd_yo<16,2><<<B_*NCHK, 256, 0, stream>>>(ws + SY, ws + SC, ws + SST, ws + SACS, sm_D, ws + SXS);
  k_gate<16,8><<<B_*LL/256, 256, 0, stream>>>(ws + SY, ws + SZ, sm_rms_w, sm_out_w,
      ws + SOUTn, 1, ws + SGF0, skp);

  // ===== norm1 =====
  k_ln1<<<B_*64, 256, 0, stream>>>(x, n1w, n1b, ws + XN);

  // ===== cascade layer 0 (fused inproj+ssd intra-chunk) =====
  k_inssd<<<32*NCHK, 256, 0, stream>>>(ws + XN, 1, cm_in_w, cm_in_b, cm_conv_w,
      cm_conv_b, cm_dt_b, cm_A_log, ws + CZ, ws + CXS, ws + CCF,
      ws + CY, ws + CST, ws + CCD, ws + CACS);
  k_scan<<<32*4, 512, 0, stream>>>(ws + CST, ws + CCD, 512);
  k_ssd_yo<64,4><<<32*NCHK, 256, 0, stream>>>(ws + CY, ws + CCF, ws + CST, ws + CACS, cm_D, ws + CXS);
  k_gate<32,16><<<32*LL/256, 256, 0, stream>>>(ws + CY, ws + CZ, cm_rms_w, cm_out_w,
      ws + XB, 0, nullptr, skp);

  // ===== cascade layer 1 =====
  k_inssd<<<32*NCHK, 256, 0, stream>>>(ws + XB, 0, cm_in_w + 3136, cm_in_b + 196,
      cm_conv_w + 480, cm_conv_b + 160, cm_dt_b + 4, cm_A_log + 4, ws + CZ, ws + CXS, ws + CCF,
      ws + CY, ws + CST, ws + CCD, ws + CACS);
  k_scan<<<32*4, 512, 0, stream>>>(ws + CST, ws + CCD, 512);
  k_ssd_yo<64,4><<<32*NCHK, 256, 0, stream>>>(ws + CY, ws + CCF, ws + CST, ws + CACS, cm_D + 4, ws + CXS);
  k_gate<32,16><<<32*LL/256, 256, 0, stream>>>(ws + CY, ws + CZ, cm_rms_w + 32, cm_out_w + 512,
      ws + YS, 2, ws + XN, skp);

  // ===== cross mix + norm2 + (fused detok seed) =====
  k_gm<<<32, 256, 0, stream>>>(ws + YS, ws + GM);
  k_mix<<<1, 256, 0, stream>>>(ws + GM, cross_W, ws + GMIX);
  k_out2<<<B_*64, 256, 0, stream>>>(ws + YS, ws + GMIX, n2w, n2b,
      x, ws + SOUTn, detok_w, detok_b, ws + OUTB);

  // ===== FFN =====
  k_fc1<<<B_*64*4, 256, 0, stream>>>(ws + OUTB, fc1w, fc1b, ws + H1);
  k_dw<<<B_*256, 256, 0, stream>>>(ws + H1, dww, dwb, ws + H2);
  k_fc2<<<B_*64*4, 256, 0, stream>>>(ws + H2, fc2w, fc2b, ws + OUTB, out);
}

// Round 9
// 587.697 us; speedup vs baseline: 1.1994x; 1.1994x over previous
//
#include <hip/hip_runtime.h>
#include <math.h>

#define B_ 4
#define CCH 128
#define HH 64
#define WW 64
#define LL 4096
#define NCHK 64

__device__ __forceinline__ float siluf(float x) { return x / (1.f + __expf(-x)); }
__device__ __forceinline__ float softplusf(float x) { return (x > 20.f) ? x : log1pf(__expf(x)); }
// swizzled [n][l] layout, pitch 64: phys = n*64 + (((l>>2) ^ ((n>>2)&15))<<2 | (l&3))
__device__ __forceinline__ int swz(int n, int l) {
  return (n << 6) + ((((l >> 2) ^ ((n >> 2) & 15)) << 2) | (l & 3));
}

// ---------------- seed tokenize v2: 256 blocks, LDS-tiled ----------------
__global__ __launch_bounds__(256) void k_seedtok(const float* __restrict__ x,
    const float* __restrict__ w, const float* __restrict__ bias, float* __restrict__ gf)
{
  __shared__ float tile[128*65];
  __shared__ float sw[8*128];
  __shared__ float bl[8];
  int tid = threadIdx.x;
  int b = blockIdx.x >> 6;
  int l0 = (blockIdx.x & 63) << 6;
  for (int i = tid; i < 1024; i += 256) sw[i] = w[i];
  if (tid < 8) bl[tid] = bias[tid];
  for (int i = tid; i < 8192; i += 256) {
    int l = i & 63, c = i >> 6;
    tile[c*65 + l] = x[((size_t)b*CCH + c)*LL + l0 + l];
  }
  __syncthreads();
  int l = tid & 63, q = tid >> 6;
  float a0 = bl[2*q], a1 = bl[2*q+1];
  const float* w0 = &sw[(2*q)*128];
  const float* w1 = &sw[(2*q+1)*128];
#pragma unroll 4
  for (int c = 0; c < 128; ++c) {
    float xv = tile[c*65 + l];
    a0 += xv * w0[c];
    a1 += xv * w1[c];
  }
  *(float2*)&gf[((size_t)b*LL + l0 + l)*8 + 2*q] = make_float2(a0, a1);
}

// ---------------- fused in-projection + conv3 + silu + softplus(dt) v4 (seed path) ----------------
template<int DIN, int NZ, int NDS, int NDT>
__global__ __launch_bounds__(256) void k_inproj(
    const float* __restrict__ src, int srcMode,
    const float* __restrict__ in_w, const float* __restrict__ in_b,
    const float* __restrict__ conv_w, const float* __restrict__ conv_b,
    const float* __restrict__ dt_bias,
    float* __restrict__ zb, float* __restrict__ dtb,
    float* __restrict__ xsb, float* __restrict__ Bb, float* __restrict__ Cb)
{
  constexpr int NXBC = NZ + 2*NDS;
  constexpr int NTOT = 2*NZ + 2*NDS + NDT;
  constexpr int NZQ  = NZ/4;
  constexpr int NDSQ = NDS/4;
  constexpr int XP   = DIN + 1;
  __shared__ float xt[66*XP];
  __shared__ float wl[NTOT*DIN];
  __shared__ float cwl[NXBC*3];
  __shared__ float cbl[NXBC];
  __shared__ float ibl[NTOT];
  __shared__ float dts[64*NDT];
  __shared__ float hp[NXBC*2];
  int tid = threadIdx.x;
  int seq = blockIdx.x >> 6;
  int l0  = (blockIdx.x & 63) << 6;
  for (int i = tid; i < NTOT*DIN; i += 256) wl[i] = in_w[i];
  for (int i = tid; i < NXBC*3; i += 256) cwl[i] = conv_w[i];
  for (int i = tid; i < NXBC; i += 256) cbl[i] = conv_b[i];
  for (int i = tid; i < NTOT; i += 256) ibl[i] = in_b[i];
  const float* sp; int sstr;
  if (srcMode == 0) { sp = src + (size_t)seq*LL*DIN; sstr = DIN; }
  else { sp = src + (size_t)(seq & 3)*LL*CCH + (seq >> 2)*16; sstr = CCH; }
  for (int i = tid; i < 66*DIN; i += 256) {
    int r = i / DIN, d = i % DIN;
    int l = l0 - 2 + r;
    xt[r*XP + d] = (l >= 0) ? sp[(size_t)l*sstr + d] : 0.f;
  }
  __syncthreads();
  for (int i = tid; i < 2*NXBC; i += 256) {
    int t = i & 1, ch = i >> 1;
    const float* wr = &wl[(NZ + ch)*DIN];
    const float* xp = &xt[t*XP];
    float acc = 0.f;
#pragma unroll
    for (int d = 0; d < DIN; ++d) acc += xp[d]*wr[d];
    hp[ch*2 + t] = acc;
  }
  __syncthreads();
  int l = tid & 63, w4 = tid >> 6;
  float xr2[DIN];
#pragma unroll
  for (int d = 0; d < DIN; ++d) xr2[d] = xt[(l+2)*XP + d];
  size_t gl = (size_t)seq*LL + l0 + l;
  int tok = l0 + l;
  float v0ok = (tok >= 2) ? 1.f : 0.f;
  float v1ok = (tok >= 1) ? 1.f : 0.f;
  {
    float zv[NZQ];
#pragma unroll
    for (int j = 0; j < NZQ; ++j) {
      int row = w4*NZQ + j;
      const float* wr = &wl[row*DIN];
      float acc = ibl[row];
#pragma unroll
      for (int d = 0; d < DIN; ++d) acc += xr2[d]*wr[d];
      zv[j] = acc;
    }
#pragma unroll
    for (int g = 0; g < NZQ/4; ++g)
      *(float4*)&zb[gl*NZ + w4*NZQ + 4*g] = make_float4(zv[4*g], zv[4*g+1], zv[4*g+2], zv[4*g+3]);
  }
  if (w4 < NDT) {
    int row = NTOT - NDT + w4;
    const float* wr = &wl[row*DIN];
    float acc = ibl[row] + dt_bias[w4];
#pragma unroll
    for (int d = 0; d < DIN; ++d) acc += xr2[d]*wr[d];
    dts[l*NDT + w4] = softplusf(acc);
  }
  auto convch = [&](int ch) -> float {
    int row = NZ + ch;
    const float* wr = &wl[row*DIN];
    float pm = 0.f;
#pragma unroll
    for (int d = 0; d < DIN; ++d) pm += xr2[d]*wr[d];
    float m1 = __shfl_up(pm, 1, 64);
    float m2 = __shfl_up(pm, 2, 64);
    float h0 = hp[ch*2 + 0], h1 = hp[ch*2 + 1];
    if (l == 0) m1 = h1;
    m2 = (l == 0) ? h0 : ((l == 1) ? h1 : m2);
    float ib = ibl[row];
    float conv = cbl[ch] + (m2+ib)*v0ok*cwl[ch*3+0] + (m1+ib)*v1ok*cwl[ch*3+1] + (pm+ib)*cwl[ch*3+2];
    return siluf(conv);
  };
  {
    float xv[NZQ];
#pragma unroll
    for (int j = 0; j < NZQ; ++j) xv[j] = convch(w4*NZQ + j);
#pragma unroll
    for (int g = 0; g < NZQ/4; ++g)
      *(float4*)&xsb[gl*NZ + w4*NZQ + 4*g] = make_float4(xv[4*g], xv[4*g+1], xv[4*g+2], xv[4*g+3]);
  }
  {
    float bv[NDSQ];
#pragma unroll
    for (int j = 0; j < NDSQ; ++j) bv[j] = convch(NZ + w4*NDSQ + j);
#pragma unroll
    for (int g = 0; g < NDSQ/4; ++g)
      *(float4*)&Bb[gl*NDS + w4*NDSQ + 4*g] = make_float4(bv[4*g], bv[4*g+1], bv[4*g+2], bv[4*g+3]);
  }
  {
    float cv[NDSQ];
#pragma unroll
    for (int j = 0; j < NDSQ; ++j) cv[j] = convch(NZ + NDS + w4*NDSQ + j);
#pragma unroll
    for (int g = 0; g < NDSQ/4; ++g)
      *(float4*)&Cb[gl*NDS + w4*NDSQ + 4*g] = make_float4(cv[4*g], cv[4*g+1], cv[4*g+2], cv[4*g+3]);
  }
  __syncthreads();
  if (tid < 64) {
    if constexpr (NDT == 4) {
      *(float4*)&dtb[((size_t)seq*LL + l0 + tid)*4] =
          make_float4(dts[tid*4], dts[tid*4+1], dts[tid*4+2], dts[tid*4+3]);
    } else {
      *(float2*)&dtb[((size_t)seq*LL + l0 + tid)*NDT] = make_float2(dts[tid*NDT], dts[tid*NDT+1]);
    }
  }
}

// ======= FUSED inproj + intra-chunk SSD v2 (cascade: DIN=16,NZ=32,NDS=64,NDT=4,NH=4) =======
// Fixes vs v1: LDS 50.1KB -> 3 blocks/CU (xt staging dropped, per-lane direct global row loads);
// B back in swz layout (float4 Gram reads); states reads Bt[swz(lane,ll)] (8-way, acceptable).
__global__ __launch_bounds__(256, 3) void k_inssd(
    const float* __restrict__ src, int srcMode,
    const float* __restrict__ in_w, const float* __restrict__ in_b,
    const float* __restrict__ conv_w, const float* __restrict__ conv_b,
    const float* __restrict__ dt_bias, const float* __restrict__ A_log,
    float* __restrict__ zb, float* __restrict__ xsb, float* __restrict__ Cb,
    float* __restrict__ ybuf, float* __restrict__ states,
    float* __restrict__ cdec, float* __restrict__ acsOut)
{
  const int DIN = 16, NZ = 32, NDS = 64, DI = 32;
  const int NXBC = 160, NTOT = 196;
  __shared__ float sm[12518];            // 50072 B -> 3 blocks/CU
  float* Bt  = sm;                       // 4096: B swz(n,l)
  float* Ct  = sm + 4096;                // 4096: C swz(n,l); later Gt swz(s,l)
  float* U   = sm + 8192;                // union: phase A staging / phase B xde
  float* wl  = U;                        // 3136
  float* cwl = U + 3136;                 // 480
  float* cbl = U + 3616;                 // 160
  float* ibl = U + 3776;                 // 196
  float* hp  = U + 3972;                 // 320
  float* ha  = U + 4292;                 // 34 (2 halo rows, pitch 17)
  float* xde = U;                        // phase B: 4*64*8 = 2048
  int tid = threadIdx.x;
  int cid = blockIdx.x & 63;
  int seq = blockIdx.x >> 6;
  int l0  = cid << 6;
  int lane = tid & 63, w = tid >> 6;     // lane = token, w = wave = head
  const float* sp; int sstr;
  if (srcMode == 0) { sp = src + (size_t)seq*LL*DIN; sstr = DIN; }
  else { sp = src + (size_t)(seq & 3)*LL*CCH + (seq >> 2)*16; sstr = CCH; }
  // early: per-lane direct global load of input row (token l0+lane)
  float xr2[DIN];
  {
    const float* p = sp + (size_t)(l0 + lane)*sstr;
#pragma unroll
    for (int k = 0; k < 4; ++k) {
      float4 v = *(const float4*)(p + 4*k);
      xr2[4*k+0]=v.x; xr2[4*k+1]=v.y; xr2[4*k+2]=v.z; xr2[4*k+3]=v.w;
    }
  }
  for (int i = tid; i < NTOT*DIN; i += 256) wl[i] = in_w[i];
  for (int i = tid; i < NXBC*3; i += 256) cwl[i] = conv_w[i];
  for (int i = tid; i < NXBC; i += 256) cbl[i] = conv_b[i];
  for (int i = tid; i < NTOT; i += 256) ibl[i] = in_b[i];
  if (tid < 32) {
    int t = tid >> 4, d = tid & 15;
    int tok = l0 - 2 + t;
    ha[t*17 + d] = (tok >= 0) ? sp[(size_t)tok*sstr + d] : 0.f;
  }
  __syncthreads();
  // halo projections for all conv channels at tokens l0-2 (t=0), l0-1 (t=1)
  for (int i = tid; i < 2*NXBC; i += 256) {
    int t = i & 1, ch = i >> 1;
    const float* wr = &wl[(NZ + ch)*DIN];
    const float* hr = &ha[t*17];
    float acc = 0.f;
#pragma unroll
    for (int d = 0; d < DIN; ++d) acc += hr[d]*wr[d];
    hp[ch*2 + t] = acc;
  }
  __syncthreads();
  size_t gl = (size_t)seq*LL + l0 + lane;
  int tok = l0 + lane;
  float v0ok = (tok >= 2) ? 1.f : 0.f;
  float v1ok = (tok >= 1) ? 1.f : 0.f;
  // ---- z quarter ----
  {
    float zv[8];
#pragma unroll
    for (int j = 0; j < 8; ++j) {
      int row = w*8 + j;
      const float* wr = &wl[row*DIN];
      float acc = ibl[row];
#pragma unroll
      for (int d = 0; d < DIN; ++d) acc += xr2[d]*wr[d];
      zv[j] = acc;
    }
    *(float4*)&zb[gl*NZ + w*8 + 0] = make_float4(zv[0], zv[1], zv[2], zv[3]);
    *(float4*)&zb[gl*NZ + w*8 + 4] = make_float4(zv[4], zv[5], zv[6], zv[7]);
  }
  // ---- dt head w (register) ----
  float dtv;
  {
    int row = NTOT - 4 + w;
    const float* wr = &wl[row*DIN];
    float acc = ibl[row] + dt_bias[w];
#pragma unroll
    for (int d = 0; d < DIN; ++d) acc += xr2[d]*wr[d];
    dtv = softplusf(acc);
  }
  auto convch = [&](int ch) -> float {
    int row = NZ + ch;
    const float* wr = &wl[row*DIN];
    float pm = 0.f;
#pragma unroll
    for (int d = 0; d < DIN; ++d) pm += xr2[d]*wr[d];
    float m1 = __shfl_up(pm, 1, 64);
    float m2 = __shfl_up(pm, 2, 64);
    float h0 = hp[ch*2 + 0], h1 = hp[ch*2 + 1];
    if (lane == 0) m1 = h1;
    m2 = (lane == 0) ? h0 : ((lane == 1) ? h1 : m2);
    float ib = ibl[row];
    float conv = cbl[ch] + (m2+ib)*v0ok*cwl[ch*3+0] + (m1+ib)*v1ok*cwl[ch*3+1] + (pm+ib)*cwl[ch*3+2];
    return siluf(conv);
  };
  // ---- xs head w: regs + global ----
  float xv[8];
#pragma unroll
  for (int j = 0; j < 8; ++j) xv[j] = convch(w*8 + j);
  *(float4*)&xsb[gl*DI + w*8 + 0] = make_float4(xv[0], xv[1], xv[2], xv[3]);
  *(float4*)&xsb[gl*DI + w*8 + 4] = make_float4(xv[4], xv[5], xv[6], xv[7]);
  // ---- B quarter -> swz LDS only ----
#pragma unroll
  for (int j = 0; j < 16; ++j) {
    int n = w*16 + j;
    Bt[swz(n, lane)] = convch(NZ + n);
  }
  // ---- C quarter -> swz LDS + global ----
  {
    float cv[16];
#pragma unroll
    for (int j = 0; j < 16; ++j) {
      int n = w*16 + j;
      cv[j] = convch(NZ + NDS + n);
      Ct[swz(n, lane)] = cv[j];
    }
#pragma unroll
    for (int g = 0; g < 4; ++g)
      *(float4*)&Cb[gl*NDS + w*16 + 4*g] = make_float4(cv[4*g], cv[4*g+1], cv[4*g+2], cv[4*g+3]);
  }
  __syncthreads();   // sync1: phase-A LDS reads done; Bt/Ct staged; U free for xde
  // ---- acs scan + xde write ----
  float Aval = -__expf(A_log[w]);
  float v = dtv * Aval;
#pragma unroll
  for (int off = 1; off < 64; off <<= 1) {
    float t = __shfl_up(v, off, 64);
    if (lane >= off) v += t;
  }
  float acs_l = v;
  float m = __shfl(v, 31, 64);
  float acsLast = __shfl(v, 63, 64);
  float el = __expf(fminf(acs_l - m, 60.f));
  float fl = __expf(fminf(m - acs_l, 60.f));
  {
    float s1 = dtv*fl;
    float* xe = &xde[(w*64 + lane)*8];
    *(float4*)xe     = make_float4(xv[0]*s1, xv[1]*s1, xv[2]*s1, xv[3]*s1);
    *(float4*)(xe+4) = make_float4(xv[4]*s1, xv[5]*s1, xv[6]*s1, xv[7]*s1);
  }
  // ---- Gram G = C.B^T (4l x 4s per thread), float4 swz reads ----
  int lt = (tid >> 4) << 2, st = (tid & 15) << 2;
  float acc[4][4] = {};
#pragma unroll 4
  for (int n = 0; n < 64; ++n) {
    float4 cvv = *(const float4*)&Ct[swz(n, lt)];
    float4 bvv = *(const float4*)&Bt[swz(n, st)];
    float cc[4] = {cvv.x, cvv.y, cvv.z, cvv.w};
    float bb[4] = {bvv.x, bvv.y, bvv.z, bvv.w};
#pragma unroll
    for (int i2 = 0; i2 < 4; ++i2)
#pragma unroll
      for (int j2 = 0; j2 < 4; ++j2)
        acc[i2][j2] += cc[i2]*bb[j2];
  }
  __syncthreads();   // sync2: Gram reads of Ct done
#pragma unroll
  for (int j = 0; j < 4; ++j) {
    *(float4*)&Ct[swz(st + j, lt)] = make_float4(acc[0][j], acc[1][j], acc[2][j], acc[3][j]);
  }
  __syncthreads();   // sync3: Gt complete
  // ---- per-head Yd ----
  int lg = lane >> 2, lm = lane & 3;
  float ya[8] = {0,0,0,0,0,0,0,0};
#pragma unroll 4
  for (int s = 0; s < 64; ++s) {
    float g = Ct[(s << 6) + (((lg ^ ((s >> 2) & 15))) << 2 | lm)];
    g = (s <= lane) ? g : 0.f;
    const float* xr = &xde[(w*64 + s)*8];
    float4 a0 = *(const float4*)xr, a1 = *(const float4*)(xr + 4);
    ya[0] += g*a0.x; ya[1] += g*a0.y; ya[2] += g*a0.z; ya[3] += g*a0.w;
    ya[4] += g*a1.x; ya[5] += g*a1.y; ya[6] += g*a1.z; ya[7] += g*a1.w;
  }
  float* yp = &ybuf[gl*DI + w*8];
  *(float4*)yp     = make_float4(ya[0]*el, ya[1]*el, ya[2]*el, ya[3]*el);
  *(float4*)(yp+4) = make_float4(ya[4]*el, ya[5]*el, ya[6]*el, ya[7]*el);
  // ---- states (lane = n) ----
  {
    float r2 = __expf(acsLast - m);
    float sa[8] = {0,0,0,0,0,0,0,0};
#pragma unroll 4
    for (int ll = 0; ll < 64; ++ll) {
      float b = Bt[swz(lane, ll)];
      const float* xr = &xde[(w*64 + ll)*8];
      float4 a0 = *(const float4*)xr, a1 = *(const float4*)(xr + 4);
      sa[0] += b*a0.x; sa[1] += b*a0.y; sa[2] += b*a0.z; sa[3] += b*a0.w;
      sa[4] += b*a1.x; sa[5] += b*a1.y; sa[6] += b*a1.z; sa[7] += b*a1.w;
    }
    float* sp2 = &states[(((size_t)seq*4 + w)*NCHK + cid)*(size_t)(8*NDS) + lane*8];
    *(float4*)sp2     = make_float4(sa[0]*r2, sa[1]*r2, sa[2]*r2, sa[3]*r2);
    *(float4*)(sp2+4) = make_float4(sa[4]*r2, sa[5]*r2, sa[6]*r2, sa[7]*r2);
  }
  if (lane == 63) cdec[((size_t)seq*4 + w)*NCHK + cid] = __expf(acsLast);
  acsOut[((size_t)seq*4 + w)*LL + l0 + lane] = acs_l;
}

// ---------------- SSD intra-chunk v3 (seed path) ----------------
template<int DS, int NH>
__global__ __launch_bounds__(256) void k_ssd1(
    const float* __restrict__ xs, const float* __restrict__ dtb,
    const float* __restrict__ Bb, const float* __restrict__ Cb,
    const float* __restrict__ A_log,
    float* __restrict__ ybuf, float* __restrict__ states,
    float* __restrict__ cdec, float* __restrict__ acsOut)
{
  constexpr int DI = NH*8;
  constexpr int NG = DS/4;
  __shared__ __align__(16) float BtBl[DS*64];
  __shared__ __align__(16) float CtGt[64*64];
  __shared__ __align__(16) float xde[NH*64*8];
  int tid = threadIdx.x;
  int cid = blockIdx.x & 63;
  int seq = blockIdx.x >> 6;
  int l0  = cid << 6;
  for (int i = tid; i < 16*DS; i += 256) {
    int ng = i % NG, l = i / NG;
    size_t g = ((size_t)seq*LL + l0 + l)*DS + 4*ng;
    float4 bv = *(const float4*)&Bb[g];
    float4 cv = *(const float4*)&Cb[g];
    BtBl[swz(4*ng+0, l)] = bv.x; BtBl[swz(4*ng+1, l)] = bv.y;
    BtBl[swz(4*ng+2, l)] = bv.z; BtBl[swz(4*ng+3, l)] = bv.w;
    CtGt[swz(4*ng+0, l)] = cv.x; CtGt[swz(4*ng+1, l)] = cv.y;
    CtGt[swz(4*ng+2, l)] = cv.z; CtGt[swz(4*ng+3, l)] = cv.w;
  }
  __syncthreads();
  int lt = (tid >> 4) << 2, st = (tid & 15) << 2;
  float acc[4][4] = {};
#pragma unroll 4
  for (int n = 0; n < DS; ++n) {
    float4 cv = *(const float4*)&CtGt[swz(n, lt)];
    float4 bv = *(const float4*)&BtBl[swz(n, st)];
    float cc[4] = {cv.x, cv.y, cv.z, cv.w};
    float bb[4] = {bv.x, bv.y, bv.z, bv.w};
#pragma unroll
    for (int i2 = 0; i2 < 4; ++i2)
#pragma unroll
      for (int j2 = 0; j2 < 4; ++j2)
        acc[i2][j2] += cc[i2]*bb[j2];
  }
  __syncthreads();
#pragma unroll
  for (int j = 0; j < 4; ++j) {
    float4 gv = make_float4(acc[0][j], acc[1][j], acc[2][j], acc[3][j]);
    *(float4*)&CtGt[swz(st + j, lt)] = gv;
  }
  for (int i = tid; i < 16*DS; i += 256) {
    int ng = i % NG, l = i / NG;
    float4 bv = *(const float4*)&Bb[((size_t)seq*LL + l0 + l)*DS + 4*ng];
    *(float4*)&BtBl[l*DS + 4*ng] = bv;
  }
  __syncthreads();
  int w = tid >> 6, lane = tid & 63;
  if (w < NH) {
    int h = w;
    float dt_l = dtb[((size_t)seq*LL + l0 + lane)*NH + h];
    float Aval = -__expf(A_log[h]);
    float v = dt_l * Aval;
#pragma unroll
    for (int off = 1; off < 64; off <<= 1) {
      float t = __shfl_up(v, off, 64);
      if (lane >= off) v += t;
    }
    float acs_l = v;
    float m = __shfl(v, 31, 64);
    float acsLast = __shfl(v, 63, 64);
    float el = __expf(fminf(acs_l - m, 60.f));
    float fl = __expf(fminf(m - acs_l, 60.f));
    const float* xp = &xs[((size_t)seq*LL + l0 + lane)*DI + h*8];
    float4 x0 = *(const float4*)xp, x1 = *(const float4*)(xp + 4);
    float s1 = dt_l*fl;
    float* xe = &xde[(h*64 + lane)*8];
    *(float4*)xe     = make_float4(x0.x*s1, x0.y*s1, x0.z*s1, x0.w*s1);
    *(float4*)(xe+4) = make_float4(x1.x*s1, x1.y*s1, x1.z*s1, x1.w*s1);
    int lg = lane >> 2, lm = lane & 3;
    float ya[8] = {0,0,0,0,0,0,0,0};
#pragma unroll 4
    for (int s = 0; s < 64; ++s) {
      float g = CtGt[(s << 6) + ((((lg ^ ((s >> 2) & 15))) << 2) | lm)];
      g = (s <= lane) ? g : 0.f;
      const float* xr = &xde[(h*64 + s)*8];
      float4 a0 = *(const float4*)xr, a1 = *(const float4*)(xr + 4);
      ya[0] += g*a0.x; ya[1] += g*a0.y; ya[2] += g*a0.z; ya[3] += g*a0.w;
      ya[4] += g*a1.x; ya[5] += g*a1.y; ya[6] += g*a1.z; ya[7] += g*a1.w;
    }
    float* yp = &ybuf[((size_t)seq*LL + l0 + lane)*DI + h*8];
    *(float4*)yp     = make_float4(ya[0]*el, ya[1]*el, ya[2]*el, ya[3]*el);
    *(float4*)(yp+4) = make_float4(ya[4]*el, ya[5]*el, ya[6]*el, ya[7]*el);
    if (lane < DS) {
      float r2 = __expf(acsLast - m);
      float sa[8] = {0,0,0,0,0,0,0,0};
#pragma unroll 4
      for (int ll = 0; ll < 64; ++ll) {
        float b = BtBl[ll*DS + lane];
        const float* xr = &xde[(h*64 + ll)*8];
        float4 a0 = *(const float4*)xr, a1 = *(const float4*)(xr + 4);
        sa[0] += b*a0.x; sa[1] += b*a0.y; sa[2] += b*a0.z; sa[3] += b*a0.w;
        sa[4] += b*a1.x; sa[5] += b*a1.y; sa[6] += b*a1.z; sa[7] += b*a1.w;
      }
      float* sp2 = &states[(((size_t)seq*NH + h)*NCHK + cid)*(size_t)(8*DS) + lane*8];
      *(float4*)sp2     = make_float4(sa[0]*r2, sa[1]*r2, sa[2]*r2, sa[3]*r2);
      *(float4*)(sp2+4) = make_float4(sa[4]*r2, sa[5]*r2, sa[6]*r2, sa[7]*r2);
    }
    if (lane == 63) cdec[((size_t)seq*NH + h)*NCHK + cid] = __expf(acsLast);
    acsOut[((size_t)seq*NH + h)*LL + l0 + lane] = acs_l;
  }
}

// ---------------- inter-chunk scan ----------------
__global__ __launch_bounds__(512) void k_scan(float* __restrict__ st, const float* __restrict__ cd, int PN)
{
  int tid = threadIdx.x;
  size_t base = (size_t)blockIdx.x * NCHK * PN + tid;
  const float* c = cd + (size_t)blockIdx.x * NCHK;
  float carry = 0.f;
  for (int k = 0; k < NCHK; ++k) {
    size_t a = base + (size_t)k*PN;
    float s = st[a];
    st[a] = carry;
    carry = carry*c[k] + s;
  }
}

// ---------------- Yo + D*xs combine ----------------
template<int DS, int NH>
__global__ __launch_bounds__(256) void k_ssd_yo(
    float* __restrict__ ybuf, const float* __restrict__ Cb,
    const float* __restrict__ prevSt, const float* __restrict__ acsG,
    const float* __restrict__ Dp, const float* __restrict__ xs)
{
  constexpr int DI = NH*8;
  constexpr int NG = DS/4;
  __shared__ __align__(16) float Ct2[DS*64];
  __shared__ __align__(16) float pvs[NH*DS*8];
  int tid = threadIdx.x;
  int cid = blockIdx.x & 63;
  int seq = blockIdx.x >> 6;
  int l0  = cid << 6;
  for (int i = tid; i < 16*DS; i += 256) {
    int ng = i % NG, l = i / NG;
    float4 cv = *(const float4*)&Cb[((size_t)seq*LL + l0 + l)*DS + 4*ng];
    Ct2[swz(4*ng+0, l)] = cv.x; Ct2[swz(4*ng+1, l)] = cv.y;
    Ct2[swz(4*ng+2, l)] = cv.z; Ct2[swz(4*ng+3, l)] = cv.w;
  }
  for (int i = tid; i < NH*DS*8; i += 256) {
    int h = i / (DS*8), r = i % (DS*8);
    pvs[i] = prevSt[(((size_t)seq*NH + h)*NCHK + cid)*(size_t)(DS*8) + r];
  }
  __syncthreads();
  int w = tid >> 6, lane = tid & 63;
  if (w < NH) {
    int h = w;
    float el = __expf(acsG[((size_t)seq*NH + h)*LL + l0 + lane]);
    float Dh = Dp[h];
    int lg = lane >> 2, lm = lane & 3;
    float acc[8] = {0,0,0,0,0,0,0,0};
#pragma unroll 4
    for (int n = 0; n < DS; ++n) {
      float c = Ct2[(n << 6) + ((((lg ^ ((n >> 2) & 15))) << 2) | lm)];
      const float* pr = &pvs[(h*DS + n)*8];
      float4 p0 = *(const float4*)pr, p1 = *(const float4*)(pr + 4);
      acc[0] += c*p0.x; acc[1] += c*p0.y; acc[2] += c*p0.z; acc[3] += c*p0.w;
      acc[4] += c*p1.x; acc[5] += c*p1.y; acc[6] += c*p1.z; acc[7] += c*p1.w;
    }
    size_t gi = ((size_t)seq*LL + l0 + lane)*DI + h*8;
    float4 y0 = *(const float4*)&ybuf[gi], y1 = *(const float4*)&ybuf[gi+4];
    float4 xv0 = *(const float4*)&xs[gi], xv1 = *(const float4*)&xs[gi+4];
    y0.x += el*acc[0] + Dh*xv0.x; y0.y += el*acc[1] + Dh*xv0.y;
    y0.z += el*acc[2] + Dh*xv0.z; y0.w += el*acc[3] + Dh*xv0.w;
    y1.x += el*acc[4] + Dh*xv1.x; y1.y += el*acc[5] + Dh*xv1.y;
    y1.z += el*acc[6] + Dh*xv1.z; y1.w += el*acc[7] + Dh*xv1.w;
    *(float4*)&ybuf[gi] = y0; *(float4*)&ybuf[gi+4] = y1;
  }
}

// ---------------- gating + RMSNorm + out-proj + optional residual ----------------
template<int DI, int DOUT>
__global__ __launch_bounds__(256) void k_gate(
    const float* __restrict__ ybuf, const float* __restrict__ zbuf,
    const float* __restrict__ rms_w, const float* __restrict__ out_w,
    float* __restrict__ dst, int resMode, const float* __restrict__ res,
    const float* __restrict__ skipPtr)
{
  __shared__ float ow[DOUT*DI];
  __shared__ float rw[DI];
  int tid = threadIdx.x;
  for (int i = tid; i < DOUT*DI; i += 256) ow[i] = out_w[i];
  for (int i = tid; i < DI; i += 256) rw[i] = rms_w[i];
  __syncthreads();
  size_t idx = (size_t)blockIdx.x*256 + tid;
  float y[DI];
  const float* yp = ybuf + idx*DI;
  const float* zp = zbuf + idx*DI;
  float ss = 0.f;
#pragma unroll
  for (int i = 0; i < DI; ++i) {
    float z = zp[i];
    float g = yp[i] * (z / (1.f + __expf(-z)));
    y[i] = g; ss += g*g;
  }
  float r = rsqrtf(ss*(1.f/DI) + 1e-5f);
#pragma unroll
  for (int i = 0; i < DI; ++i) y[i] *= r*rw[i];
  const float* rp = nullptr; float skip = 1.f;
  int seq = (int)(idx / LL), l = (int)(idx % LL);
  if (resMode == 1) rp = res + idx*DOUT;
  else if (resMode == 2) {
    int s = seq / B_, b = seq % B_;
    rp = res + ((size_t)b*LL + l)*CCH + s*DOUT;
    skip = skipPtr[0];
  }
  float* dp = dst + idx*DOUT;
#pragma unroll
  for (int o = 0; o < DOUT; ++o) {
    float acc = 0.f;
#pragma unroll
    for (int i = 0; i < DI; ++i) acc += y[i]*ow[o*DI + i];
    if (rp) acc += skip * rp[o];
    dp[o] = acc;
  }
}

// ---------------- LN over C of x[b,c,l] -> xn[b,l,c] ----------------
__global__ __launch_bounds__(256) void k_ln1(const float* __restrict__ x,
    const float* __restrict__ w, const float* __restrict__ bb, float* __restrict__ xn)
{
  __shared__ float tile[128*65];
  __shared__ float mu[64], rs[64];
  int tid = threadIdx.x;
  int b = blockIdx.x >> 6;
  int l0 = (blockIdx.x & 63) << 6;
  for (int i = tid; i < 8192; i += 256) {
    int l = i & 63, c = i >> 6;
    tile[c*65 + l] = x[((size_t)b*CCH + c)*LL + l0 + l];
  }
  __syncthreads();
  if (tid < 64) {
    float s = 0.f;
    for (int c = 0; c < CCH; ++c) s += tile[c*65 + tid];
    float m = s * (1.f/CCH);
    float v = 0.f;
    for (int c = 0; c < CCH; ++c) { float d = tile[c*65 + tid] - m; v += d*d; }
    mu[tid] = m; rs[tid] = rsqrtf(v*(1.f/CCH) + 1e-5f);
  }
  __syncthreads();
  for (int i = tid; i < 8192; i += 256) {
    int c = i & 127, l = i >> 7;
    xn[((size_t)b*LL + l0 + l)*CCH + c] = (tile[c*65 + l] - mu[l])*rs[l]*w[c] + bb[c];
  }
}

// ---------------- gm[seq,c] = mean_l ys[seq,l,c] ----------------
__global__ __launch_bounds__(256) void k_gm(const float* __restrict__ ys, float* __restrict__ gm)
{
  __shared__ float red[256];
  int tid = threadIdx.x;
  int seq = blockIdx.x;
  int c = tid & 15, lane = tid >> 4;
  float s = 0.f;
  for (int l = lane; l < LL; l += 16) s += ys[((size_t)seq*LL + l)*16 + c];
  red[tid] = s;
  __syncthreads();
  if (tid < 16) {
    float t = 0.f;
    for (int g = 0; g < 16; ++g) t += red[g*16 + tid];
    gm[(size_t)seq*16 + tid] = t * (1.f/LL);
  }
}

// ---------------- gmix ----------------
__global__ __launch_bounds__(256) void k_mix(const float* __restrict__ gm,
    const float* __restrict__ crossW, float* __restrict__ gmix)
{
  __shared__ float wsm[64];
  int tid = threadIdx.x;
  if (tid < 8) {
    float mx = -1e30f;
    for (int p = 0; p < 8; ++p) mx = fmaxf(mx, crossW[tid*8 + p]);
    float e[8]; float s = 0.f;
    for (int p = 0; p < 8; ++p) { e[p] = __expf(crossW[tid*8 + p] - mx); s += e[p]; }
    for (int p = 0; p < 8; ++p) wsm[tid*8 + p] = e[p] / s;
  }
  __syncthreads();
  for (int i = tid; i < 512; i += 256) {
    int c = i & 15; int bb = (i >> 4) & 3; int p = i >> 6;
    float acc = 0.f;
    for (int q = 0; q < 8; ++q) acc += gm[((size_t)(q*B_ + bb))*16 + c] * wsm[q*8 + p];
    gmix[((size_t)(p*B_ + bb))*16 + c] = acc;
  }
}

// ---------------- assemble ys+gmix, LN2, + (x + detok(gf2)) -> outb[b,c,l] ----------------
__global__ __launch_bounds__(256) void k_out2(const float* __restrict__ ys,
    const float* __restrict__ gmix, const float* __restrict__ w, const float* __restrict__ bb,
    const float* __restrict__ x, const float* __restrict__ gf2,
    const float* __restrict__ dw, const float* __restrict__ db,
    float* __restrict__ outb)
{
  __shared__ float tile[128*65];
  __shared__ float mu[64], rs[64];
  int tid = threadIdx.x;
  int b = blockIdx.x >> 6;
  int l0 = (blockIdx.x & 63) << 6;
  for (int i = tid; i < 8192; i += 256) {
    int c = i & 15; int l = (i >> 4) & 63; int s = i >> 10;
    int seq = s*B_ + b;
    tile[(s*16 + c)*65 + l] = ys[((size_t)seq*LL + l0 + l)*16 + c] + gmix[(size_t)seq*16 + c];
  }
  __syncthreads();
  if (tid < 64) {
    float sm = 0.f;
    for (int c = 0; c < 128; ++c) sm += tile[c*65 + tid];
    float m = sm * (1.f/128.f);
    float v = 0.f;
    for (int c = 0; c < 128; ++c) { float d = tile[c*65 + tid] - m; v += d*d; }
    mu[tid] = m; rs[tid] = rsqrtf(v*(1.f/128.f) + 1e-5f);
  }
  __syncthreads();
  int lfix = tid & 63;
  float g8[8];
  {
    const float* gp = gf2 + ((size_t)b*LL + l0 + lfix)*8;
#pragma unroll
    for (int k = 0; k < 8; ++k) g8[k] = gp[k];
  }
  for (int i = tid; i < 8192; i += 256) {
    int l = i & 63, c = i >> 6;
    size_t gi = ((size_t)b*CCH + c)*LL + l0 + l;
    float det = db[c];
#pragma unroll
    for (int k = 0; k < 8; ++k) det += g8[k]*dw[c*8 + k];
    outb[gi] = (tile[c*65 + l] - mu[l])*rs[l]*w[c] + bb[c] + x[gi] + det;
  }
}

// ---------------- fc1: register-tiled GEMM ----------------
__global__ __launch_bounds__(256) void k_fc1(const float* __restrict__ src,
    const float* __restrict__ w, const float* __restrict__ bias, float* __restrict__ dst)
{
  constexpr int WP = 129;
  __shared__ float st[128*64];
  __shared__ float wt[64*WP];
  int tid = threadIdx.x;
  int blk = blockIdx.x;
  int ot = blk & 3;
  int lt = (blk >> 2) & 63;
  int b  = blk >> 8;
  int l0 = lt << 6, o0 = ot << 6;
  for (int i = tid; i < 8192; i += 256) {
    int l = i & 63, c = i >> 6;
    st[c*64 + l] = src[((size_t)b*CCH + c)*LL + l0 + l];
  }
  for (int i = tid; i < 8192; i += 256) {
    int c = i & 127, o = i >> 7;
    wt[o*WP + c] = w[(size_t)(o0 + o)*128 + c];
  }
  __syncthreads();
  int l4 = (tid & 15) << 2, o4 = (tid >> 4) << 2;
  float a0[4] = {}, a1[4] = {}, a2[4] = {}, a3[4] = {};
#pragma unroll 4
  for (int c = 0; c < 128; ++c) {
    float4 sv = *(float4*)&st[c*64 + l4];
    float w0 = wt[(o4+0)*WP + c];
    float w1 = wt[(o4+1)*WP + c];
    float w2 = wt[(o4+2)*WP + c];
    float w3 = wt[(o4+3)*WP + c];
    a0[0] += w0*sv.x; a0[1] += w0*sv.y; a0[2] += w0*sv.z; a0[3] += w0*sv.w;
    a1[0] += w1*sv.x; a1[1] += w1*sv.y; a1[2] += w1*sv.z; a1[3] += w1*sv.w;
    a2[0] += w2*sv.x; a2[1] += w2*sv.y; a2[2] += w2*sv.z; a2[3] += w2*sv.w;
    a3[0] += w3*sv.x; a3[1] += w3*sv.y; a3[2] += w3*sv.z; a3[3] += w3*sv.w;
  }
  float* rows[4] = {a0, a1, a2, a3};
#pragma unroll
  for (int j = 0; j < 4; ++j) {
    int o = o0 + o4 + j;
    float bi = bias[o];
    float* a = rows[j];
    *(float4*)&dst[((size_t)b*256 + o)*LL + l0 + l4] =
        make_float4(a[0]+bi, a[1]+bi, a[2]+bi, a[3]+bi);
  }
}

// ---------------- depthwise 3x3 + gelu, LDS-tiled ----------------
__global__ __launch_bounds__(256) void k_dw(const float* __restrict__ h1,
    const float* __restrict__ w, const float* __restrict__ bias, float* __restrict__ h2)
{
  __shared__ float tile[66*66];
  int tid = threadIdx.x;
  int blk = blockIdx.x;
  const float* base = h1 + (size_t)blk*LL;
  const float* wp = w + (blk & 255)*9;
  float bi = bias[blk & 255];
  for (int i = tid; i < 66*66; i += 256) {
    int r = i / 66, cc = i % 66;
    int gr = r - 1, gc = cc - 1;
    tile[i] = (gr >= 0 && gr < HH && gc >= 0 && gc < WW) ? base[gr*WW + gc] : 0.f;
  }
  float w00 = wp[0], w01 = wp[1], w02 = wp[2];
  float w10 = wp[3], w11 = wp[4], w12 = wp[5];
  float w20 = wp[6], w21 = wp[7], w22 = wp[8];
  __syncthreads();
  float* outp = h2 + (size_t)blk*LL;
#pragma unroll
  for (int k = 0; k < 16; ++k) {
    int j = tid + k*256;
    int row = j >> 6, col = j & 63;
    const float* t0 = &tile[row*66 + col];
    float acc = t0[0]*w00  + t0[1]*w01  + t0[2]*w02
              + t0[66]*w10 + t0[67]*w11 + t0[68]*w12
              + t0[132]*w20 + t0[133]*w21 + t0[134]*w22;
    float v = acc + bi;
    float u = 0.7978845608028654f*(v + 0.044715f*v*v*v);
    float e = __expf(2.f*u);
    float th = 1.f - 2.f/(e + 1.f);
    outp[j] = 0.5f*v*(1.f + th);
  }
}

// ---------------- fc2: register-tiled GEMM ----------------
__global__ __launch_bounds__(256) void k_fc2(const float* __restrict__ h2,
    const float* __restrict__ w, const float* __restrict__ bias,
    const float* __restrict__ resid, float* __restrict__ dst)
{
  constexpr int WP = 260;
  __shared__ float st[128*64];
  __shared__ float wt[32*WP];
  int tid = threadIdx.x;
  int blk = blockIdx.x;
  int ct = blk & 3;
  int lt = (blk >> 2) & 63;
  int b  = blk >> 8;
  int l0 = lt << 6, c0 = ct << 5;
  for (int i = tid; i < 32*256; i += 256) {
    int o = i & 255, c = i >> 8;
    wt[c*WP + o] = w[(size_t)(c0 + c)*256 + o];
  }
  int l4 = (tid & 15) << 2, c2 = (tid >> 4) << 1;
  float a0[4] = {}, a1[4] = {};
  for (int ko = 0; ko < 256; ko += 128) {
    __syncthreads();
    for (int i = tid; i < 8192; i += 256) {
      int l = i & 63, o = i >> 6;
      st[o*64 + l] = h2[((size_t)b*256 + ko + o)*LL + l0 + l];
    }
    __syncthreads();
#pragma unroll 4
    for (int o = 0; o < 128; ++o) {
      float4 sv = *(float4*)&st[o*64 + l4];
      float w0 = wt[(c2+0)*WP + ko + o];
      float w1 = wt[(c2+1)*WP + ko + o];
      a0[0] += w0*sv.x; a0[1] += w0*sv.y; a0[2] += w0*sv.z; a0[3] += w0*sv.w;
      a1[0] += w1*sv.x; a1[1] += w1*sv.y; a1[2] += w1*sv.z; a1[3] += w1*sv.w;
    }
  }
  float* rows[2] = {a0, a1};
#pragma unroll
  for (int j = 0; j < 2; ++j) {
    int c = c0 + c2 + j;
    float bi = bias[c];
    size_t gi = ((size_t)b*CCH + c)*LL + l0 + l4;
    float4 rv = *(const float4*)&resid[gi];
    float* a = rows[j];
    *(float4*)&dst[gi] = make_float4(a[0]+bi+rv.x, a[1]+bi+rv.y, a[2]+bi+rv.z, a[3]+bi+rv.w);
  }
}

extern "C" void kernel_launch(void* const* d_in, const int* in_sizes, int n_in,
                              void* d_out, int out_size, void* d_ws, size_t ws_size,
                              hipStream_t stream) {
  (void)in_sizes; (void)n_in; (void)out_size; (void)ws_size;
  const float* x        = (const float*)d_in[0];
  const float* tok_w    = (const float*)d_in[1];
  const float* tok_b    = (const float*)d_in[2];
  const float* detok_w  = (const float*)d_in[3];
  const float* detok_b  = (const float*)d_in[4];
  const float* sm_in_w  = (const float*)d_in[5];
  const float* sm_in_b  = (const float*)d_in[6];
  const float* sm_conv_w= (const float*)d_in[7];
  const float* sm_conv_b= (const float*)d_in[8];
  const float* sm_A_log = (const float*)d_in[9];
  const float* sm_D     = (const float*)d_in[10];
  const float* sm_dt_b  = (const float*)d_in[11];
  const float* sm_rms_w = (const float*)d_in[12];
  const float* sm_out_w = (const float*)d_in[13];
  const float* cm_in_w  = (const float*)d_in[14];
  const float* cm_in_b  = (const float*)d_in[15];
  const float* cm_conv_w= (const float*)d_in[16];
  const float* cm_conv_b= (const float*)d_in[17];
  const float* cm_A_log = (const float*)d_in[18];
  const float* cm_D     = (const float*)d_in[19];
  const float* cm_dt_b  = (const float*)d_in[20];
  const float* cm_rms_w = (const float*)d_in[21];
  const float* cm_out_w = (const float*)d_in[22];
  const float* cross_W  = (const float*)d_in[23];
  const float* n1w      = (const float*)d_in[24];
  const float* n1b      = (const float*)d_in[25];
  const float* n2w      = (const float*)d_in[26];
  const float* n2b      = (const float*)d_in[27];
  const float* fc1w     = (const float*)d_in[28];
  const float* fc1b     = (const float*)d_in[29];
  const float* dww      = (const float*)d_in[30];
  const float* dwb      = (const float*)d_in[31];
  const float* fc2w     = (const float*)d_in[32];
  const float* fc2b     = (const float*)d_in[33];
  const float* skp      = (const float*)d_in[34];
  float* ws  = (float*)d_ws;
  float* out = (float*)d_out;

  const size_t SGF0 = 0;
  const size_t SOUTn= 131072;
  const size_t XN   = 2097152;
  const size_t YS   = 4194304;
  const size_t OUTB = 6291456;
  const size_t GM   = 8388608;
  const size_t GMIX = 8389120;
  const size_t SCR  = 8389632;
  const size_t CZ   = SCR;
  const size_t CXS  = CZ   + 4194304;
  const size_t CCF  = CXS  + 4194304;
  const size_t CACS = CCF  + 8388608;
  const size_t CST  = CACS + 2097152;
  const size_t CCD  = CST  + 4194304;
  const size_t CY   = CCD  + 8192;
  const size_t XB   = CY   + 4194304;
  const size_t SZ   = SCR;
  const size_t SDT  = SZ  + 262144;
  const size_t SXS  = SDT + 32768;
  const size_t SB   = SXS + 262144;
  const size_t SC   = SB  + 262144;
  const size_t SACS = SC  + 262144;
  const size_t SST  = SACS + 32768;
  const size_t SCD  = SST + 65536;
  const size_t SY   = SCD + 512;
  const size_t H1 = SCR;
  const size_t H2 = SCR + 4194304;

  // ===== seed path =====
  k_seedtok<<<B_*64, 256, 0, stream>>>(x, tok_w, tok_b, ws + SGF0);
  k_inproj<8,16,16,2><<<B_*64, 256, 0, stream>>>(ws + SGF0, 0, sm_in_w, sm_in_b, sm_conv_w,
      sm_conv_b, sm_dt_b, ws + SZ, ws + SDT, ws + SXS, ws + SB, ws + SC);
  k_ssd1<16,2><<<B_*NCHK, 256, 0, stream>>>(ws + SXS, ws + SDT, ws + SB, ws + SC,
      sm_A_log, ws + SY, ws + SST, ws + SCD, ws + SACS);
  k_scan<<<B_*2, 128, 0, stream>>>(ws + SST, ws + SCD, 128);
  k_ssd_yo<16,2><<<B_*NCHK, 256, 0, stream>>>(ws + SY, ws + SC, ws + SST, ws + SACS, sm_D, ws + SXS);
  k_gate<16,8><<<B_*LL/256, 256, 0, stream>>>(ws + SY, ws + SZ, sm_rms_w, sm_out_w,
      ws + SOUTn, 1, ws + SGF0, skp);

  // ===== norm1 =====
  k_ln1<<<B_*64, 256, 0, stream>>>(x, n1w, n1b, ws + XN);

  // ===== cascade layer 0 (fused inproj+ssd, fixed) =====
  k_inssd<<<32*NCHK, 256, 0, stream>>>(ws + XN, 1, cm_in_w, cm_in_b, cm_conv_w,
      cm_conv_b, cm_dt_b, cm_A_log, ws + CZ, ws + CXS, ws + CCF,
      ws + CY, ws + CST, ws + CCD, ws + CACS);
  k_scan<<<32*4, 512, 0, stream>>>(ws + CST, ws + CCD, 512);
  k_ssd_yo<64,4><<<32*NCHK, 256, 0, stream>>>(ws + CY, ws + CCF, ws + CST, ws + CACS, cm_D, ws + CXS);
  k_gate<32,16><<<32*LL/256, 256, 0, stream>>>(ws + CY, ws + CZ, cm_rms_w, cm_out_w,
      ws + XB, 0, nullptr, skp);

  // ===== cascade layer 1 =====
  k_inssd<<<32*NCHK, 256, 0, stream>>>(ws + XB, 0, cm_in_w + 3136, cm_in_b + 196,
      cm_conv_w + 480, cm_conv_b + 160, cm_dt_b + 4, cm_A_log + 4, ws + CZ, ws + CXS, ws + CCF,
      ws + CY, ws + CST, ws + CCD, ws + CACS);
  k_scan<<<32*4, 512, 0, stream>>>(ws + CST, ws + CCD, 512);
  k_ssd_yo<64,4><<<32*NCHK, 256, 0, stream>>>(ws + CY, ws + CCF, ws + CST, ws + CACS, cm_D + 4, ws + CXS);
  k_gate<32,16><<<32*LL/256, 256, 0, stream>>>(ws + CY, ws + CZ, cm_rms_w + 32, cm_out_w + 512,
      ws + YS, 2, ws + XN, skp);

  // ===== cross mix + norm2 + (fused detok seed) =====
  k_gm<<<32, 256, 0, stream>>>(ws + YS, ws + GM);
  k_mix<<<1, 256, 0, stream>>>(ws + GM, cross_W, ws + GMIX);
  k_out2<<<B_*64, 256, 0, stream>>>(ws + YS, ws + GMIX, n2w, n2b,
      x, ws + SOUTn, detok_w, detok_b, ws + OUTB);

  // ===== FFN =====
  k_fc1<<<B_*64*4, 256, 0, stream>>>(ws + OUTB, fc1w, fc1b, ws + H1);
  k_dw<<<B_*256, 256, 0, stream>>>(ws + H1, dww, dwb, ws + H2);
  k_fc2<<<B_*64*4, 256, 0, stream>>>(ws + H2, fc2w, fc2b, ws + OUTB, out);
}

// Round 10
// 557.438 us; speedup vs baseline: 1.2645x; 1.0543x over previous
//
#include <hip/hip_runtime.h>
#include <math.h>

#define B_ 4
#define CCH 128
#define HH 64
#define WW 64
#define LL 4096
#define NCHK 64

__device__ __forceinline__ float siluf(float x) { return x / (1.f + __expf(-x)); }
__device__ __forceinline__ float softplusf(float x) { return (x > 20.f) ? x : log1pf(__expf(x)); }
// swizzled [n][l] layout, pitch 64: phys = n*64 + (((l>>2) ^ ((n>>2)&15))<<2 | (l&3))
__device__ __forceinline__ int swz(int n, int l) {
  return (n << 6) + ((((l >> 2) ^ ((n >> 2) & 15)) << 2) | (l & 3));
}

// ---------------- seed tokenize v2 ----------------
__global__ __launch_bounds__(256) void k_seedtok(const float* __restrict__ x,
    const float* __restrict__ w, const float* __restrict__ bias, float* __restrict__ gf)
{
  __shared__ float tile[128*65];
  __shared__ float sw[8*128];
  __shared__ float bl[8];
  int tid = threadIdx.x;
  int b = blockIdx.x >> 6;
  int l0 = (blockIdx.x & 63) << 6;
  for (int i = tid; i < 1024; i += 256) sw[i] = w[i];
  if (tid < 8) bl[tid] = bias[tid];
  for (int i = tid; i < 8192; i += 256) {
    int l = i & 63, c = i >> 6;
    tile[c*65 + l] = x[((size_t)b*CCH + c)*LL + l0 + l];
  }
  __syncthreads();
  int l = tid & 63, q = tid >> 6;
  float a0 = bl[2*q], a1 = bl[2*q+1];
  const float* w0 = &sw[(2*q)*128];
  const float* w1 = &sw[(2*q+1)*128];
#pragma unroll 4
  for (int c = 0; c < 128; ++c) {
    float xv = tile[c*65 + l];
    a0 += xv * w0[c];
    a1 += xv * w1[c];
  }
  *(float2*)&gf[((size_t)b*LL + l0 + l)*8 + 2*q] = make_float2(a0, a1);
}

// ---------------- fused in-projection + conv3 + silu + softplus(dt) (seed path) ----------------
template<int DIN, int NZ, int NDS, int NDT>
__global__ __launch_bounds__(256) void k_inproj(
    const float* __restrict__ src, int srcMode,
    const float* __restrict__ in_w, const float* __restrict__ in_b,
    const float* __restrict__ conv_w, const float* __restrict__ conv_b,
    const float* __restrict__ dt_bias,
    float* __restrict__ zb, float* __restrict__ dtb,
    float* __restrict__ xsb, float* __restrict__ Bb, float* __restrict__ Cb)
{
  constexpr int NXBC = NZ + 2*NDS;
  constexpr int NTOT = 2*NZ + 2*NDS + NDT;
  constexpr int NZQ  = NZ/4;
  constexpr int NDSQ = NDS/4;
  constexpr int XP   = DIN + 1;
  __shared__ float xt[66*XP];
  __shared__ float wl[NTOT*DIN];
  __shared__ float cwl[NXBC*3];
  __shared__ float cbl[NXBC];
  __shared__ float ibl[NTOT];
  __shared__ float dts[64*NDT];
  __shared__ float hp[NXBC*2];
  int tid = threadIdx.x;
  int seq = blockIdx.x >> 6;
  int l0  = (blockIdx.x & 63) << 6;
  for (int i = tid; i < NTOT*DIN; i += 256) wl[i] = in_w[i];
  for (int i = tid; i < NXBC*3; i += 256) cwl[i] = conv_w[i];
  for (int i = tid; i < NXBC; i += 256) cbl[i] = conv_b[i];
  for (int i = tid; i < NTOT; i += 256) ibl[i] = in_b[i];
  const float* sp; int sstr;
  if (srcMode == 0) { sp = src + (size_t)seq*LL*DIN; sstr = DIN; }
  else { sp = src + (size_t)(seq & 3)*LL*CCH + (seq >> 2)*16; sstr = CCH; }
  for (int i = tid; i < 66*DIN; i += 256) {
    int r = i / DIN, d = i % DIN;
    int l = l0 - 2 + r;
    xt[r*XP + d] = (l >= 0) ? sp[(size_t)l*sstr + d] : 0.f;
  }
  __syncthreads();
  for (int i = tid; i < 2*NXBC; i += 256) {
    int t = i & 1, ch = i >> 1;
    const float* wr = &wl[(NZ + ch)*DIN];
    const float* xp = &xt[t*XP];
    float acc = 0.f;
#pragma unroll
    for (int d = 0; d < DIN; ++d) acc += xp[d]*wr[d];
    hp[ch*2 + t] = acc;
  }
  __syncthreads();
  int l = tid & 63, w4 = tid >> 6;
  float xr2[DIN];
#pragma unroll
  for (int d = 0; d < DIN; ++d) xr2[d] = xt[(l+2)*XP + d];
  size_t gl = (size_t)seq*LL + l0 + l;
  int tok = l0 + l;
  float v0ok = (tok >= 2) ? 1.f : 0.f;
  float v1ok = (tok >= 1) ? 1.f : 0.f;
  {
    float zv[NZQ];
#pragma unroll
    for (int j = 0; j < NZQ; ++j) {
      int row = w4*NZQ + j;
      const float* wr = &wl[row*DIN];
      float acc = ibl[row];
#pragma unroll
      for (int d = 0; d < DIN; ++d) acc += xr2[d]*wr[d];
      zv[j] = acc;
    }
#pragma unroll
    for (int g = 0; g < NZQ/4; ++g)
      *(float4*)&zb[gl*NZ + w4*NZQ + 4*g] = make_float4(zv[4*g], zv[4*g+1], zv[4*g+2], zv[4*g+3]);
  }
  if (w4 < NDT) {
    int row = NTOT - NDT + w4;
    const float* wr = &wl[row*DIN];
    float acc = ibl[row] + dt_bias[w4];
#pragma unroll
    for (int d = 0; d < DIN; ++d) acc += xr2[d]*wr[d];
    dts[l*NDT + w4] = softplusf(acc);
  }
  auto convch = [&](int ch) -> float {
    int row = NZ + ch;
    const float* wr = &wl[row*DIN];
    float pm = 0.f;
#pragma unroll
    for (int d = 0; d < DIN; ++d) pm += xr2[d]*wr[d];
    float m1 = __shfl_up(pm, 1, 64);
    float m2 = __shfl_up(pm, 2, 64);
    float h0 = hp[ch*2 + 0], h1 = hp[ch*2 + 1];
    if (l == 0) m1 = h1;
    m2 = (l == 0) ? h0 : ((l == 1) ? h1 : m2);
    float ib = ibl[row];
    float conv = cbl[ch] + (m2+ib)*v0ok*cwl[ch*3+0] + (m1+ib)*v1ok*cwl[ch*3+1] + (pm+ib)*cwl[ch*3+2];
    return siluf(conv);
  };
  {
    float xv[NZQ];
#pragma unroll
    for (int j = 0; j < NZQ; ++j) xv[j] = convch(w4*NZQ + j);
#pragma unroll
    for (int g = 0; g < NZQ/4; ++g)
      *(float4*)&xsb[gl*NZ + w4*NZQ + 4*g] = make_float4(xv[4*g], xv[4*g+1], xv[4*g+2], xv[4*g+3]);
  }
  {
    float bv[NDSQ];
#pragma unroll
    for (int j = 0; j < NDSQ; ++j) bv[j] = convch(NZ + w4*NDSQ + j);
#pragma unroll
    for (int g = 0; g < NDSQ/4; ++g)
      *(float4*)&Bb[gl*NDS + w4*NDSQ + 4*g] = make_float4(bv[4*g], bv[4*g+1], bv[4*g+2], bv[4*g+3]);
  }
  {
    float cv[NDSQ];
#pragma unroll
    for (int j = 0; j < NDSQ; ++j) cv[j] = convch(NZ + NDS + w4*NDSQ + j);
#pragma unroll
    for (int g = 0; g < NDSQ/4; ++g)
      *(float4*)&Cb[gl*NDS + w4*NDSQ + 4*g] = make_float4(cv[4*g], cv[4*g+1], cv[4*g+2], cv[4*g+3]);
  }
  __syncthreads();
  if (tid < 64) {
    if constexpr (NDT == 4) {
      *(float4*)&dtb[((size_t)seq*LL + l0 + tid)*4] =
          make_float4(dts[tid*4], dts[tid*4+1], dts[tid*4+2], dts[tid*4+3]);
    } else {
      *(float2*)&dtb[((size_t)seq*LL + l0 + tid)*NDT] = make_float2(dts[tid*NDT], dts[tid*NDT+1]);
    }
  }
}

// ======= FUSED inproj + intra-chunk SSD v2 (cascade) =======
__global__ __launch_bounds__(256, 3) void k_inssd(
    const float* __restrict__ src, int srcMode,
    const float* __restrict__ in_w, const float* __restrict__ in_b,
    const float* __restrict__ conv_w, const float* __restrict__ conv_b,
    const float* __restrict__ dt_bias, const float* __restrict__ A_log,
    float* __restrict__ zb, float* __restrict__ xsb, float* __restrict__ Cb,
    float* __restrict__ ybuf, float* __restrict__ states,
    float* __restrict__ cdec, float* __restrict__ acsOut)
{
  const int DIN = 16, NZ = 32, NDS = 64, DI = 32;
  const int NXBC = 160, NTOT = 196;
  __shared__ float sm[12518];            // 50072 B -> 3 blocks/CU
  float* Bt  = sm;
  float* Ct  = sm + 4096;
  float* U   = sm + 8192;
  float* wl  = U;
  float* cwl = U + 3136;
  float* cbl = U + 3616;
  float* ibl = U + 3776;
  float* hp  = U + 3972;
  float* ha  = U + 4292;
  float* xde = U;
  int tid = threadIdx.x;
  int cid = blockIdx.x & 63;
  int seq = blockIdx.x >> 6;
  int l0  = cid << 6;
  int lane = tid & 63, w = tid >> 6;
  const float* sp; int sstr;
  if (srcMode == 0) { sp = src + (size_t)seq*LL*DIN; sstr = DIN; }
  else { sp = src + (size_t)(seq & 3)*LL*CCH + (seq >> 2)*16; sstr = CCH; }
  float xr2[DIN];
  {
    const float* p = sp + (size_t)(l0 + lane)*sstr;
#pragma unroll
    for (int k = 0; k < 4; ++k) {
      float4 v = *(const float4*)(p + 4*k);
      xr2[4*k+0]=v.x; xr2[4*k+1]=v.y; xr2[4*k+2]=v.z; xr2[4*k+3]=v.w;
    }
  }
  for (int i = tid; i < NTOT*DIN; i += 256) wl[i] = in_w[i];
  for (int i = tid; i < NXBC*3; i += 256) cwl[i] = conv_w[i];
  for (int i = tid; i < NXBC; i += 256) cbl[i] = conv_b[i];
  for (int i = tid; i < NTOT; i += 256) ibl[i] = in_b[i];
  if (tid < 32) {
    int t = tid >> 4, d = tid & 15;
    int tok = l0 - 2 + t;
    ha[t*17 + d] = (tok >= 0) ? sp[(size_t)tok*sstr + d] : 0.f;
  }
  __syncthreads();
  for (int i = tid; i < 2*NXBC; i += 256) {
    int t = i & 1, ch = i >> 1;
    const float* wr = &wl[(NZ + ch)*DIN];
    const float* hr = &ha[t*17];
    float acc = 0.f;
#pragma unroll
    for (int d = 0; d < DIN; ++d) acc += hr[d]*wr[d];
    hp[ch*2 + t] = acc;
  }
  __syncthreads();
  size_t gl = (size_t)seq*LL + l0 + lane;
  int tok = l0 + lane;
  float v0ok = (tok >= 2) ? 1.f : 0.f;
  float v1ok = (tok >= 1) ? 1.f : 0.f;
  {
    float zv[8];
#pragma unroll
    for (int j = 0; j < 8; ++j) {
      int row = w*8 + j;
      const float* wr = &wl[row*DIN];
      float acc = ibl[row];
#pragma unroll
      for (int d = 0; d < DIN; ++d) acc += xr2[d]*wr[d];
      zv[j] = acc;
    }
    *(float4*)&zb[gl*NZ + w*8 + 0] = make_float4(zv[0], zv[1], zv[2], zv[3]);
    *(float4*)&zb[gl*NZ + w*8 + 4] = make_float4(zv[4], zv[5], zv[6], zv[7]);
  }
  float dtv;
  {
    int row = NTOT - 4 + w;
    const float* wr = &wl[row*DIN];
    float acc = ibl[row] + dt_bias[w];
#pragma unroll
    for (int d = 0; d < DIN; ++d) acc += xr2[d]*wr[d];
    dtv = softplusf(acc);
  }
  auto convch = [&](int ch) -> float {
    int row = NZ + ch;
    const float* wr = &wl[row*DIN];
    float pm = 0.f;
#pragma unroll
    for (int d = 0; d < DIN; ++d) pm += xr2[d]*wr[d];
    float m1 = __shfl_up(pm, 1, 64);
    float m2 = __shfl_up(pm, 2, 64);
    float h0 = hp[ch*2 + 0], h1 = hp[ch*2 + 1];
    if (lane == 0) m1 = h1;
    m2 = (lane == 0) ? h0 : ((lane == 1) ? h1 : m2);
    float ib = ibl[row];
    float conv = cbl[ch] + (m2+ib)*v0ok*cwl[ch*3+0] + (m1+ib)*v1ok*cwl[ch*3+1] + (pm+ib)*cwl[ch*3+2];
    return siluf(conv);
  };
  float xv[8];
#pragma unroll
  for (int j = 0; j < 8; ++j) xv[j] = convch(w*8 + j);
  *(float4*)&xsb[gl*DI + w*8 + 0] = make_float4(xv[0], xv[1], xv[2], xv[3]);
  *(float4*)&xsb[gl*DI + w*8 + 4] = make_float4(xv[4], xv[5], xv[6], xv[7]);
#pragma unroll
  for (int j = 0; j < 16; ++j) {
    int n = w*16 + j;
    Bt[swz(n, lane)] = convch(NZ + n);
  }
  {
    float cv[16];
#pragma unroll
    for (int j = 0; j < 16; ++j) {
      int n = w*16 + j;
      cv[j] = convch(NZ + NDS + n);
      Ct[swz(n, lane)] = cv[j];
    }
#pragma unroll
    for (int g = 0; g < 4; ++g)
      *(float4*)&Cb[gl*NDS + w*16 + 4*g] = make_float4(cv[4*g], cv[4*g+1], cv[4*g+2], cv[4*g+3]);
  }
  __syncthreads();
  float Aval = -__expf(A_log[w]);
  float v = dtv * Aval;
#pragma unroll
  for (int off = 1; off < 64; off <<= 1) {
    float t = __shfl_up(v, off, 64);
    if (lane >= off) v += t;
  }
  float acs_l = v;
  float m = __shfl(v, 31, 64);
  float acsLast = __shfl(v, 63, 64);
  float el = __expf(fminf(acs_l - m, 60.f));
  float fl = __expf(fminf(m - acs_l, 60.f));
  {
    float s1 = dtv*fl;
    float* xe = &xde[(w*64 + lane)*8];
    *(float4*)xe     = make_float4(xv[0]*s1, xv[1]*s1, xv[2]*s1, xv[3]*s1);
    *(float4*)(xe+4) = make_float4(xv[4]*s1, xv[5]*s1, xv[6]*s1, xv[7]*s1);
  }
  int lt = (tid >> 4) << 2, st = (tid & 15) << 2;
  float acc[4][4] = {};
#pragma unroll 4
  for (int n = 0; n < 64; ++n) {
    float4 cvv = *(const float4*)&Ct[swz(n, lt)];
    float4 bvv = *(const float4*)&Bt[swz(n, st)];
    float cc[4] = {cvv.x, cvv.y, cvv.z, cvv.w};
    float bb[4] = {bvv.x, bvv.y, bvv.z, bvv.w};
#pragma unroll
    for (int i2 = 0; i2 < 4; ++i2)
#pragma unroll
      for (int j2 = 0; j2 < 4; ++j2)
        acc[i2][j2] += cc[i2]*bb[j2];
  }
  __syncthreads();
#pragma unroll
  for (int j = 0; j < 4; ++j) {
    *(float4*)&Ct[swz(st + j, lt)] = make_float4(acc[0][j], acc[1][j], acc[2][j], acc[3][j]);
  }
  __syncthreads();
  int lg = lane >> 2, lm = lane & 3;
  float ya[8] = {0,0,0,0,0,0,0,0};
#pragma unroll 4
  for (int s = 0; s < 64; ++s) {
    float g = Ct[(s << 6) + (((lg ^ ((s >> 2) & 15))) << 2 | lm)];
    g = (s <= lane) ? g : 0.f;
    const float* xr = &xde[(w*64 + s)*8];
    float4 a0 = *(const float4*)xr, a1 = *(const float4*)(xr + 4);
    ya[0] += g*a0.x; ya[1] += g*a0.y; ya[2] += g*a0.z; ya[3] += g*a0.w;
    ya[4] += g*a1.x; ya[5] += g*a1.y; ya[6] += g*a1.z; ya[7] += g*a1.w;
  }
  float* yp = &ybuf[gl*DI + w*8];
  *(float4*)yp     = make_float4(ya[0]*el, ya[1]*el, ya[2]*el, ya[3]*el);
  *(float4*)(yp+4) = make_float4(ya[4]*el, ya[5]*el, ya[6]*el, ya[7]*el);
  {
    float r2 = __expf(acsLast - m);
    float sa[8] = {0,0,0,0,0,0,0,0};
#pragma unroll 4
    for (int ll = 0; ll < 64; ++ll) {
      float b = Bt[swz(lane, ll)];
      const float* xr = &xde[(w*64 + ll)*8];
      float4 a0 = *(const float4*)xr, a1 = *(const float4*)(xr + 4);
      sa[0] += b*a0.x; sa[1] += b*a0.y; sa[2] += b*a0.z; sa[3] += b*a0.w;
      sa[4] += b*a1.x; sa[5] += b*a1.y; sa[6] += b*a1.z; sa[7] += b*a1.w;
    }
    float* sp2 = &states[(((size_t)seq*4 + w)*NCHK + cid)*(size_t)(8*NDS) + lane*8];
    *(float4*)sp2     = make_float4(sa[0]*r2, sa[1]*r2, sa[2]*r2, sa[3]*r2);
    *(float4*)(sp2+4) = make_float4(sa[4]*r2, sa[5]*r2, sa[6]*r2, sa[7]*r2);
  }
  if (lane == 63) cdec[((size_t)seq*4 + w)*NCHK + cid] = __expf(acsLast);
  acsOut[((size_t)seq*4 + w)*LL + l0 + lane] = acs_l;
}

// ---------------- SSD intra-chunk v3 (seed path) ----------------
template<int DS, int NH>
__global__ __launch_bounds__(256) void k_ssd1(
    const float* __restrict__ xs, const float* __restrict__ dtb,
    const float* __restrict__ Bb, const float* __restrict__ Cb,
    const float* __restrict__ A_log,
    float* __restrict__ ybuf, float* __restrict__ states,
    float* __restrict__ cdec, float* __restrict__ acsOut)
{
  constexpr int DI = NH*8;
  constexpr int NG = DS/4;
  __shared__ __align__(16) float BtBl[DS*64];
  __shared__ __align__(16) float CtGt[64*64];
  __shared__ __align__(16) float xde[NH*64*8];
  int tid = threadIdx.x;
  int cid = blockIdx.x & 63;
  int seq = blockIdx.x >> 6;
  int l0  = cid << 6;
  for (int i = tid; i < 16*DS; i += 256) {
    int ng = i % NG, l = i / NG;
    size_t g = ((size_t)seq*LL + l0 + l)*DS + 4*ng;
    float4 bv = *(const float4*)&Bb[g];
    float4 cv = *(const float4*)&Cb[g];
    BtBl[swz(4*ng+0, l)] = bv.x; BtBl[swz(4*ng+1, l)] = bv.y;
    BtBl[swz(4*ng+2, l)] = bv.z; BtBl[swz(4*ng+3, l)] = bv.w;
    CtGt[swz(4*ng+0, l)] = cv.x; CtGt[swz(4*ng+1, l)] = cv.y;
    CtGt[swz(4*ng+2, l)] = cv.z; CtGt[swz(4*ng+3, l)] = cv.w;
  }
  __syncthreads();
  int lt = (tid >> 4) << 2, st = (tid & 15) << 2;
  float acc[4][4] = {};
#pragma unroll 4
  for (int n = 0; n < DS; ++n) {
    float4 cv = *(const float4*)&CtGt[swz(n, lt)];
    float4 bv = *(const float4*)&BtBl[swz(n, st)];
    float cc[4] = {cv.x, cv.y, cv.z, cv.w};
    float bb[4] = {bv.x, bv.y, bv.z, bv.w};
#pragma unroll
    for (int i2 = 0; i2 < 4; ++i2)
#pragma unroll
      for (int j2 = 0; j2 < 4; ++j2)
        acc[i2][j2] += cc[i2]*bb[j2];
  }
  __syncthreads();
#pragma unroll
  for (int j = 0; j < 4; ++j) {
    float4 gv = make_float4(acc[0][j], acc[1][j], acc[2][j], acc[3][j]);
    *(float4*)&CtGt[swz(st + j, lt)] = gv;
  }
  for (int i = tid; i < 16*DS; i += 256) {
    int ng = i % NG, l = i / NG;
    float4 bv = *(const float4*)&Bb[((size_t)seq*LL + l0 + l)*DS + 4*ng];
    *(float4*)&BtBl[l*DS + 4*ng] = bv;
  }
  __syncthreads();
  int w = tid >> 6, lane = tid & 63;
  if (w < NH) {
    int h = w;
    float dt_l = dtb[((size_t)seq*LL + l0 + lane)*NH + h];
    float Aval = -__expf(A_log[h]);
    float v = dt_l * Aval;
#pragma unroll
    for (int off = 1; off < 64; off <<= 1) {
      float t = __shfl_up(v, off, 64);
      if (lane >= off) v += t;
    }
    float acs_l = v;
    float m = __shfl(v, 31, 64);
    float acsLast = __shfl(v, 63, 64);
    float el = __expf(fminf(acs_l - m, 60.f));
    float fl = __expf(fminf(m - acs_l, 60.f));
    const float* xp = &xs[((size_t)seq*LL + l0 + lane)*DI + h*8];
    float4 x0 = *(const float4*)xp, x1 = *(const float4*)(xp + 4);
    float s1 = dt_l*fl;
    float* xe = &xde[(h*64 + lane)*8];
    *(float4*)xe     = make_float4(x0.x*s1, x0.y*s1, x0.z*s1, x0.w*s1);
    *(float4*)(xe+4) = make_float4(x1.x*s1, x1.y*s1, x1.z*s1, x1.w*s1);
    int lg = lane >> 2, lm = lane & 3;
    float ya[8] = {0,0,0,0,0,0,0,0};
#pragma unroll 4
    for (int s = 0; s < 64; ++s) {
      float g = CtGt[(s << 6) + ((((lg ^ ((s >> 2) & 15))) << 2) | lm)];
      g = (s <= lane) ? g : 0.f;
      const float* xr = &xde[(h*64 + s)*8];
      float4 a0 = *(const float4*)xr, a1 = *(const float4*)(xr + 4);
      ya[0] += g*a0.x; ya[1] += g*a0.y; ya[2] += g*a0.z; ya[3] += g*a0.w;
      ya[4] += g*a1.x; ya[5] += g*a1.y; ya[6] += g*a1.z; ya[7] += g*a1.w;
    }
    float* yp = &ybuf[((size_t)seq*LL + l0 + lane)*DI + h*8];
    *(float4*)yp     = make_float4(ya[0]*el, ya[1]*el, ya[2]*el, ya[3]*el);
    *(float4*)(yp+4) = make_float4(ya[4]*el, ya[5]*el, ya[6]*el, ya[7]*el);
    if (lane < DS) {
      float r2 = __expf(acsLast - m);
      float sa[8] = {0,0,0,0,0,0,0,0};
#pragma unroll 4
      for (int ll = 0; ll < 64; ++ll) {
        float b = BtBl[ll*DS + lane];
        const float* xr = &xde[(h*64 + ll)*8];
        float4 a0 = *(const float4*)xr, a1 = *(const float4*)(xr + 4);
        sa[0] += b*a0.x; sa[1] += b*a0.y; sa[2] += b*a0.z; sa[3] += b*a0.w;
        sa[4] += b*a1.x; sa[5] += b*a1.y; sa[6] += b*a1.z; sa[7] += b*a1.w;
      }
      float* sp2 = &states[(((size_t)seq*NH + h)*NCHK + cid)*(size_t)(8*DS) + lane*8];
      *(float4*)sp2     = make_float4(sa[0]*r2, sa[1]*r2, sa[2]*r2, sa[3]*r2);
      *(float4*)(sp2+4) = make_float4(sa[4]*r2, sa[5]*r2, sa[6]*r2, sa[7]*r2);
    }
    if (lane == 63) cdec[((size_t)seq*NH + h)*NCHK + cid] = __expf(acsLast);
    acsOut[((size_t)seq*NH + h)*LL + l0 + lane] = acs_l;
  }
}

// ---------------- inter-chunk scan ----------------
__global__ __launch_bounds__(512) void k_scan(float* __restrict__ st, const float* __restrict__ cd, int PN)
{
  int tid = threadIdx.x;
  size_t base = (size_t)blockIdx.x * NCHK * PN + tid;
  const float* c = cd + (size_t)blockIdx.x * NCHK;
  float carry = 0.f;
  for (int k = 0; k < NCHK; ++k) {
    size_t a = base + (size_t)k*PN;
    float s = st[a];
    st[a] = carry;
    carry = carry*c[k] + s;
  }
}

// ======= FUSED Yo + D*xs + gating + RMSNorm + out-proj (replaces k_ssd_yo + k_gate) =======
// Block per (seq, chunk). Phase 1: wave w (head) computes y = Yd + el*(C.prev) + D*xs for its
// 8 channels, gates with silu(z), stores g to LDS + per-head square partials. Phase 2: thread
// (token, quarter) does RMS, scales by rms_w, out-projects DOUT/4 channels, adds residual.
template<int DS, int NH, int DOUT>
__global__ __launch_bounds__(256) void k_yogate(
    const float* __restrict__ ybuf, const float* __restrict__ Cb,
    const float* __restrict__ prevSt, const float* __restrict__ acsG,
    const float* __restrict__ Dp, const float* __restrict__ xs,
    const float* __restrict__ zb,
    const float* __restrict__ rms_w, const float* __restrict__ out_w,
    float* __restrict__ dst, int resMode, const float* __restrict__ res,
    const float* __restrict__ skipPtr)
{
  constexpr int DI = NH*8;
  constexpr int NG = DS/4;
  constexpr int DIP = DI + 4;
  constexpr int OQ = DOUT/4;
  __shared__ __align__(16) float Ct2[DS*64];
  __shared__ __align__(16) float pvs[NH*DS*8];
  __shared__ __align__(16) float gt[64*DIP];
  __shared__ float ps[NH*64];
  __shared__ float ow[DOUT*DI];
  __shared__ float rwl[DI];
  int tid = threadIdx.x;
  int cid = blockIdx.x & 63;
  int seq = blockIdx.x >> 6;
  int l0  = cid << 6;
  for (int i = tid; i < 16*DS; i += 256) {
    int ng = i % NG, l = i / NG;
    float4 cv = *(const float4*)&Cb[((size_t)seq*LL + l0 + l)*DS + 4*ng];
    Ct2[swz(4*ng+0, l)] = cv.x; Ct2[swz(4*ng+1, l)] = cv.y;
    Ct2[swz(4*ng+2, l)] = cv.z; Ct2[swz(4*ng+3, l)] = cv.w;
  }
  for (int i = tid; i < NH*DS*8; i += 256) {
    int h = i / (DS*8), r = i % (DS*8);
    pvs[i] = prevSt[(((size_t)seq*NH + h)*NCHK + cid)*(size_t)(DS*8) + r];
  }
  for (int i = tid; i < DOUT*DI; i += 256) ow[i] = out_w[i];
  for (int i = tid; i < DI; i += 256) rwl[i] = rms_w[i];
  __syncthreads();
  int w = tid >> 6, lane = tid & 63;
  if (w < NH) {
    float el = __expf(acsG[((size_t)seq*NH + w)*LL + l0 + lane]);
    float Dh = Dp[w];
    int lg = lane >> 2, lm = lane & 3;
    float acc[8] = {0,0,0,0,0,0,0,0};
#pragma unroll 4
    for (int n = 0; n < DS; ++n) {
      float c = Ct2[(n << 6) + ((((lg ^ ((n >> 2) & 15))) << 2) | lm)];
      const float* pr = &pvs[(w*DS + n)*8];
      float4 p0 = *(const float4*)pr, p1 = *(const float4*)(pr + 4);
      acc[0] += c*p0.x; acc[1] += c*p0.y; acc[2] += c*p0.z; acc[3] += c*p0.w;
      acc[4] += c*p1.x; acc[5] += c*p1.y; acc[6] += c*p1.z; acc[7] += c*p1.w;
    }
    size_t gi = ((size_t)seq*LL + l0 + lane)*DI + w*8;
    float4 y0 = *(const float4*)&ybuf[gi], y1 = *(const float4*)&ybuf[gi+4];
    float4 xv0 = *(const float4*)&xs[gi], xv1 = *(const float4*)&xs[gi+4];
    float4 z0 = *(const float4*)&zb[gi], z1 = *(const float4*)&zb[gi+4];
    float g[8];
    g[0] = (y0.x + el*acc[0] + Dh*xv0.x) * siluf(z0.x);
    g[1] = (y0.y + el*acc[1] + Dh*xv0.y) * siluf(z0.y);
    g[2] = (y0.z + el*acc[2] + Dh*xv0.z) * siluf(z0.z);
    g[3] = (y0.w + el*acc[3] + Dh*xv0.w) * siluf(z0.w);
    g[4] = (y1.x + el*acc[4] + Dh*xv1.x) * siluf(z1.x);
    g[5] = (y1.y + el*acc[5] + Dh*xv1.y) * siluf(z1.y);
    g[6] = (y1.z + el*acc[6] + Dh*xv1.z) * siluf(z1.z);
    g[7] = (y1.w + el*acc[7] + Dh*xv1.w) * siluf(z1.w);
    float ssum = 0.f;
#pragma unroll
    for (int j = 0; j < 8; ++j) ssum += g[j]*g[j];
    float* gp = &gt[lane*DIP + w*8];
    *(float4*)gp     = make_float4(g[0], g[1], g[2], g[3]);
    *(float4*)(gp+4) = make_float4(g[4], g[5], g[6], g[7]);
    ps[w*64 + lane] = ssum;
  }
  __syncthreads();
  int tok = tid & 63, q = tid >> 6;
  float rsum = 0.f;
#pragma unroll
  for (int h = 0; h < NH; ++h) rsum += ps[h*64 + tok];
  float r = rsqrtf(rsum*(1.f/DI) + 1e-5f);
  float gr[DI];
#pragma unroll
  for (int k = 0; k < DI/4; ++k) {
    float4 v = *(const float4*)&gt[tok*DIP + 4*k];
    gr[4*k+0] = v.x*r*rwl[4*k+0];
    gr[4*k+1] = v.y*r*rwl[4*k+1];
    gr[4*k+2] = v.z*r*rwl[4*k+2];
    gr[4*k+3] = v.w*r*rwl[4*k+3];
  }
  int l = l0 + tok;
  const float* rp = nullptr; float skip = 1.f;
  if (resMode == 1) rp = res + ((size_t)seq*LL + l)*DOUT + q*OQ;
  else if (resMode == 2) {
    int s = seq / B_, b = seq % B_;
    rp = res + ((size_t)b*LL + l)*CCH + s*DOUT + q*OQ;
    skip = skipPtr[0];
  }
  float ov[OQ];
#pragma unroll
  for (int j = 0; j < OQ; ++j) {
    int o = q*OQ + j;
    const float* wr = &ow[o*DI];
    float acc2 = 0.f;
#pragma unroll
    for (int i = 0; i < DI; ++i) acc2 += gr[i]*wr[i];
    if (rp) acc2 += skip * rp[j];
    ov[j] = acc2;
  }
  float* dp = &dst[((size_t)seq*LL + l)*DOUT + q*OQ];
  if constexpr (OQ == 4) *(float4*)dp = make_float4(ov[0], ov[1], ov[2], ov[3]);
  else *(float2*)dp = make_float2(ov[0], ov[1]);
}

// ---------------- LN over C of x[b,c,l] -> xn[b,l,c] ----------------
__global__ __launch_bounds__(256) void k_ln1(const float* __restrict__ x,
    const float* __restrict__ w, const float* __restrict__ bb, float* __restrict__ xn)
{
  __shared__ float tile[128*65];
  __shared__ float mu[64], rs[64];
  int tid = threadIdx.x;
  int b = blockIdx.x >> 6;
  int l0 = (blockIdx.x & 63) << 6;
  for (int i = tid; i < 8192; i += 256) {
    int l = i & 63, c = i >> 6;
    tile[c*65 + l] = x[((size_t)b*CCH + c)*LL + l0 + l];
  }
  __syncthreads();
  if (tid < 64) {
    float s = 0.f;
    for (int c = 0; c < CCH; ++c) s += tile[c*65 + tid];
    float m = s * (1.f/CCH);
    float v = 0.f;
    for (int c = 0; c < CCH; ++c) { float d = tile[c*65 + tid] - m; v += d*d; }
    mu[tid] = m; rs[tid] = rsqrtf(v*(1.f/CCH) + 1e-5f);
  }
  __syncthreads();
  for (int i = tid; i < 8192; i += 256) {
    int c = i & 127, l = i >> 7;
    xn[((size_t)b*LL + l0 + l)*CCH + c] = (tile[c*65 + l] - mu[l])*rs[l]*w[c] + bb[c];
  }
}

// ---------------- gm[seq,c] = mean_l ys[seq,l,c] ----------------
__global__ __launch_bounds__(256) void k_gm(const float* __restrict__ ys, float* __restrict__ gm)
{
  __shared__ float red[256];
  int tid = threadIdx.x;
  int seq = blockIdx.x;
  int c = tid & 15, lane = tid >> 4;
  float s = 0.f;
  for (int l = lane; l < LL; l += 16) s += ys[((size_t)seq*LL + l)*16 + c];
  red[tid] = s;
  __syncthreads();
  if (tid < 16) {
    float t = 0.f;
    for (int g = 0; g < 16; ++g) t += red[g*16 + tid];
    gm[(size_t)seq*16 + tid] = t * (1.f/LL);
  }
}

// ---------------- gmix ----------------
__global__ __launch_bounds__(256) void k_mix(const float* __restrict__ gm,
    const float* __restrict__ crossW, float* __restrict__ gmix)
{
  __shared__ float wsm[64];
  int tid = threadIdx.x;
  if (tid < 8) {
    float mx = -1e30f;
    for (int p = 0; p < 8; ++p) mx = fmaxf(mx, crossW[tid*8 + p]);
    float e[8]; float s = 0.f;
    for (int p = 0; p < 8; ++p) { e[p] = __expf(crossW[tid*8 + p] - mx); s += e[p]; }
    for (int p = 0; p < 8; ++p) wsm[tid*8 + p] = e[p] / s;
  }
  __syncthreads();
  for (int i = tid; i < 512; i += 256) {
    int c = i & 15; int bb = (i >> 4) & 3; int p = i >> 6;
    float acc = 0.f;
    for (int q = 0; q < 8; ++q) acc += gm[((size_t)(q*B_ + bb))*16 + c] * wsm[q*8 + p];
    gmix[((size_t)(p*B_ + bb))*16 + c] = acc;
  }
}

// ---------------- assemble ys+gmix, LN2, + (x + detok(gf2)) -> outb[b,c,l] ----------------
__global__ __launch_bounds__(256) void k_out2(const float* __restrict__ ys,
    const float* __restrict__ gmix, const float* __restrict__ w, const float* __restrict__ bb,
    const float* __restrict__ x, const float* __restrict__ gf2,
    const float* __restrict__ dw, const float* __restrict__ db,
    float* __restrict__ outb)
{
  __shared__ float tile[128*65];
  __shared__ float mu[64], rs[64];
  int tid = threadIdx.x;
  int b = blockIdx.x >> 6;
  int l0 = (blockIdx.x & 63) << 6;
  for (int i = tid; i < 8192; i += 256) {
    int c = i & 15; int l = (i >> 4) & 63; int s = i >> 10;
    int seq = s*B_ + b;
    tile[(s*16 + c)*65 + l] = ys[((size_t)seq*LL + l0 + l)*16 + c] + gmix[(size_t)seq*16 + c];
  }
  __syncthreads();
  if (tid < 64) {
    float sm = 0.f;
    for (int c = 0; c < 128; ++c) sm += tile[c*65 + tid];
    float m = sm * (1.f/128.f);
    float v = 0.f;
    for (int c = 0; c < 128; ++c) { float d = tile[c*65 + tid] - m; v += d*d; }
    mu[tid] = m; rs[tid] = rsqrtf(v*(1.f/128.f) + 1e-5f);
  }
  __syncthreads();
  int lfix = tid & 63;
  float g8[8];
  {
    const float* gp = gf2 + ((size_t)b*LL + l0 + lfix)*8;
#pragma unroll
    for (int k = 0; k < 8; ++k) g8[k] = gp[k];
  }
  for (int i = tid; i < 8192; i += 256) {
    int l = i & 63, c = i >> 6;
    size_t gi = ((size_t)b*CCH + c)*LL + l0 + l;
    float det = db[c];
#pragma unroll
    for (int k = 0; k < 8; ++k) det += g8[k]*dw[c*8 + k];
    outb[gi] = (tile[c*65 + l] - mu[l])*rs[l]*w[c] + bb[c] + x[gi] + det;
  }
}

// ---------------- fc1: register-tiled GEMM ----------------
__global__ __launch_bounds__(256) void k_fc1(const float* __restrict__ src,
    const float* __restrict__ w, const float* __restrict__ bias, float* __restrict__ dst)
{
  constexpr int WP = 129;
  __shared__ float st[128*64];
  __shared__ float wt[64*WP];
  int tid = threadIdx.x;
  int blk = blockIdx.x;
  int ot = blk & 3;
  int lt = (blk >> 2) & 63;
  int b  = blk >> 8;
  int l0 = lt << 6, o0 = ot << 6;
  for (int i = tid; i < 8192; i += 256) {
    int l = i & 63, c = i >> 6;
    st[c*64 + l] = src[((size_t)b*CCH + c)*LL + l0 + l];
  }
  for (int i = tid; i < 8192; i += 256) {
    int c = i & 127, o = i >> 7;
    wt[o*WP + c] = w[(size_t)(o0 + o)*128 + c];
  }
  __syncthreads();
  int l4 = (tid & 15) << 2, o4 = (tid >> 4) << 2;
  float a0[4] = {}, a1[4] = {}, a2[4] = {}, a3[4] = {};
#pragma unroll 4
  for (int c = 0; c < 128; ++c) {
    float4 sv = *(float4*)&st[c*64 + l4];
    float w0 = wt[(o4+0)*WP + c];
    float w1 = wt[(o4+1)*WP + c];
    float w2 = wt[(o4+2)*WP + c];
    float w3 = wt[(o4+3)*WP + c];
    a0[0] += w0*sv.x; a0[1] += w0*sv.y; a0[2] += w0*sv.z; a0[3] += w0*sv.w;
    a1[0] += w1*sv.x; a1[1] += w1*sv.y; a1[2] += w1*sv.z; a1[3] += w1*sv.w;
    a2[0] += w2*sv.x; a2[1] += w2*sv.y; a2[2] += w2*sv.z; a2[3] += w2*sv.w;
    a3[0] += w3*sv.x; a3[1] += w3*sv.y; a3[2] += w3*sv.z; a3[3] += w3*sv.w;
  }
  float* rows[4] = {a0, a1, a2, a3};
#pragma unroll
  for (int j = 0; j < 4; ++j) {
    int o = o0 + o4 + j;
    float bi = bias[o];
    float* a = rows[j];
    *(float4*)&dst[((size_t)b*256 + o)*LL + l0 + l4] =
        make_float4(a[0]+bi, a[1]+bi, a[2]+bi, a[3]+bi);
  }
}

// ---------------- depthwise 3x3 + gelu, LDS-tiled ----------------
__global__ __launch_bounds__(256) void k_dw(const float* __restrict__ h1,
    const float* __restrict__ w, const float* __restrict__ bias, float* __restrict__ h2)
{
  __shared__ float tile[66*66];
  int tid = threadIdx.x;
  int blk = blockIdx.x;
  const float* base = h1 + (size_t)blk*LL;
  const float* wp = w + (blk & 255)*9;
  float bi = bias[blk & 255];
  for (int i = tid; i < 66*66; i += 256) {
    int r = i / 66, cc = i % 66;
    int gr = r - 1, gc = cc - 1;
    tile[i] = (gr >= 0 && gr < HH && gc >= 0 && gc < WW) ? base[gr*WW + gc] : 0.f;
  }
  float w00 = wp[0], w01 = wp[1], w02 = wp[2];
  float w10 = wp[3], w11 = wp[4], w12 = wp[5];
  float w20 = wp[6], w21 = wp[7], w22 = wp[8];
  __syncthreads();
  float* outp = h2 + (size_t)blk*LL;
#pragma unroll
  for (int k = 0; k < 16; ++k) {
    int j = tid + k*256;
    int row = j >> 6, col = j & 63;
    const float* t0 = &tile[row*66 + col];
    float acc = t0[0]*w00  + t0[1]*w01  + t0[2]*w02
              + t0[66]*w10 + t0[67]*w11 + t0[68]*w12
              + t0[132]*w20 + t0[133]*w21 + t0[134]*w22;
    float v = acc + bi;
    float u = 0.7978845608028654f*(v + 0.044715f*v*v*v);
    float e = __expf(2.f*u);
    float th = 1.f - 2.f/(e + 1.f);
    outp[j] = 0.5f*v*(1.f + th);
  }
}

// ---------------- fc2: register-tiled GEMM ----------------
__global__ __launch_bounds__(256) void k_fc2(const float* __restrict__ h2,
    const float* __restrict__ w, const float* __restrict__ bias,
    const float* __restrict__ resid, float* __restrict__ dst)
{
  constexpr int WP = 260;
  __shared__ float st[128*64];
  __shared__ float wt[32*WP];
  int tid = threadIdx.x;
  int blk = blockIdx.x;
  int ct = blk & 3;
  int lt = (blk >> 2) & 63;
  int b  = blk >> 8;
  int l0 = lt << 6, c0 = ct << 5;
  for (int i = tid; i < 32*256; i += 256) {
    int o = i & 255, c = i >> 8;
    wt[c*WP + o] = w[(size_t)(c0 + c)*256 + o];
  }
  int l4 = (tid & 15) << 2, c2 = (tid >> 4) << 1;
  float a0[4] = {}, a1[4] = {};
  for (int ko = 0; ko < 256; ko += 128) {
    __syncthreads();
    for (int i = tid; i < 8192; i += 256) {
      int l = i & 63, o = i >> 6;
      st[o*64 + l] = h2[((size_t)b*256 + ko + o)*LL + l0 + l];
    }
    __syncthreads();
#pragma unroll 4
    for (int o = 0; o < 128; ++o) {
      float4 sv = *(float4*)&st[o*64 + l4];
      float w0 = wt[(c2+0)*WP + ko + o];
      float w1 = wt[(c2+1)*WP + ko + o];
      a0[0] += w0*sv.x; a0[1] += w0*sv.y; a0[2] += w0*sv.z; a0[3] += w0*sv.w;
      a1[0] += w1*sv.x; a1[1] += w1*sv.y; a1[2] += w1*sv.z; a1[3] += w1*sv.w;
    }
  }
  float* rows[2] = {a0, a1};
#pragma unroll
  for (int j = 0; j < 2; ++j) {
    int c = c0 + c2 + j;
    float bi = bias[c];
    size_t gi = ((size_t)b*CCH + c)*LL + l0 + l4;
    float4 rv = *(const float4*)&resid[gi];
    float* a = rows[j];
    *(float4*)&dst[gi] = make_float4(a[0]+bi+rv.x, a[1]+bi+rv.y, a[2]+bi+rv.z, a[3]+bi+rv.w);
  }
}

extern "C" void kernel_launch(void* const* d_in, const int* in_sizes, int n_in,
                              void* d_out, int out_size, void* d_ws, size_t ws_size,
                              hipStream_t stream) {
  (void)in_sizes; (void)n_in; (void)out_size; (void)ws_size;
  const float* x        = (const float*)d_in[0];
  const float* tok_w    = (const float*)d_in[1];
  const float* tok_b    = (const float*)d_in[2];
  const float* detok_w  = (const float*)d_in[3];
  const float* detok_b  = (const float*)d_in[4];
  const float* sm_in_w  = (const float*)d_in[5];
  const float* sm_in_b  = (const float*)d_in[6];
  const float* sm_conv_w= (const float*)d_in[7];
  const float* sm_conv_b= (const float*)d_in[8];
  const float* sm_A_log = (const float*)d_in[9];
  const float* sm_D     = (const float*)d_in[10];
  const float* sm_dt_b  = (const float*)d_in[11];
  const float* sm_rms_w = (const float*)d_in[12];
  const float* sm_out_w = (const float*)d_in[13];
  const float* cm_in_w  = (const float*)d_in[14];
  const float* cm_in_b  = (const float*)d_in[15];
  const float* cm_conv_w= (const float*)d_in[16];
  const float* cm_conv_b= (const float*)d_in[17];
  const float* cm_A_log = (const float*)d_in[18];
  const float* cm_D     = (const float*)d_in[19];
  const float* cm_dt_b  = (const float*)d_in[20];
  const float* cm_rms_w = (const float*)d_in[21];
  const float* cm_out_w = (const float*)d_in[22];
  const float* cross_W  = (const float*)d_in[23];
  const float* n1w      = (const float*)d_in[24];
  const float* n1b      = (const float*)d_in[25];
  const float* n2w      = (const float*)d_in[26];
  const float* n2b      = (const float*)d_in[27];
  const float* fc1w     = (const float*)d_in[28];
  const float* fc1b     = (const float*)d_in[29];
  const float* dww      = (const float*)d_in[30];
  const float* dwb      = (const float*)d_in[31];
  const float* fc2w     = (const float*)d_in[32];
  const float* fc2b     = (const float*)d_in[33];
  const float* skp      = (const float*)d_in[34];
  float* ws  = (float*)d_ws;
  float* out = (float*)d_out;

  const size_t SGF0 = 0;
  const size_t SOUTn= 131072;
  const size_t XN   = 2097152;
  const size_t YS   = 4194304;
  const size_t OUTB = 6291456;
  const size_t GM   = 8388608;
  const size_t GMIX = 8389120;
  const size_t SCR  = 8389632;
  const size_t CZ   = SCR;
  const size_t CXS  = CZ   + 4194304;
  const size_t CCF  = CXS  + 4194304;
  const size_t CACS = CCF  + 8388608;
  const size_t CST  = CACS + 2097152;
  const size_t CCD  = CST  + 4194304;
  const size_t CY   = CCD  + 8192;
  const size_t XB   = CY   + 4194304;
  const size_t SZ   = SCR;
  const size_t SDT  = SZ  + 262144;
  const size_t SXS  = SDT + 32768;
  const size_t SB   = SXS + 262144;
  const size_t SC   = SB  + 262144;
  const size_t SACS = SC  + 262144;
  const size_t SST  = SACS + 32768;
  const size_t SCD  = SST + 65536;
  const size_t SY   = SCD + 512;
  const size_t H1 = SCR;
  const size_t H2 = SCR + 4194304;

  // ===== seed path =====
  k_seedtok<<<B_*64, 256, 0, stream>>>(x, tok_w, tok_b, ws + SGF0);
  k_inproj<8,16,16,2><<<B_*64, 256, 0, stream>>>(ws + SGF0, 0, sm_in_w, sm_in_b, sm_conv_w,
      sm_conv_b, sm_dt_b, ws + SZ, ws + SDT, ws + SXS, ws + SB, ws + SC);
  k_ssd1<16,2><<<B_*NCHK, 256, 0, stream>>>(ws + SXS, ws + SDT, ws + SB, ws + SC,
      sm_A_log, ws + SY, ws + SST, ws + SCD, ws + SACS);
  k_scan<<<B_*2, 128, 0, stream>>>(ws + SST, ws + SCD, 128);
  k_yogate<16,2,8><<<B_*NCHK, 256, 0, stream>>>(ws + SY, ws + SC, ws + SST, ws + SACS,
      sm_D, ws + SXS, ws + SZ, sm_rms_w, sm_out_w, ws + SOUTn, 1, ws + SGF0, skp);

  // ===== norm1 =====
  k_ln1<<<B_*64, 256, 0, stream>>>(x, n1w, n1b, ws + XN);

  // ===== cascade layer 0 =====
  k_inssd<<<32*NCHK, 256, 0, stream>>>(ws + XN, 1, cm_in_w, cm_in_b, cm_conv_w,
      cm_conv_b, cm_dt_b, cm_A_log, ws + CZ, ws + CXS, ws + CCF,
      ws + CY, ws + CST, ws + CCD, ws + CACS);
  k_scan<<<32*4, 512, 0, stream>>>(ws + CST, ws + CCD, 512);
  k_yogate<64,4,16><<<32*NCHK, 256, 0, stream>>>(ws + CY, ws + CCF, ws + CST, ws + CACS,
      cm_D, ws + CXS, ws + CZ, cm_rms_w, cm_out_w, ws + XB, 0, nullptr, skp);

  // ===== cascade layer 1 =====
  k_inssd<<<32*NCHK, 256, 0, stream>>>(ws + XB, 0, cm_in_w + 3136, cm_in_b + 196,
      cm_conv_w + 480, cm_conv_b + 160, cm_dt_b + 4, cm_A_log + 4, ws + CZ, ws + CXS, ws + CCF,
      ws + CY, ws + CST, ws + CCD, ws + CACS);
  k_scan<<<32*4, 512, 0, stream>>>(ws + CST, ws + CCD, 512);
  k_yogate<64,4,16><<<32*NCHK, 256, 0, stream>>>(ws + CY, ws + CCF, ws + CST, ws + CACS,
      cm_D + 4, ws + CXS, ws + CZ, cm_rms_w + 32, cm_out_w + 512, ws + YS, 2, ws + XN, skp);

  // ===== cross mix + norm2 + (fused detok seed) =====
  k_gm<<<32, 256, 0, stream>>>(ws + YS, ws + GM);
  k_mix<<<1, 256, 0, stream>>>(ws + GM, cross_W, ws + GMIX);
  k_out2<<<B_*64, 256, 0, stream>>>(ws + YS, ws + GMIX, n2w, n2b,
      x, ws + SOUTn, detok_w, detok_b, ws + OUTB);

  // ===== FFN =====
  k_fc1<<<B_*64*4, 256, 0, stream>>>(ws + OUTB, fc1w, fc1b, ws + H1);
  k_dw<<<B_*256, 256, 0, stream>>>(ws + H1, dww, dwb, ws + H2);
  k_fc2<<<B_*64*4, 256, 0, stream>>>(ws + H2, fc2w, fc2b, ws + OUTB, out);
}

// Round 11
// 540.000 us; speedup vs baseline: 1.3054x; 1.0323x over previous
//
#include <hip/hip_runtime.h>
#include <math.h>

#define B_ 4
#define CCH 128
#define HH 64
#define WW 64
#define LL 4096
#define NCHK 64

__device__ __forceinline__ float siluf(float x) { return x / (1.f + __expf(-x)); }
__device__ __forceinline__ float softplusf(float x) { return (x > 20.f) ? x : log1pf(__expf(x)); }
// swizzled [n][l] layout, pitch 64: phys = n*64 + (((l>>2) ^ ((n>>2)&15))<<2 | (l&3))
__device__ __forceinline__ int swz(int n, int l) {
  return (n << 6) + ((((l >> 2) ^ ((n >> 2) & 15)) << 2) | (l & 3));
}

// ---------------- seed tokenize v2 ----------------
__global__ __launch_bounds__(256) void k_seedtok(const float* __restrict__ x,
    const float* __restrict__ w, const float* __restrict__ bias, float* __restrict__ gf)
{
  __shared__ float tile[128*65];
  __shared__ float sw[8*128];
  __shared__ float bl[8];
  int tid = threadIdx.x;
  int b = blockIdx.x >> 6;
  int l0 = (blockIdx.x & 63) << 6;
  for (int i = tid; i < 1024; i += 256) sw[i] = w[i];
  if (tid < 8) bl[tid] = bias[tid];
  for (int i = tid; i < 8192; i += 256) {
    int l = i & 63, c = i >> 6;
    tile[c*65 + l] = x[((size_t)b*CCH + c)*LL + l0 + l];
  }
  __syncthreads();
  int l = tid & 63, q = tid >> 6;
  float a0 = bl[2*q], a1 = bl[2*q+1];
  const float* w0 = &sw[(2*q)*128];
  const float* w1 = &sw[(2*q+1)*128];
#pragma unroll 4
  for (int c = 0; c < 128; ++c) {
    float xv = tile[c*65 + l];
    a0 += xv * w0[c];
    a1 += xv * w1[c];
  }
  *(float2*)&gf[((size_t)b*LL + l0 + l)*8 + 2*q] = make_float2(a0, a1);
}

// ---------------- fused in-projection + conv3 + silu + softplus(dt) (seed path) ----------------
template<int DIN, int NZ, int NDS, int NDT>
__global__ __launch_bounds__(256) void k_inproj(
    const float* __restrict__ src, int srcMode,
    const float* __restrict__ in_w, const float* __restrict__ in_b,
    const float* __restrict__ conv_w, const float* __restrict__ conv_b,
    const float* __restrict__ dt_bias,
    float* __restrict__ zb, float* __restrict__ dtb,
    float* __restrict__ xsb, float* __restrict__ Bb, float* __restrict__ Cb)
{
  constexpr int NXBC = NZ + 2*NDS;
  constexpr int NTOT = 2*NZ + 2*NDS + NDT;
  constexpr int NZQ  = NZ/4;
  constexpr int NDSQ = NDS/4;
  constexpr int XP   = DIN + 1;
  __shared__ float xt[66*XP];
  __shared__ float wl[NTOT*DIN];
  __shared__ float cwl[NXBC*3];
  __shared__ float cbl[NXBC];
  __shared__ float ibl[NTOT];
  __shared__ float dts[64*NDT];
  __shared__ float hp[NXBC*2];
  int tid = threadIdx.x;
  int seq = blockIdx.x >> 6;
  int l0  = (blockIdx.x & 63) << 6;
  for (int i = tid; i < NTOT*DIN; i += 256) wl[i] = in_w[i];
  for (int i = tid; i < NXBC*3; i += 256) cwl[i] = conv_w[i];
  for (int i = tid; i < NXBC; i += 256) cbl[i] = conv_b[i];
  for (int i = tid; i < NTOT; i += 256) ibl[i] = in_b[i];
  const float* sp; int sstr;
  if (srcMode == 0) { sp = src + (size_t)seq*LL*DIN; sstr = DIN; }
  else { sp = src + (size_t)(seq & 3)*LL*CCH + (seq >> 2)*16; sstr = CCH; }
  for (int i = tid; i < 66*DIN; i += 256) {
    int r = i / DIN, d = i % DIN;
    int l = l0 - 2 + r;
    xt[r*XP + d] = (l >= 0) ? sp[(size_t)l*sstr + d] : 0.f;
  }
  __syncthreads();
  for (int i = tid; i < 2*NXBC; i += 256) {
    int t = i & 1, ch = i >> 1;
    const float* wr = &wl[(NZ + ch)*DIN];
    const float* xp = &xt[t*XP];
    float acc = 0.f;
#pragma unroll
    for (int d = 0; d < DIN; ++d) acc += xp[d]*wr[d];
    hp[ch*2 + t] = acc;
  }
  __syncthreads();
  int l = tid & 63, w4 = tid >> 6;
  float xr2[DIN];
#pragma unroll
  for (int d = 0; d < DIN; ++d) xr2[d] = xt[(l+2)*XP + d];
  size_t gl = (size_t)seq*LL + l0 + l;
  int tok = l0 + l;
  float v0ok = (tok >= 2) ? 1.f : 0.f;
  float v1ok = (tok >= 1) ? 1.f : 0.f;
  {
    float zv[NZQ];
#pragma unroll
    for (int j = 0; j < NZQ; ++j) {
      int row = w4*NZQ + j;
      const float* wr = &wl[row*DIN];
      float acc = ibl[row];
#pragma unroll
      for (int d = 0; d < DIN; ++d) acc += xr2[d]*wr[d];
      zv[j] = acc;
    }
#pragma unroll
    for (int g = 0; g < NZQ/4; ++g)
      *(float4*)&zb[gl*NZ + w4*NZQ + 4*g] = make_float4(zv[4*g], zv[4*g+1], zv[4*g+2], zv[4*g+3]);
  }
  if (w4 < NDT) {
    int row = NTOT - NDT + w4;
    const float* wr = &wl[row*DIN];
    float acc = ibl[row] + dt_bias[w4];
#pragma unroll
    for (int d = 0; d < DIN; ++d) acc += xr2[d]*wr[d];
    dts[l*NDT + w4] = softplusf(acc);
  }
  auto convch = [&](int ch) -> float {
    int row = NZ + ch;
    const float* wr = &wl[row*DIN];
    float pm = 0.f;
#pragma unroll
    for (int d = 0; d < DIN; ++d) pm += xr2[d]*wr[d];
    float m1 = __shfl_up(pm, 1, 64);
    float m2 = __shfl_up(pm, 2, 64);
    float h0 = hp[ch*2 + 0], h1 = hp[ch*2 + 1];
    if (l == 0) m1 = h1;
    m2 = (l == 0) ? h0 : ((l == 1) ? h1 : m2);
    float ib = ibl[row];
    float conv = cbl[ch] + (m2+ib)*v0ok*cwl[ch*3+0] + (m1+ib)*v1ok*cwl[ch*3+1] + (pm+ib)*cwl[ch*3+2];
    return siluf(conv);
  };
  {
    float xv[NZQ];
#pragma unroll
    for (int j = 0; j < NZQ; ++j) xv[j] = convch(w4*NZQ + j);
#pragma unroll
    for (int g = 0; g < NZQ/4; ++g)
      *(float4*)&xsb[gl*NZ + w4*NZQ + 4*g] = make_float4(xv[4*g], xv[4*g+1], xv[4*g+2], xv[4*g+3]);
  }
  {
    float bv[NDSQ];
#pragma unroll
    for (int j = 0; j < NDSQ; ++j) bv[j] = convch(NZ + w4*NDSQ + j);
#pragma unroll
    for (int g = 0; g < NDSQ/4; ++g)
      *(float4*)&Bb[gl*NDS + w4*NDSQ + 4*g] = make_float4(bv[4*g], bv[4*g+1], bv[4*g+2], bv[4*g+3]);
  }
  {
    float cv[NDSQ];
#pragma unroll
    for (int j = 0; j < NDSQ; ++j) cv[j] = convch(NZ + NDS + w4*NDSQ + j);
#pragma unroll
    for (int g = 0; g < NDSQ/4; ++g)
      *(float4*)&Cb[gl*NDS + w4*NDSQ + 4*g] = make_float4(cv[4*g], cv[4*g+1], cv[4*g+2], cv[4*g+3]);
  }
  __syncthreads();
  if (tid < 64) {
    if constexpr (NDT == 4) {
      *(float4*)&dtb[((size_t)seq*LL + l0 + tid)*4] =
          make_float4(dts[tid*4], dts[tid*4+1], dts[tid*4+2], dts[tid*4+3]);
    } else {
      *(float2*)&dtb[((size_t)seq*LL + l0 + tid)*NDT] = make_float2(dts[tid*NDT], dts[tid*NDT+1]);
    }
  }
}

// ======= FUSED inproj + intra-chunk SSD v3 (cascade) =======
// v3: merged Yd+states loop (xde read once); D*xs folded into ybuf; xsb buffer eliminated.
__global__ __launch_bounds__(256, 3) void k_inssd(
    const float* __restrict__ src, int srcMode,
    const float* __restrict__ in_w, const float* __restrict__ in_b,
    const float* __restrict__ conv_w, const float* __restrict__ conv_b,
    const float* __restrict__ dt_bias, const float* __restrict__ A_log,
    const float* __restrict__ Dp,
    float* __restrict__ zb, float* __restrict__ Cb,
    float* __restrict__ ybuf, float* __restrict__ states,
    float* __restrict__ cdec, float* __restrict__ acsOut)
{
  const int DIN = 16, NZ = 32, NDS = 64, DI = 32;
  const int NXBC = 160, NTOT = 196;
  __shared__ float sm[12518];            // 50072 B -> 3 blocks/CU
  float* Bt  = sm;
  float* Ct  = sm + 4096;
  float* U   = sm + 8192;
  float* wl  = U;
  float* cwl = U + 3136;
  float* cbl = U + 3616;
  float* ibl = U + 3776;
  float* hp  = U + 3972;
  float* ha  = U + 4292;
  float* xde = U;
  int tid = threadIdx.x;
  int cid = blockIdx.x & 63;
  int seq = blockIdx.x >> 6;
  int l0  = cid << 6;
  int lane = tid & 63, w = tid >> 6;
  const float* sp; int sstr;
  if (srcMode == 0) { sp = src + (size_t)seq*LL*DIN; sstr = DIN; }
  else { sp = src + (size_t)(seq & 3)*LL*CCH + (seq >> 2)*16; sstr = CCH; }
  float xr2[DIN];
  {
    const float* p = sp + (size_t)(l0 + lane)*sstr;
#pragma unroll
    for (int k = 0; k < 4; ++k) {
      float4 v = *(const float4*)(p + 4*k);
      xr2[4*k+0]=v.x; xr2[4*k+1]=v.y; xr2[4*k+2]=v.z; xr2[4*k+3]=v.w;
    }
  }
  for (int i = tid; i < NTOT*DIN; i += 256) wl[i] = in_w[i];
  for (int i = tid; i < NXBC*3; i += 256) cwl[i] = conv_w[i];
  for (int i = tid; i < NXBC; i += 256) cbl[i] = conv_b[i];
  for (int i = tid; i < NTOT; i += 256) ibl[i] = in_b[i];
  if (tid < 32) {
    int t = tid >> 4, d = tid & 15;
    int tok = l0 - 2 + t;
    ha[t*17 + d] = (tok >= 0) ? sp[(size_t)tok*sstr + d] : 0.f;
  }
  __syncthreads();
  for (int i = tid; i < 2*NXBC; i += 256) {
    int t = i & 1, ch = i >> 1;
    const float* wr = &wl[(NZ + ch)*DIN];
    const float* hr = &ha[t*17];
    float acc = 0.f;
#pragma unroll
    for (int d = 0; d < DIN; ++d) acc += hr[d]*wr[d];
    hp[ch*2 + t] = acc;
  }
  __syncthreads();
  size_t gl = (size_t)seq*LL + l0 + lane;
  int tok = l0 + lane;
  float v0ok = (tok >= 2) ? 1.f : 0.f;
  float v1ok = (tok >= 1) ? 1.f : 0.f;
  {
    float zv[8];
#pragma unroll
    for (int j = 0; j < 8; ++j) {
      int row = w*8 + j;
      const float* wr = &wl[row*DIN];
      float acc = ibl[row];
#pragma unroll
      for (int d = 0; d < DIN; ++d) acc += xr2[d]*wr[d];
      zv[j] = acc;
    }
    *(float4*)&zb[gl*NZ + w*8 + 0] = make_float4(zv[0], zv[1], zv[2], zv[3]);
    *(float4*)&zb[gl*NZ + w*8 + 4] = make_float4(zv[4], zv[5], zv[6], zv[7]);
  }
  float dtv;
  {
    int row = NTOT - 4 + w;
    const float* wr = &wl[row*DIN];
    float acc = ibl[row] + dt_bias[w];
#pragma unroll
    for (int d = 0; d < DIN; ++d) acc += xr2[d]*wr[d];
    dtv = softplusf(acc);
  }
  auto convch = [&](int ch) -> float {
    int row = NZ + ch;
    const float* wr = &wl[row*DIN];
    float pm = 0.f;
#pragma unroll
    for (int d = 0; d < DIN; ++d) pm += xr2[d]*wr[d];
    float m1 = __shfl_up(pm, 1, 64);
    float m2 = __shfl_up(pm, 2, 64);
    float h0 = hp[ch*2 + 0], h1 = hp[ch*2 + 1];
    if (lane == 0) m1 = h1;
    m2 = (lane == 0) ? h0 : ((lane == 1) ? h1 : m2);
    float ib = ibl[row];
    float conv = cbl[ch] + (m2+ib)*v0ok*cwl[ch*3+0] + (m1+ib)*v1ok*cwl[ch*3+1] + (pm+ib)*cwl[ch*3+2];
    return siluf(conv);
  };
  // xs head w: registers only (D*xs folded into ybuf below)
  float xv[8];
#pragma unroll
  for (int j = 0; j < 8; ++j) xv[j] = convch(w*8 + j);
#pragma unroll
  for (int j = 0; j < 16; ++j) {
    int n = w*16 + j;
    Bt[swz(n, lane)] = convch(NZ + n);
  }
  {
    float cv[16];
#pragma unroll
    for (int j = 0; j < 16; ++j) {
      int n = w*16 + j;
      cv[j] = convch(NZ + NDS + n);
      Ct[swz(n, lane)] = cv[j];
    }
#pragma unroll
    for (int g = 0; g < 4; ++g)
      *(float4*)&Cb[gl*NDS + w*16 + 4*g] = make_float4(cv[4*g], cv[4*g+1], cv[4*g+2], cv[4*g+3]);
  }
  __syncthreads();
  float Aval = -__expf(A_log[w]);
  float Dh = Dp[w];
  float v = dtv * Aval;
#pragma unroll
  for (int off = 1; off < 64; off <<= 1) {
    float t = __shfl_up(v, off, 64);
    if (lane >= off) v += t;
  }
  float acs_l = v;
  float m = __shfl(v, 31, 64);
  float acsLast = __shfl(v, 63, 64);
  float el = __expf(fminf(acs_l - m, 60.f));
  float fl = __expf(fminf(m - acs_l, 60.f));
  {
    float s1 = dtv*fl;
    float* xe = &xde[(w*64 + lane)*8];
    *(float4*)xe     = make_float4(xv[0]*s1, xv[1]*s1, xv[2]*s1, xv[3]*s1);
    *(float4*)(xe+4) = make_float4(xv[4]*s1, xv[5]*s1, xv[6]*s1, xv[7]*s1);
  }
  int lt = (tid >> 4) << 2, st = (tid & 15) << 2;
  float acc[4][4] = {};
#pragma unroll 4
  for (int n = 0; n < 64; ++n) {
    float4 cvv = *(const float4*)&Ct[swz(n, lt)];
    float4 bvv = *(const float4*)&Bt[swz(n, st)];
    float cc[4] = {cvv.x, cvv.y, cvv.z, cvv.w};
    float bb[4] = {bvv.x, bvv.y, bvv.z, bvv.w};
#pragma unroll
    for (int i2 = 0; i2 < 4; ++i2)
#pragma unroll
      for (int j2 = 0; j2 < 4; ++j2)
        acc[i2][j2] += cc[i2]*bb[j2];
  }
  __syncthreads();
#pragma unroll
  for (int j = 0; j < 4; ++j) {
    *(float4*)&Ct[swz(st + j, lt)] = make_float4(acc[0][j], acc[1][j], acc[2][j], acc[3][j]);
  }
  __syncthreads();
  // ---- merged Yd + states: xde rows read ONCE per s ----
  int lg = lane >> 2, lm = lane & 3;
  float ya[8] = {0,0,0,0,0,0,0,0};
  float sa[8] = {0,0,0,0,0,0,0,0};
#pragma unroll 4
  for (int s = 0; s < 64; ++s) {
    float g = Ct[(s << 6) + (((lg ^ ((s >> 2) & 15))) << 2 | lm)];
    g = (s <= lane) ? g : 0.f;
    float b = Bt[swz(lane, s)];
    const float* xr = &xde[(w*64 + s)*8];
    float4 a0 = *(const float4*)xr, a1 = *(const float4*)(xr + 4);
    ya[0] += g*a0.x; ya[1] += g*a0.y; ya[2] += g*a0.z; ya[3] += g*a0.w;
    ya[4] += g*a1.x; ya[5] += g*a1.y; ya[6] += g*a1.z; ya[7] += g*a1.w;
    sa[0] += b*a0.x; sa[1] += b*a0.y; sa[2] += b*a0.z; sa[3] += b*a0.w;
    sa[4] += b*a1.x; sa[5] += b*a1.y; sa[6] += b*a1.z; sa[7] += b*a1.w;
  }
  float* yp = &ybuf[gl*DI + w*8];
  *(float4*)yp     = make_float4(ya[0]*el + Dh*xv[0], ya[1]*el + Dh*xv[1],
                                 ya[2]*el + Dh*xv[2], ya[3]*el + Dh*xv[3]);
  *(float4*)(yp+4) = make_float4(ya[4]*el + Dh*xv[4], ya[5]*el + Dh*xv[5],
                                 ya[6]*el + Dh*xv[6], ya[7]*el + Dh*xv[7]);
  {
    float r2 = __expf(acsLast - m);
    float* sp2 = &states[(((size_t)seq*4 + w)*NCHK + cid)*(size_t)(8*NDS) + lane*8];
    *(float4*)sp2     = make_float4(sa[0]*r2, sa[1]*r2, sa[2]*r2, sa[3]*r2);
    *(float4*)(sp2+4) = make_float4(sa[4]*r2, sa[5]*r2, sa[6]*r2, sa[7]*r2);
  }
  if (lane == 63) cdec[((size_t)seq*4 + w)*NCHK + cid] = __expf(acsLast);
  acsOut[((size_t)seq*4 + w)*LL + l0 + lane] = acs_l;
}

// ---------------- SSD intra-chunk v4 (seed path): D*xs folded into ybuf ----------------
template<int DS, int NH>
__global__ __launch_bounds__(256) void k_ssd1(
    const float* __restrict__ xs, const float* __restrict__ dtb,
    const float* __restrict__ Bb, const float* __restrict__ Cb,
    const float* __restrict__ A_log, const float* __restrict__ Dp,
    float* __restrict__ ybuf, float* __restrict__ states,
    float* __restrict__ cdec, float* __restrict__ acsOut)
{
  constexpr int DI = NH*8;
  constexpr int NG = DS/4;
  __shared__ __align__(16) float BtBl[DS*64];
  __shared__ __align__(16) float CtGt[64*64];
  __shared__ __align__(16) float xde[NH*64*8];
  int tid = threadIdx.x;
  int cid = blockIdx.x & 63;
  int seq = blockIdx.x >> 6;
  int l0  = cid << 6;
  for (int i = tid; i < 16*DS; i += 256) {
    int ng = i % NG, l = i / NG;
    size_t g = ((size_t)seq*LL + l0 + l)*DS + 4*ng;
    float4 bv = *(const float4*)&Bb[g];
    float4 cv = *(const float4*)&Cb[g];
    BtBl[swz(4*ng+0, l)] = bv.x; BtBl[swz(4*ng+1, l)] = bv.y;
    BtBl[swz(4*ng+2, l)] = bv.z; BtBl[swz(4*ng+3, l)] = bv.w;
    CtGt[swz(4*ng+0, l)] = cv.x; CtGt[swz(4*ng+1, l)] = cv.y;
    CtGt[swz(4*ng+2, l)] = cv.z; CtGt[swz(4*ng+3, l)] = cv.w;
  }
  __syncthreads();
  int lt = (tid >> 4) << 2, st = (tid & 15) << 2;
  float acc[4][4] = {};
#pragma unroll 4
  for (int n = 0; n < DS; ++n) {
    float4 cv = *(const float4*)&CtGt[swz(n, lt)];
    float4 bv = *(const float4*)&BtBl[swz(n, st)];
    float cc[4] = {cv.x, cv.y, cv.z, cv.w};
    float bb[4] = {bv.x, bv.y, bv.z, bv.w};
#pragma unroll
    for (int i2 = 0; i2 < 4; ++i2)
#pragma unroll
      for (int j2 = 0; j2 < 4; ++j2)
        acc[i2][j2] += cc[i2]*bb[j2];
  }
  __syncthreads();
#pragma unroll
  for (int j = 0; j < 4; ++j) {
    float4 gv = make_float4(acc[0][j], acc[1][j], acc[2][j], acc[3][j]);
    *(float4*)&CtGt[swz(st + j, lt)] = gv;
  }
  for (int i = tid; i < 16*DS; i += 256) {
    int ng = i % NG, l = i / NG;
    float4 bv = *(const float4*)&Bb[((size_t)seq*LL + l0 + l)*DS + 4*ng];
    *(float4*)&BtBl[l*DS + 4*ng] = bv;
  }
  __syncthreads();
  int w = tid >> 6, lane = tid & 63;
  if (w < NH) {
    int h = w;
    float dt_l = dtb[((size_t)seq*LL + l0 + lane)*NH + h];
    float Aval = -__expf(A_log[h]);
    float Dh = Dp[h];
    float v = dt_l * Aval;
#pragma unroll
    for (int off = 1; off < 64; off <<= 1) {
      float t = __shfl_up(v, off, 64);
      if (lane >= off) v += t;
    }
    float acs_l = v;
    float m = __shfl(v, 31, 64);
    float acsLast = __shfl(v, 63, 64);
    float el = __expf(fminf(acs_l - m, 60.f));
    float fl = __expf(fminf(m - acs_l, 60.f));
    const float* xp = &xs[((size_t)seq*LL + l0 + lane)*DI + h*8];
    float4 x0 = *(const float4*)xp, x1 = *(const float4*)(xp + 4);
    float s1 = dt_l*fl;
    float* xe = &xde[(h*64 + lane)*8];
    *(float4*)xe     = make_float4(x0.x*s1, x0.y*s1, x0.z*s1, x0.w*s1);
    *(float4*)(xe+4) = make_float4(x1.x*s1, x1.y*s1, x1.z*s1, x1.w*s1);
    int lg = lane >> 2, lm = lane & 3;
    float ya[8] = {0,0,0,0,0,0,0,0};
#pragma unroll 4
    for (int s = 0; s < 64; ++s) {
      float g = CtGt[(s << 6) + ((((lg ^ ((s >> 2) & 15))) << 2) | lm)];
      g = (s <= lane) ? g : 0.f;
      const float* xr = &xde[(h*64 + s)*8];
      float4 a0 = *(const float4*)xr, a1 = *(const float4*)(xr + 4);
      ya[0] += g*a0.x; ya[1] += g*a0.y; ya[2] += g*a0.z; ya[3] += g*a0.w;
      ya[4] += g*a1.x; ya[5] += g*a1.y; ya[6] += g*a1.z; ya[7] += g*a1.w;
    }
    float* yp = &ybuf[((size_t)seq*LL + l0 + lane)*DI + h*8];
    *(float4*)yp     = make_float4(ya[0]*el + Dh*x0.x, ya[1]*el + Dh*x0.y,
                                   ya[2]*el + Dh*x0.z, ya[3]*el + Dh*x0.w);
    *(float4*)(yp+4) = make_float4(ya[4]*el + Dh*x1.x, ya[5]*el + Dh*x1.y,
                                   ya[6]*el + Dh*x1.z, ya[7]*el + Dh*x1.w);
    if (lane < DS) {
      float r2 = __expf(acsLast - m);
      float sa[8] = {0,0,0,0,0,0,0,0};
#pragma unroll 4
      for (int ll = 0; ll < 64; ++ll) {
        float b = BtBl[ll*DS + lane];
        const float* xr = &xde[(h*64 + ll)*8];
        float4 a0 = *(const float4*)xr, a1 = *(const float4*)(xr + 4);
        sa[0] += b*a0.x; sa[1] += b*a0.y; sa[2] += b*a0.z; sa[3] += b*a0.w;
        sa[4] += b*a1.x; sa[5] += b*a1.y; sa[6] += b*a1.z; sa[7] += b*a1.w;
      }
      float* sp2 = &states[(((size_t)seq*NH + h)*NCHK + cid)*(size_t)(8*DS) + lane*8];
      *(float4*)sp2     = make_float4(sa[0]*r2, sa[1]*r2, sa[2]*r2, sa[3]*r2);
      *(float4*)(sp2+4) = make_float4(sa[4]*r2, sa[5]*r2, sa[6]*r2, sa[7]*r2);
    }
    if (lane == 63) cdec[((size_t)seq*NH + h)*NCHK + cid] = __expf(acsLast);
    acsOut[((size_t)seq*NH + h)*LL + l0 + lane] = acs_l;
  }
}

// ---------------- inter-chunk scan ----------------
__global__ __launch_bounds__(512) void k_scan(float* __restrict__ st, const float* __restrict__ cd, int PN)
{
  int tid = threadIdx.x;
  size_t base = (size_t)blockIdx.x * NCHK * PN + tid;
  const float* c = cd + (size_t)blockIdx.x * NCHK;
  float carry = 0.f;
  for (int k = 0; k < NCHK; ++k) {
    size_t a = base + (size_t)k*PN;
    float s = st[a];
    st[a] = carry;
    carry = carry*c[k] + s;
  }
}

// ======= FUSED Yo + gating + RMSNorm + out-proj (D*xs already folded into ybuf) =======
template<int DS, int NH, int DOUT>
__global__ __launch_bounds__(256) void k_yogate(
    const float* __restrict__ ybuf, const float* __restrict__ Cb,
    const float* __restrict__ prevSt, const float* __restrict__ acsG,
    const float* __restrict__ zb,
    const float* __restrict__ rms_w, const float* __restrict__ out_w,
    float* __restrict__ dst, int resMode, const float* __restrict__ res,
    const float* __restrict__ skipPtr)
{
  constexpr int DI = NH*8;
  constexpr int NG = DS/4;
  constexpr int DIP = DI + 4;
  constexpr int OQ = DOUT/4;
  __shared__ __align__(16) float Ct2[DS*64];
  __shared__ __align__(16) float pvs[NH*DS*8];
  __shared__ __align__(16) float gt[64*DIP];
  __shared__ float ps[NH*64];
  __shared__ float ow[DOUT*DI];
  __shared__ float rwl[DI];
  int tid = threadIdx.x;
  int cid = blockIdx.x & 63;
  int seq = blockIdx.x >> 6;
  int l0  = cid << 6;
  for (int i = tid; i < 16*DS; i += 256) {
    int ng = i % NG, l = i / NG;
    float4 cv = *(const float4*)&Cb[((size_t)seq*LL + l0 + l)*DS + 4*ng];
    Ct2[swz(4*ng+0, l)] = cv.x; Ct2[swz(4*ng+1, l)] = cv.y;
    Ct2[swz(4*ng+2, l)] = cv.z; Ct2[swz(4*ng+3, l)] = cv.w;
  }
  for (int i = tid; i < NH*DS*8; i += 256) {
    int h = i / (DS*8), r = i % (DS*8);
    pvs[i] = prevSt[(((size_t)seq*NH + h)*NCHK + cid)*(size_t)(DS*8) + r];
  }
  for (int i = tid; i < DOUT*DI; i += 256) ow[i] = out_w[i];
  for (int i = tid; i < DI; i += 256) rwl[i] = rms_w[i];
  __syncthreads();
  int w = tid >> 6, lane = tid & 63;
  if (w < NH) {
    float el = __expf(acsG[((size_t)seq*NH + w)*LL + l0 + lane]);
    int lg = lane >> 2, lm = lane & 3;
    float acc[8] = {0,0,0,0,0,0,0,0};
#pragma unroll 4
    for (int n = 0; n < DS; ++n) {
      float c = Ct2[(n << 6) + ((((lg ^ ((n >> 2) & 15))) << 2) | lm)];
      const float* pr = &pvs[(w*DS + n)*8];
      float4 p0 = *(const float4*)pr, p1 = *(const float4*)(pr + 4);
      acc[0] += c*p0.x; acc[1] += c*p0.y; acc[2] += c*p0.z; acc[3] += c*p0.w;
      acc[4] += c*p1.x; acc[5] += c*p1.y; acc[6] += c*p1.z; acc[7] += c*p1.w;
    }
    size_t gi = ((size_t)seq*LL + l0 + lane)*DI + w*8;
    float4 y0 = *(const float4*)&ybuf[gi], y1 = *(const float4*)&ybuf[gi+4];
    float4 z0 = *(const float4*)&zb[gi], z1 = *(const float4*)&zb[gi+4];
    float g[8];
    g[0] = (y0.x + el*acc[0]) * siluf(z0.x);
    g[1] = (y0.y + el*acc[1]) * siluf(z0.y);
    g[2] = (y0.z + el*acc[2]) * siluf(z0.z);
    g[3] = (y0.w + el*acc[3]) * siluf(z0.w);
    g[4] = (y1.x + el*acc[4]) * siluf(z1.x);
    g[5] = (y1.y + el*acc[5]) * siluf(z1.y);
    g[6] = (y1.z + el*acc[6]) * siluf(z1.z);
    g[7] = (y1.w + el*acc[7]) * siluf(z1.w);
    float ssum = 0.f;
#pragma unroll
    for (int j = 0; j < 8; ++j) ssum += g[j]*g[j];
    float* gp = &gt[lane*DIP + w*8];
    *(float4*)gp     = make_float4(g[0], g[1], g[2], g[3]);
    *(float4*)(gp+4) = make_float4(g[4], g[5], g[6], g[7]);
    ps[w*64 + lane] = ssum;
  }
  __syncthreads();
  int tok = tid & 63, q = tid >> 6;
  float rsum = 0.f;
#pragma unroll
  for (int h = 0; h < NH; ++h) rsum += ps[h*64 + tok];
  float r = rsqrtf(rsum*(1.f/DI) + 1e-5f);
  float gr[DI];
#pragma unroll
  for (int k = 0; k < DI/4; ++k) {
    float4 v = *(const float4*)&gt[tok*DIP + 4*k];
    gr[4*k+0] = v.x*r*rwl[4*k+0];
    gr[4*k+1] = v.y*r*rwl[4*k+1];
    gr[4*k+2] = v.z*r*rwl[4*k+2];
    gr[4*k+3] = v.w*r*rwl[4*k+3];
  }
  int l = l0 + tok;
  const float* rp = nullptr; float skip = 1.f;
  if (resMode == 1) rp = res + ((size_t)seq*LL + l)*DOUT + q*OQ;
  else if (resMode == 2) {
    int s = seq / B_, b = seq % B_;
    rp = res + ((size_t)b*LL + l)*CCH + s*DOUT + q*OQ;
    skip = skipPtr[0];
  }
  float ov[OQ];
#pragma unroll
  for (int j = 0; j < OQ; ++j) {
    int o = q*OQ + j;
    const float* wr = &ow[o*DI];
    float acc2 = 0.f;
#pragma unroll
    for (int i = 0; i < DI; ++i) acc2 += gr[i]*wr[i];
    if (rp) acc2 += skip * rp[j];
    ov[j] = acc2;
  }
  float* dp = &dst[((size_t)seq*LL + l)*DOUT + q*OQ];
  if constexpr (OQ == 4) *(float4*)dp = make_float4(ov[0], ov[1], ov[2], ov[3]);
  else *(float2*)dp = make_float2(ov[0], ov[1]);
}

// ---------------- LN over C of x[b,c,l] -> xn[b,l,c] ----------------
__global__ __launch_bounds__(256) void k_ln1(const float* __restrict__ x,
    const float* __restrict__ w, const float* __restrict__ bb, float* __restrict__ xn)
{
  __shared__ float tile[128*65];
  __shared__ float mu[64], rs[64];
  int tid = threadIdx.x;
  int b = blockIdx.x >> 6;
  int l0 = (blockIdx.x & 63) << 6;
  for (int i = tid; i < 8192; i += 256) {
    int l = i & 63, c = i >> 6;
    tile[c*65 + l] = x[((size_t)b*CCH + c)*LL + l0 + l];
  }
  __syncthreads();
  if (tid < 64) {
    float s = 0.f;
    for (int c = 0; c < CCH; ++c) s += tile[c*65 + tid];
    float m = s * (1.f/CCH);
    float v = 0.f;
    for (int c = 0; c < CCH; ++c) { float d = tile[c*65 + tid] - m; v += d*d; }
    mu[tid] = m; rs[tid] = rsqrtf(v*(1.f/CCH) + 1e-5f);
  }
  __syncthreads();
  for (int i = tid; i < 8192; i += 256) {
    int c = i & 127, l = i >> 7;
    xn[((size_t)b*LL + l0 + l)*CCH + c] = (tile[c*65 + l] - mu[l])*rs[l]*w[c] + bb[c];
  }
}

// ---------------- gm[seq,c] = mean_l ys[seq,l,c] ----------------
__global__ __launch_bounds__(256) void k_gm(const float* __restrict__ ys, float* __restrict__ gm)
{
  __shared__ float red[256];
  int tid = threadIdx.x;
  int seq = blockIdx.x;
  int c = tid & 15, lane = tid >> 4;
  float s = 0.f;
  for (int l = lane; l < LL; l += 16) s += ys[((size_t)seq*LL + l)*16 + c];
  red[tid] = s;
  __syncthreads();
  if (tid < 16) {
    float t = 0.f;
    for (int g = 0; g < 16; ++g) t += red[g*16 + tid];
    gm[(size_t)seq*16 + tid] = t * (1.f/LL);
  }
}

// ---------------- gmix ----------------
__global__ __launch_bounds__(256) void k_mix(const float* __restrict__ gm,
    const float* __restrict__ crossW, float* __restrict__ gmix)
{
  __shared__ float wsm[64];
  int tid = threadIdx.x;
  if (tid < 8) {
    float mx = -1e30f;
    for (int p = 0; p < 8; ++p) mx = fmaxf(mx, crossW[tid*8 + p]);
    float e[8]; float s = 0.f;
    for (int p = 0; p < 8; ++p) { e[p] = __expf(crossW[tid*8 + p] - mx); s += e[p]; }
    for (int p = 0; p < 8; ++p) wsm[tid*8 + p] = e[p] / s;
  }
  __syncthreads();
  for (int i = tid; i < 512; i += 256) {
    int c = i & 15; int bb = (i >> 4) & 3; int p = i >> 6;
    float acc = 0.f;
    for (int q = 0; q < 8; ++q) acc += gm[((size_t)(q*B_ + bb))*16 + c] * wsm[q*8 + p];
    gmix[((size_t)(p*B_ + bb))*16 + c] = acc;
  }
}

// ---------------- assemble ys+gmix, LN2, + (x + detok(gf2)) -> outb[b,c,l] ----------------
__global__ __launch_bounds__(256) void k_out2(const float* __restrict__ ys,
    const float* __restrict__ gmix, const float* __restrict__ w, const float* __restrict__ bb,
    const float* __restrict__ x, const float* __restrict__ gf2,
    const float* __restrict__ dw, const float* __restrict__ db,
    float* __restrict__ outb)
{
  __shared__ float tile[128*65];
  __shared__ float mu[64], rs[64];
  int tid = threadIdx.x;
  int b = blockIdx.x >> 6;
  int l0 = (blockIdx.x & 63) << 6;
  for (int i = tid; i < 8192; i += 256) {
    int c = i & 15; int l = (i >> 4) & 63; int s = i >> 10;
    int seq = s*B_ + b;
    tile[(s*16 + c)*65 + l] = ys[((size_t)seq*LL + l0 + l)*16 + c] + gmix[(size_t)seq*16 + c];
  }
  __syncthreads();
  if (tid < 64) {
    float sm = 0.f;
    for (int c = 0; c < 128; ++c) sm += tile[c*65 + tid];
    float m = sm * (1.f/128.f);
    float v = 0.f;
    for (int c = 0; c < 128; ++c) { float d = tile[c*65 + tid] - m; v += d*d; }
    mu[tid] = m; rs[tid] = rsqrtf(v*(1.f/128.f) + 1e-5f);
  }
  __syncthreads();
  int lfix = tid & 63;
  float g8[8];
  {
    const float* gp = gf2 + ((size_t)b*LL + l0 + lfix)*8;
#pragma unroll
    for (int k = 0; k < 8; ++k) g8[k] = gp[k];
  }
  for (int i = tid; i < 8192; i += 256) {
    int l = i & 63, c = i >> 6;
    size_t gi = ((size_t)b*CCH + c)*LL + l0 + l;
    float det = db[c];
#pragma unroll
    for (int k = 0; k < 8; ++k) det += g8[k]*dw[c*8 + k];
    outb[gi] = (tile[c*65 + l] - mu[l])*rs[l]*w[c] + bb[c] + x[gi] + det;
  }
}

// ---------------- fc1: register-tiled GEMM ----------------
__global__ __launch_bounds__(256) void k_fc1(const float* __restrict__ src,
    const float* __restrict__ w, const float* __restrict__ bias, float* __restrict__ dst)
{
  constexpr int WP = 129;
  __shared__ float st[128*64];
  __shared__ float wt[64*WP];
  int tid = threadIdx.x;
  int blk = blockIdx.x;
  int ot = blk & 3;
  int lt = (blk >> 2) & 63;
  int b  = blk >> 8;
  int l0 = lt << 6, o0 = ot << 6;
  for (int i = tid; i < 8192; i += 256) {
    int l = i & 63, c = i >> 6;
    st[c*64 + l] = src[((size_t)b*CCH + c)*LL + l0 + l];
  }
  for (int i = tid; i < 8192; i += 256) {
    int c = i & 127, o = i >> 7;
    wt[o*WP + c] = w[(size_t)(o0 + o)*128 + c];
  }
  __syncthreads();
  int l4 = (tid & 15) << 2, o4 = (tid >> 4) << 2;
  float a0[4] = {}, a1[4] = {}, a2[4] = {}, a3[4] = {};
#pragma unroll 4
  for (int c = 0; c < 128; ++c) {
    float4 sv = *(float4*)&st[c*64 + l4];
    float w0 = wt[(o4+0)*WP + c];
    float w1 = wt[(o4+1)*WP + c];
    float w2 = wt[(o4+2)*WP + c];
    float w3 = wt[(o4+3)*WP + c];
    a0[0] += w0*sv.x; a0[1] += w0*sv.y; a0[2] += w0*sv.z; a0[3] += w0*sv.w;
    a1[0] += w1*sv.x; a1[1] += w1*sv.y; a1[2] += w1*sv.z; a1[3] += w1*sv.w;
    a2[0] += w2*sv.x; a2[1] += w2*sv.y; a2[2] += w2*sv.z; a2[3] += w2*sv.w;
    a3[0] += w3*sv.x; a3[1] += w3*sv.y; a3[2] += w3*sv.z; a3[3] += w3*sv.w;
  }
  float* rows[4] = {a0, a1, a2, a3};
#pragma unroll
  for (int j = 0; j < 4; ++j) {
    int o = o0 + o4 + j;
    float bi = bias[o];
    float* a = rows[j];
    *(float4*)&dst[((size_t)b*256 + o)*LL + l0 + l4] =
        make_float4(a[0]+bi, a[1]+bi, a[2]+bi, a[3]+bi);
  }
}

// ---------------- depthwise 3x3 + gelu, LDS-tiled ----------------
__global__ __launch_bounds__(256) void k_dw(const float* __restrict__ h1,
    const float* __restrict__ w, const float* __restrict__ bias, float* __restrict__ h2)
{
  __shared__ float tile[66*66];
  int tid = threadIdx.x;
  int blk = blockIdx.x;
  const float* base = h1 + (size_t)blk*LL;
  const float* wp = w + (blk & 255)*9;
  float bi = bias[blk & 255];
  for (int i = tid; i < 66*66; i += 256) {
    int r = i / 66, cc = i % 66;
    int gr = r - 1, gc = cc - 1;
    tile[i] = (gr >= 0 && gr < HH && gc >= 0 && gc < WW) ? base[gr*WW + gc] : 0.f;
  }
  float w00 = wp[0], w01 = wp[1], w02 = wp[2];
  float w10 = wp[3], w11 = wp[4], w12 = wp[5];
  float w20 = wp[6], w21 = wp[7], w22 = wp[8];
  __syncthreads();
  float* outp = h2 + (size_t)blk*LL;
#pragma unroll
  for (int k = 0; k < 16; ++k) {
    int j = tid + k*256;
    int row = j >> 6, col = j & 63;
    const float* t0 = &tile[row*66 + col];
    float acc = t0[0]*w00  + t0[1]*w01  + t0[2]*w02
              + t0[66]*w10 + t0[67]*w11 + t0[68]*w12
              + t0[132]*w20 + t0[133]*w21 + t0[134]*w22;
    float v = acc + bi;
    float u = 0.7978845608028654f*(v + 0.044715f*v*v*v);
    float e = __expf(2.f*u);
    float th = 1.f - 2.f/(e + 1.f);
    outp[j] = 0.5f*v*(1.f + th);
  }
}

// ---------------- fc2: register-tiled GEMM ----------------
__global__ __launch_bounds__(256) void k_fc2(const float* __restrict__ h2,
    const float* __restrict__ w, const float* __restrict__ bias,
    const float* __restrict__ resid, float* __restrict__ dst)
{
  constexpr int WP = 260;
  __shared__ float st[128*64];
  __shared__ float wt[32*WP];
  int tid = threadIdx.x;
  int blk = blockIdx.x;
  int ct = blk & 3;
  int lt = (blk >> 2) & 63;
  int b  = blk >> 8;
  int l0 = lt << 6, c0 = ct << 5;
  for (int i = tid; i < 32*256; i += 256) {
    int o = i & 255, c = i >> 8;
    wt[c*WP + o] = w[(size_t)(c0 + c)*256 + o];
  }
  int l4 = (tid & 15) << 2, c2 = (tid >> 4) << 1;
  float a0[4] = {}, a1[4] = {};
  for (int ko = 0; ko < 256; ko += 128) {
    __syncthreads();
    for (int i = tid; i < 8192; i += 256) {
      int l = i & 63, o = i >> 6;
      st[o*64 + l] = h2[((size_t)b*256 + ko + o)*LL + l0 + l];
    }
    __syncthreads();
#pragma unroll 4
    for (int o = 0; o < 128; ++o) {
      float4 sv = *(float4*)&st[o*64 + l4];
      float w0 = wt[(c2+0)*WP + ko + o];
      float w1 = wt[(c2+1)*WP + ko + o];
      a0[0] += w0*sv.x; a0[1] += w0*sv.y; a0[2] += w0*sv.z; a0[3] += w0*sv.w;
      a1[0] += w1*sv.x; a1[1] += w1*sv.y; a1[2] += w1*sv.z; a1[3] += w1*sv.w;
    }
  }
  float* rows[2] = {a0, a1};
#pragma unroll
  for (int j = 0; j < 2; ++j) {
    int c = c0 + c2 + j;
    float bi = bias[c];
    size_t gi = ((size_t)b*CCH + c)*LL + l0 + l4;
    float4 rv = *(const float4*)&resid[gi];
    float* a = rows[j];
    *(float4*)&dst[gi] = make_float4(a[0]+bi+rv.x, a[1]+bi+rv.y, a[2]+bi+rv.z, a[3]+bi+rv.w);
  }
}

extern "C" void kernel_launch(void* const* d_in, const int* in_sizes, int n_in,
                              void* d_out, int out_size, void* d_ws, size_t ws_size,
                              hipStream_t stream) {
  (void)in_sizes; (void)n_in; (void)out_size; (void)ws_size;
  const float* x        = (const float*)d_in[0];
  const float* tok_w    = (const float*)d_in[1];
  const float* tok_b    = (const float*)d_in[2];
  const float* detok_w  = (const float*)d_in[3];
  const float* detok_b  = (const float*)d_in[4];
  const float* sm_in_w  = (const float*)d_in[5];
  const float* sm_in_b  = (const float*)d_in[6];
  const float* sm_conv_w= (const float*)d_in[7];
  const float* sm_conv_b= (const float*)d_in[8];
  const float* sm_A_log = (const float*)d_in[9];
  const float* sm_D     = (const float*)d_in[10];
  const float* sm_dt_b  = (const float*)d_in[11];
  const float* sm_rms_w = (const float*)d_in[12];
  const float* sm_out_w = (const float*)d_in[13];
  const float* cm_in_w  = (const float*)d_in[14];
  const float* cm_in_b  = (const float*)d_in[15];
  const float* cm_conv_w= (const float*)d_in[16];
  const float* cm_conv_b= (const float*)d_in[17];
  const float* cm_A_log = (const float*)d_in[18];
  const float* cm_D     = (const float*)d_in[19];
  const float* cm_dt_b  = (const float*)d_in[20];
  const float* cm_rms_w = (const float*)d_in[21];
  const float* cm_out_w = (const float*)d_in[22];
  const float* cross_W  = (const float*)d_in[23];
  const float* n1w      = (const float*)d_in[24];
  const float* n1b      = (const float*)d_in[25];
  const float* n2w      = (const float*)d_in[26];
  const float* n2b      = (const float*)d_in[27];
  const float* fc1w     = (const float*)d_in[28];
  const float* fc1b     = (const float*)d_in[29];
  const float* dww      = (const float*)d_in[30];
  const float* dwb      = (const float*)d_in[31];
  const float* fc2w     = (const float*)d_in[32];
  const float* fc2b     = (const float*)d_in[33];
  const float* skp      = (const float*)d_in[34];
  float* ws  = (float*)d_ws;
  float* out = (float*)d_out;

  const size_t SGF0 = 0;
  const size_t SOUTn= 131072;
  const size_t XN   = 2097152;
  const size_t YS   = 4194304;
  const size_t OUTB = 6291456;
  const size_t GM   = 8388608;
  const size_t GMIX = 8389120;
  const size_t SCR  = 8389632;
  const size_t CZ   = SCR;
  const size_t CCF  = CZ   + 4194304;
  const size_t CACS = CCF  + 8388608;
  const size_t CST  = CACS + 2097152;
  const size_t CCD  = CST  + 4194304;
  const size_t CY   = CCD  + 8192;
  const size_t XB   = CY   + 4194304;
  const size_t SZ   = SCR;
  const size_t SDT  = SZ  + 262144;
  const size_t SXS  = SDT + 32768;
  const size_t SB   = SXS + 262144;
  const size_t SC   = SB  + 262144;
  const size_t SACS = SC  + 262144;
  const size_t SST  = SACS + 32768;
  const size_t SCD  = SST + 65536;
  const size_t SY   = SCD + 512;
  const size_t H1 = SCR;
  const size_t H2 = SCR + 4194304;

  // ===== seed path =====
  k_seedtok<<<B_*64, 256, 0, stream>>>(x, tok_w, tok_b, ws + SGF0);
  k_inproj<8,16,16,2><<<B_*64, 256, 0, stream>>>(ws + SGF0, 0, sm_in_w, sm_in_b, sm_conv_w,
      sm_conv_b, sm_dt_b, ws + SZ, ws + SDT, ws + SXS, ws + SB, ws + SC);
  k_ssd1<16,2><<<B_*NCHK, 256, 0, stream>>>(ws + SXS, ws + SDT, ws + SB, ws + SC,
      sm_A_log, sm_D, ws + SY, ws + SST, ws + SCD, ws + SACS);
  k_scan<<<B_*2, 128, 0, stream>>>(ws + SST, ws + SCD, 128);
  k_yogate<16,2,8><<<B_*NCHK, 256, 0, stream>>>(ws + SY, ws + SC, ws + SST, ws + SACS,
      ws + SZ, sm_rms_w, sm_out_w, ws + SOUTn, 1, ws + SGF0, skp);

  // ===== norm1 =====
  k_ln1<<<B_*64, 256, 0, stream>>>(x, n1w, n1b, ws + XN);

  // ===== cascade layer 0 =====
  k_inssd<<<32*NCHK, 256, 0, stream>>>(ws + XN, 1, cm_in_w, cm_in_b, cm_conv_w,
      cm_conv_b, cm_dt_b, cm_A_log, cm_D, ws + CZ, ws + CCF,
      ws + CY, ws + CST, ws + CCD, ws + CACS);
  k_scan<<<32*4, 512, 0, stream>>>(ws + CST, ws + CCD, 512);
  k_yogate<64,4,16><<<32*NCHK, 256, 0, stream>>>(ws + CY, ws + CCF, ws + CST, ws + CACS,
      ws + CZ, cm_rms_w, cm_out_w, ws + XB, 0, nullptr, skp);

  // ===== cascade layer 1 =====
  k_inssd<<<32*NCHK, 256, 0, stream>>>(ws + XB, 0, cm_in_w + 3136, cm_in_b + 196,
      cm_conv_w + 480, cm_conv_b + 160, cm_dt_b + 4, cm_A_log + 4, cm_D + 4, ws + CZ, ws + CCF,
      ws + CY, ws + CST, ws + CCD, ws + CACS);
  k_scan<<<32*4, 512, 0, stream>>>(ws + CST, ws + CCD, 512);
  k_yogate<64,4,16><<<32*NCHK, 256, 0, stream>>>(ws + CY, ws + CCF, ws + CST, ws + CACS,
      ws + CZ, cm_rms_w + 32, cm_out_w + 512, ws + YS, 2, ws + XN, skp);

  // ===== cross mix + norm2 + (fused detok seed) =====
  k_gm<<<32, 256, 0, stream>>>(ws + YS, ws + GM);
  k_mix<<<1, 256, 0, stream>>>(ws + GM, cross_W, ws + GMIX);
  k_out2<<<B_*64, 256, 0, stream>>>(ws + YS, ws + GMIX, n2w, n2b,
      x, ws + SOUTn, detok_w, detok_b, ws + OUTB);

  // ===== FFN =====
  k_fc1<<<B_*64*4, 256, 0, stream>>>(ws + OUTB, fc1w, fc1b, ws + H1);
  k_dw<<<B_*256, 256, 0, stream>>>(ws + H1, dww, dwb, ws + H2);
  k_fc2<<<B_*64*4, 256, 0, stream>>>(ws + H2, fc2w, fc2b, ws + OUTB, out);
}